// Round 1
// baseline (943.664 us; speedup 1.0000x reference)
//
#include <hip/hip_runtime.h>

#define NN 50000
#define BN_EPS_C 1e-5f

// ---------------- zero y + sums ----------------
__global__ __launch_bounds__(256) void zero_k(float* __restrict__ y,
                                              float* __restrict__ sums) {
  int gid = blockIdx.x * 256 + threadIdx.x;
  float4* y4 = (float4*)y;
  const int tot = NN * 16;  // N*64/4 float4s
  for (int i = gid; i < tot; i += gridDim.x * 256)
    y4[i] = make_float4(0.f, 0.f, 0.f, 0.f);
  if (gid < 128) sums[gid] = 0.f;
}

// ---------------- scatter aggregate: y[dst] += x[src]*w ----------------
// 16 threads per edge, float4 per thread.
__global__ __launch_bounds__(256) void agg_k(const float* __restrict__ x,
                                             const int* __restrict__ src,
                                             const int* __restrict__ dst,
                                             const float* __restrict__ ew,
                                             float* __restrict__ y, int E) {
  int gid = blockIdx.x * 256 + threadIdx.x;
  int tot = E * 16;
  if (gid >= tot) return;
  int e = gid >> 4;
  int q = gid & 15;
  int s = src[e];
  int d = dst[e];
  float w = ew[e];
  float4 v = ((const float4*)x)[s * 16 + q];
  float* yb = y + (size_t)d * 64 + q * 4;
  atomicAdd(yb + 0, v.x * w);
  atomicAdd(yb + 1, v.y * w);
  atomicAdd(yb + 2, v.z * w);
  atomicAdd(yb + 3, v.w * w);
}

// ---------------- MLP layer 1: h1 = relu((y + (1+eps)*x) @ W1^T + b1) ----------
// One wave per node; lane = output feature. W1 transposed into LDS with
// stride 65 (bank-conflict-free reads: bank=(k+f)%32 -> 2-way, free).
__global__ __launch_bounds__(256) void mlp1_k(const float* __restrict__ x,
                                              const float* __restrict__ y,
                                              const float* __restrict__ W1,
                                              const float* __restrict__ b1,
                                              const float* __restrict__ eps,
                                              float* __restrict__ h1) {
  __shared__ float Wt[64 * 65];
  int tid = threadIdx.x;
  for (int i = tid; i < 4096; i += 256) {
    int f = i >> 6, k = i & 63;
    Wt[k * 65 + f] = W1[i];  // Wt[k][f] = W1[f][k]
  }
  __syncthreads();
  const float c1 = 1.0f + eps[0];
  int lane = tid & 63;
  int wid = (blockIdx.x * 256 + tid) >> 6;
  int nwaves = (gridDim.x * 256) >> 6;
  float bias = b1[lane];
  for (int node = wid; node < NN; node += nwaves) {
    int base = node * 64;
    float in = fmaf(c1, x[base + lane], y[base + lane]);
    float acc = bias;
#pragma unroll
    for (int k = 0; k < 64; ++k)
      acc = fmaf(__shfl(in, k), Wt[k * 65 + lane], acc);
    h1[base + lane] = fmaxf(acc, 0.f);
  }
}

// ---------------- MLP layer 2: h2 = h1 @ W2^T + b2, plus BN partial sums ------
__global__ __launch_bounds__(256) void mlp2_k(const float* __restrict__ h1,
                                              const float* __restrict__ W2,
                                              const float* __restrict__ b2,
                                              float* __restrict__ h2,
                                              float* __restrict__ sums) {
  __shared__ float Wt[64 * 65];
  int tid = threadIdx.x;
  for (int i = tid; i < 4096; i += 256) {
    int f = i >> 6, k = i & 63;
    Wt[k * 65 + f] = W2[i];
  }
  __syncthreads();
  int lane = tid & 63;
  int wid = (blockIdx.x * 256 + tid) >> 6;
  int nwaves = (gridDim.x * 256) >> 6;
  float bias = b2[lane];
  float s = 0.f, sq = 0.f;
  for (int node = wid; node < NN; node += nwaves) {
    int base = node * 64;
    float in = h1[base + lane];
    float acc = bias;
#pragma unroll
    for (int k = 0; k < 64; ++k)
      acc = fmaf(__shfl(in, k), Wt[k * 65 + lane], acc);
    h2[base + lane] = acc;
    s += acc;
    sq = fmaf(acc, acc, sq);
  }
  // lane == feature index; one pair of atomics per wave
  atomicAdd(&sums[lane], s);
  atomicAdd(&sums[64 + lane], sq);
}

// ---------------- BN finalize + relu, in place on d_out ----------------
__global__ __launch_bounds__(256) void bn_k(float* __restrict__ h2out,
                                            const float* __restrict__ sums,
                                            const float* __restrict__ gamma,
                                            const float* __restrict__ beta) {
  __shared__ float sc[64], sh[64];
  int tid = threadIdx.x;
  if (tid < 64) {
    const float invN = 1.0f / NN;
    float mean = sums[tid] * invN;
    float var = fmaf(-mean, mean, sums[64 + tid] * invN);
    float s = gamma[tid] * rsqrtf(var + BN_EPS_C);
    sc[tid] = s;
    sh[tid] = fmaf(-mean, s, beta[tid]);
  }
  __syncthreads();
  int gid = blockIdx.x * 256 + tid;
  const int tot = NN * 16;
  float4* p = (float4*)h2out;
  for (int i = gid; i < tot; i += gridDim.x * 256) {
    int f0 = (i & 15) * 4;
    float4 v = p[i];
    v.x = fmaxf(fmaf(v.x, sc[f0 + 0], sh[f0 + 0]), 0.f);
    v.y = fmaxf(fmaf(v.y, sc[f0 + 1], sh[f0 + 1]), 0.f);
    v.z = fmaxf(fmaf(v.z, sc[f0 + 2], sh[f0 + 2]), 0.f);
    v.w = fmaxf(fmaf(v.w, sc[f0 + 3], sh[f0 + 3]), 0.f);
    p[i] = v;
  }
}

extern "C" void kernel_launch(void* const* d_in, const int* in_sizes, int n_in,
                              void* d_out, int out_size, void* d_ws, size_t ws_size,
                              hipStream_t stream) {
  const float* x     = (const float*)d_in[0];
  const int*   src   = (const int*)d_in[1];
  const int*   dst   = (const int*)d_in[2];
  const float* ew    = (const float*)d_in[3];
  const float* W1    = (const float*)d_in[4];
  const float* b1    = (const float*)d_in[5];
  const float* W2    = (const float*)d_in[6];
  const float* b2    = (const float*)d_in[7];
  const float* eps   = (const float*)d_in[8];
  const float* gamma = (const float*)d_in[9];
  const float* beta  = (const float*)d_in[10];
  int E = in_sizes[1];

  // ws layout: y [N*64] | h1 [N*64] | sums [128]   (25.6MB + 512B)
  float* y    = (float*)d_ws;
  float* h1   = y + NN * 64;
  float* sums = h1 + NN * 64;
  float* h2   = (float*)d_out;  // h2 lives in d_out; BN normalizes in place

  zero_k<<<1024, 256, 0, stream>>>(y, sums);
  int aggBlocks = (E * 16 + 255) / 256;
  agg_k<<<aggBlocks, 256, 0, stream>>>(x, src, dst, ew, y, E);
  mlp1_k<<<2048, 256, 0, stream>>>(x, y, W1, b1, eps, h1);
  mlp2_k<<<2048, 256, 0, stream>>>(h1, W2, b2, h2, sums);
  bn_k<<<3125, 256, 0, stream>>>(h2, sums, gamma, beta);
}

// Round 2
// 424.221 us; speedup vs baseline: 2.2245x; 2.2245x over previous
//
#include <hip/hip_runtime.h>

#define NN 50000
#define BN_EPS_C 1e-5f

// ---------------- zero counts + sums ----------------
__global__ __launch_bounds__(256) void zero_k(int* __restrict__ counts,
                                              float* __restrict__ sums) {
  int gid = blockIdx.x * 256 + threadIdx.x;
  for (int i = gid; i < NN; i += gridDim.x * 256) counts[i] = 0;
  if (gid < 128) sums[gid] = 0.f;
}

// ---------------- histogram of dst ----------------
__global__ __launch_bounds__(256) void hist_k(const int* __restrict__ dst,
                                              int* __restrict__ counts, int E) {
  int e = blockIdx.x * 256 + threadIdx.x;
  if (e < E) atomicAdd(&counts[dst[e]], 1);
}

// ---------------- exclusive scan over counts (single block) ----------------
__global__ __launch_bounds__(1024) void scan_k(const int* __restrict__ counts,
                                               int* __restrict__ offs,
                                               int* __restrict__ cursor) {
  __shared__ int sbuf[1024];
  int tid = threadIdx.x;
  const int C = (NN + 1023) / 1024;  // 49 elements per thread
  int lo = tid * C, hi = min(lo + C, NN);
  int lsum = 0;
  for (int i = lo; i < hi; ++i) lsum += counts[i];
  sbuf[tid] = lsum;
  __syncthreads();
  for (int off = 1; off < 1024; off <<= 1) {
    int v = (tid >= off) ? sbuf[tid - off] : 0;
    __syncthreads();
    sbuf[tid] += v;
    __syncthreads();
  }
  int run = sbuf[tid] - lsum;  // exclusive prefix of this chunk
  for (int i = lo; i < hi; ++i) {
    offs[i] = run;
    cursor[i] = run;
    run += counts[i];
  }
}

// ---------------- scatter edges into dst-sorted order ----------------
__global__ __launch_bounds__(256) void scatter_k(const int* __restrict__ src,
                                                 const int* __restrict__ dst,
                                                 const float* __restrict__ ew,
                                                 int* __restrict__ cursor,
                                                 int2* __restrict__ sorted, int E) {
  int e = blockIdx.x * 256 + threadIdx.x;
  if (e >= E) return;
  int d = dst[e];
  int pos = atomicAdd(&cursor[d], 1);
  sorted[pos] = make_int2(src[e], __float_as_int(ew[e]));
}

// ---------------- fused gather-aggregate + GIN residual + MLP1 ----------------
// One wave per node, lane = feature. W1 row `lane` held in 64 VGPRs.
__global__ __launch_bounds__(256) void gmlp1_k(const float* __restrict__ x,
                                               const int2* __restrict__ sorted,
                                               const int* __restrict__ offs,
                                               const int* __restrict__ counts,
                                               const float* __restrict__ W1,
                                               const float* __restrict__ b1,
                                               const float* __restrict__ eps,
                                               float* __restrict__ h1) {
  int tid = threadIdx.x;
  int lane = tid & 63;
  float w1r[64];
  {
    const float4* W4 = (const float4*)(W1 + lane * 64);
#pragma unroll
    for (int q = 0; q < 16; ++q) {
      float4 t = W4[q];
      w1r[4 * q + 0] = t.x; w1r[4 * q + 1] = t.y;
      w1r[4 * q + 2] = t.z; w1r[4 * q + 3] = t.w;
    }
  }
  const float c1 = 1.0f + eps[0];
  const float bias = b1[lane];
  int wid = (blockIdx.x * 256 + tid) >> 6;
  int nwaves = (gridDim.x * 256) >> 6;
  for (int node = wid; node < NN; node += nwaves) {
    float acc = c1 * x[node * 64 + lane];
    int off = offs[node], cnt = counts[node];
    float a0 = 0.f, a1 = 0.f, a2 = 0.f, a3 = 0.f;
    for (int i = 0; i < cnt; i += 64) {
      int take = min(64, cnt - i);
      int2 meta = make_int2(0, 0);
      if (lane < take) meta = sorted[off + i + lane];
      int j = 0;
      for (; j + 3 < take; j += 4) {
        int s0 = __shfl(meta.x, j + 0), s1 = __shfl(meta.x, j + 1),
            s2 = __shfl(meta.x, j + 2), s3 = __shfl(meta.x, j + 3);
        float w0 = __int_as_float(__shfl(meta.y, j + 0));
        float w1 = __int_as_float(__shfl(meta.y, j + 1));
        float w2 = __int_as_float(__shfl(meta.y, j + 2));
        float w3 = __int_as_float(__shfl(meta.y, j + 3));
        a0 = fmaf(x[s0 * 64 + lane], w0, a0);
        a1 = fmaf(x[s1 * 64 + lane], w1, a1);
        a2 = fmaf(x[s2 * 64 + lane], w2, a2);
        a3 = fmaf(x[s3 * 64 + lane], w3, a3);
      }
      for (; j < take; ++j) {
        int s = __shfl(meta.x, j);
        float w = __int_as_float(__shfl(meta.y, j));
        a0 = fmaf(x[s * 64 + lane], w, a0);
      }
    }
    acc += (a0 + a1) + (a2 + a3);
    // MLP1: out[lane] = relu(b1[lane] + sum_k in[k] * W1[lane][k])
    float o = bias;
#pragma unroll
    for (int k = 0; k < 64; ++k)
      o = fmaf(__shfl(acc, k), w1r[k], o);
    h1[node * 64 + lane] = fmaxf(o, 0.f);
  }
}

// ---------------- MLP2 + BN partial sums ----------------
__global__ __launch_bounds__(256) void mlp2_k(const float* __restrict__ h1,
                                              const float* __restrict__ W2,
                                              const float* __restrict__ b2,
                                              float* __restrict__ h2,
                                              float* __restrict__ sums) {
  int tid = threadIdx.x;
  int lane = tid & 63;
  float w2r[64];
  {
    const float4* W4 = (const float4*)(W2 + lane * 64);
#pragma unroll
    for (int q = 0; q < 16; ++q) {
      float4 t = W4[q];
      w2r[4 * q + 0] = t.x; w2r[4 * q + 1] = t.y;
      w2r[4 * q + 2] = t.z; w2r[4 * q + 3] = t.w;
    }
  }
  const float bias = b2[lane];
  int wid = (blockIdx.x * 256 + tid) >> 6;
  int nwaves = (gridDim.x * 256) >> 6;
  float s = 0.f, sq = 0.f;
  for (int node = wid; node < NN; node += nwaves) {
    float in = h1[node * 64 + lane];
    float o = bias;
#pragma unroll
    for (int k = 0; k < 64; ++k)
      o = fmaf(__shfl(in, k), w2r[k], o);
    h2[node * 64 + lane] = o;
    s += o;
    sq = fmaf(o, o, sq);
  }
  atomicAdd(&sums[lane], s);
  atomicAdd(&sums[64 + lane], sq);
}

// ---------------- BN finalize + relu, in place on d_out ----------------
__global__ __launch_bounds__(256) void bn_k(float* __restrict__ h2out,
                                            const float* __restrict__ sums,
                                            const float* __restrict__ gamma,
                                            const float* __restrict__ beta) {
  __shared__ float sc[64], sh[64];
  int tid = threadIdx.x;
  if (tid < 64) {
    const float invN = 1.0f / NN;
    float mean = sums[tid] * invN;
    float var = fmaf(-mean, mean, sums[64 + tid] * invN);
    float s = gamma[tid] * rsqrtf(var + BN_EPS_C);
    sc[tid] = s;
    sh[tid] = fmaf(-mean, s, beta[tid]);
  }
  __syncthreads();
  int gid = blockIdx.x * 256 + tid;
  const int tot = NN * 16;
  float4* p = (float4*)h2out;
  for (int i = gid; i < tot; i += gridDim.x * 256) {
    int f0 = (i & 15) * 4;
    float4 v = p[i];
    v.x = fmaxf(fmaf(v.x, sc[f0 + 0], sh[f0 + 0]), 0.f);
    v.y = fmaxf(fmaf(v.y, sc[f0 + 1], sh[f0 + 1]), 0.f);
    v.z = fmaxf(fmaf(v.z, sc[f0 + 2], sh[f0 + 2]), 0.f);
    v.w = fmaxf(fmaf(v.w, sc[f0 + 3], sh[f0 + 3]), 0.f);
    p[i] = v;
  }
}

extern "C" void kernel_launch(void* const* d_in, const int* in_sizes, int n_in,
                              void* d_out, int out_size, void* d_ws, size_t ws_size,
                              hipStream_t stream) {
  const float* x     = (const float*)d_in[0];
  const int*   src   = (const int*)d_in[1];
  const int*   dst   = (const int*)d_in[2];
  const float* ew    = (const float*)d_in[3];
  const float* W1    = (const float*)d_in[4];
  const float* b1    = (const float*)d_in[5];
  const float* W2    = (const float*)d_in[6];
  const float* b2    = (const float*)d_in[7];
  const float* eps   = (const float*)d_in[8];
  const float* gamma = (const float*)d_in[9];
  const float* beta  = (const float*)d_in[10];
  int E = in_sizes[1];

  // ws layout: counts[NN] | offs[NN] | cursor[NN] | sorted[E] int2 | h1[NN*64] | sums[128]
  int*   counts = (int*)d_ws;
  int*   offs   = counts + NN;
  int*   cursor = offs + NN;
  int2*  sorted = (int2*)(cursor + NN);
  float* h1     = (float*)(sorted + E);
  float* sums   = h1 + NN * 64;
  float* h2     = (float*)d_out;  // h2 lives in d_out; BN normalizes in place

  int eb = (E + 255) / 256;
  zero_k<<<256, 256, 0, stream>>>(counts, sums);
  hist_k<<<eb, 256, 0, stream>>>(dst, counts, E);
  scan_k<<<1, 1024, 0, stream>>>(counts, offs, cursor);
  scatter_k<<<eb, 256, 0, stream>>>(src, dst, ew, cursor, sorted, E);
  gmlp1_k<<<1024, 256, 0, stream>>>(x, sorted, offs, counts, W1, b1, eps, h1);
  mlp2_k<<<1024, 256, 0, stream>>>(h1, W2, b2, h2, sums);
  bn_k<<<3125, 256, 0, stream>>>(h2, sums, gamma, beta);
}

// Round 3
// 332.773 us; speedup vs baseline: 2.8358x; 1.2748x over previous
//
#include <hip/hip_runtime.h>

#define NN 50000
#define BN_EPS_C 1e-5f
#define TILE 64
#define NB ((NN + TILE - 1) / TILE)  // 782

// ---------------- prep: zero counts/sums, transpose W1,W2 into ws ----------------
__global__ __launch_bounds__(256) void prep_k(const float* __restrict__ W1,
                                              const float* __restrict__ W2,
                                              int* __restrict__ counts,
                                              float* __restrict__ sums,
                                              float* __restrict__ W1t,
                                              float* __restrict__ W2t) {
  int gid = blockIdx.x * 256 + threadIdx.x;
  for (int i = gid; i < NN; i += gridDim.x * 256) counts[i] = 0;
  if (gid < 128) sums[gid] = 0.f;
  for (int i = gid; i < 4096; i += gridDim.x * 256) {
    int f = i >> 6, k = i & 63;
    W1t[k * 64 + f] = W1[i];  // Wt[k][f] = W[f][k]
    W2t[k * 64 + f] = W2[i];
  }
}

// ---------------- histogram of dst ----------------
__global__ __launch_bounds__(256) void hist_k(const int* __restrict__ dst,
                                              int* __restrict__ counts, int E) {
  int e = blockIdx.x * 256 + threadIdx.x;
  if (e < E) atomicAdd(&counts[dst[e]], 1);
}

// ---------------- exclusive scan over counts (single block) ----------------
__global__ __launch_bounds__(1024) void scan_k(const int* __restrict__ counts,
                                               int* __restrict__ offs,
                                               int* __restrict__ cursor) {
  __shared__ int sbuf[1024];
  int tid = threadIdx.x;
  const int C = (NN + 1023) / 1024;  // 49
  int lo = tid * C, hi = min(lo + C, NN);
  int lsum = 0;
  for (int i = lo; i < hi; ++i) lsum += counts[i];
  sbuf[tid] = lsum;
  __syncthreads();
  for (int off = 1; off < 1024; off <<= 1) {
    int v = (tid >= off) ? sbuf[tid - off] : 0;
    __syncthreads();
    sbuf[tid] += v;
    __syncthreads();
  }
  int run = sbuf[tid] - lsum;
  for (int i = lo; i < hi; ++i) {
    offs[i] = run;
    cursor[i] = run;
    run += counts[i];
  }
}

// ---------------- scatter edges into dst-sorted order ----------------
__global__ __launch_bounds__(256) void scatter_k(const int* __restrict__ src,
                                                 const int* __restrict__ dst,
                                                 const float* __restrict__ ew,
                                                 int* __restrict__ cursor,
                                                 int2* __restrict__ sorted, int E) {
  int e = blockIdx.x * 256 + threadIdx.x;
  if (e >= E) return;
  int d = dst[e];
  int pos = atomicAdd(&cursor[d], 1);
  sorted[pos] = make_int2(src[e], __float_as_int(ew[e]));
}

// ---------------- fused: gather + residual + MLP1(relu) + MLP2 + BN partials ----
// Block = 64-node tile, 256 threads. Gather: wave per 16 nodes, lane = feature.
// GEMMs: 16x16 thread grid, 4 nodes x 4 feats register tile per thread.
__global__ __launch_bounds__(256) void fuse_k(const float* __restrict__ x,
                                              const int2* __restrict__ sorted,
                                              const int* __restrict__ offs,
                                              const int* __restrict__ counts,
                                              const float* __restrict__ W1t,
                                              const float* __restrict__ W2t,
                                              const float* __restrict__ b1,
                                              const float* __restrict__ b2,
                                              const float* __restrict__ eps,
                                              float* __restrict__ out,
                                              float* __restrict__ sums) {
  __shared__ float hT[64][68];   // [k][local node], pad 68 keeps 16B alignment
  __shared__ float h1T[64][68];
  __shared__ float WA[64][64];   // W1t, then reused for W2t
  int tid = threadIdx.x;
  int lane = tid & 63;
  int wv = tid >> 6;
  int tile0 = blockIdx.x * TILE;

  for (int i = tid; i < 4096; i += 256) ((float*)WA)[i] = W1t[i];

  const float c1 = 1.0f + eps[0];
  // ---- gather phase: 16 nodes per wave, lane = input feature ----
  for (int i = 0; i < 16; ++i) {
    int node = tile0 + wv * 16 + i;
    float acc = 0.f;
    if (node < NN) {
      acc = c1 * x[node * 64 + lane];
      int off = offs[node], cnt = counts[node];
      float a0 = 0.f, a1 = 0.f, a2 = 0.f, a3 = 0.f;
      for (int b = 0; b < cnt; b += 64) {
        int take = min(64, cnt - b);
        int2 meta = make_int2(0, 0);
        if (lane < take) meta = sorted[off + b + lane];
        int j = 0;
        for (; j + 3 < take; j += 4) {
          int s0 = __shfl(meta.x, j + 0), s1 = __shfl(meta.x, j + 1),
              s2 = __shfl(meta.x, j + 2), s3 = __shfl(meta.x, j + 3);
          float w0 = __int_as_float(__shfl(meta.y, j + 0));
          float w1 = __int_as_float(__shfl(meta.y, j + 1));
          float w2 = __int_as_float(__shfl(meta.y, j + 2));
          float w3 = __int_as_float(__shfl(meta.y, j + 3));
          a0 = fmaf(x[s0 * 64 + lane], w0, a0);
          a1 = fmaf(x[s1 * 64 + lane], w1, a1);
          a2 = fmaf(x[s2 * 64 + lane], w2, a2);
          a3 = fmaf(x[s3 * 64 + lane], w3, a3);
        }
        for (; j < take; ++j) {
          int s = __shfl(meta.x, j);
          float w = __int_as_float(__shfl(meta.y, j));
          a0 = fmaf(x[s * 64 + lane], w, a0);
        }
      }
      acc += (a0 + a1) + (a2 + a3);
    }
    hT[lane][wv * 16 + i] = acc;  // stride 68 across lanes -> benign banks
  }
  __syncthreads();

  // ---- GEMM1: o[n][f] = relu(b1[f] + sum_k hT[k][n] * WA[k][f]) ----
  int fg = tid & 15, ng = tid >> 4;
  int f0 = fg * 4, n0 = ng * 4;
  float4 bv = *(const float4*)(b1 + f0);
  float o[4][4];
#pragma unroll
  for (int n = 0; n < 4; ++n) {
    o[n][0] = bv.x; o[n][1] = bv.y; o[n][2] = bv.z; o[n][3] = bv.w;
  }
#pragma unroll 8
  for (int k = 0; k < 64; ++k) {
    float4 in4 = *(const float4*)&hT[k][n0];
    float4 w4 = *(const float4*)&WA[k][f0];
    float in[4] = {in4.x, in4.y, in4.z, in4.w};
    float ww[4] = {w4.x, w4.y, w4.z, w4.w};
#pragma unroll
    for (int n = 0; n < 4; ++n)
#pragma unroll
      for (int j = 0; j < 4; ++j) o[n][j] = fmaf(in[n], ww[j], o[n][j]);
  }
#pragma unroll
  for (int n = 0; n < 4; ++n)
#pragma unroll
    for (int j = 0; j < 4; ++j) o[n][j] = fmaxf(o[n][j], 0.f);

  __syncthreads();  // GEMM1 reads of hT/WA done
  // write h1 transposed; swap WA to W2t
#pragma unroll
  for (int j = 0; j < 4; ++j) {
    float4 v = {o[0][j], o[1][j], o[2][j], o[3][j]};
    *(float4*)&h1T[f0 + j][n0] = v;
  }
  for (int i = tid; i < 4096; i += 256) ((float*)WA)[i] = W2t[i];
  __syncthreads();

  // ---- GEMM2: o2[n][f] = b2[f] + sum_k h1T[k][n] * WA[k][f] ----
  float4 bv2 = *(const float4*)(b2 + f0);
  float o2[4][4];
#pragma unroll
  for (int n = 0; n < 4; ++n) {
    o2[n][0] = bv2.x; o2[n][1] = bv2.y; o2[n][2] = bv2.z; o2[n][3] = bv2.w;
  }
#pragma unroll 8
  for (int k = 0; k < 64; ++k) {
    float4 in4 = *(const float4*)&h1T[k][n0];
    float4 w4 = *(const float4*)&WA[k][f0];
    float in[4] = {in4.x, in4.y, in4.z, in4.w};
    float ww[4] = {w4.x, w4.y, w4.z, w4.w};
#pragma unroll
    for (int n = 0; n < 4; ++n)
#pragma unroll
      for (int j = 0; j < 4; ++j) o2[n][j] = fmaf(in[n], ww[j], o2[n][j]);
  }

  // ---- write h2 + BN partial sums ----
  float s[4] = {0.f, 0.f, 0.f, 0.f}, q[4] = {0.f, 0.f, 0.f, 0.f};
#pragma unroll
  for (int n = 0; n < 4; ++n) {
    int node = tile0 + n0 + n;
    if (node < NN) {
      float4 v = {o2[n][0], o2[n][1], o2[n][2], o2[n][3]};
      *(float4*)&out[node * 64 + f0] = v;
#pragma unroll
      for (int j = 0; j < 4; ++j) {
        s[j] += o2[n][j];
        q[j] = fmaf(o2[n][j], o2[n][j], q[j]);
      }
    }
  }
  float* red = &hT[0][0];  // hT is dead after GEMM1; 2048 floats needed
#pragma unroll
  for (int j = 0; j < 4; ++j) {
    red[(f0 + j) * 16 + ng] = s[j];
    red[1024 + (f0 + j) * 16 + ng] = q[j];
  }
  __syncthreads();
  if (tid < 64) {
    float ss = 0.f, qq = 0.f;
    for (int g = 0; g < 16; ++g) {
      ss += red[tid * 16 + g];
      qq += red[1024 + tid * 16 + g];
    }
    atomicAdd(&sums[tid], ss);
    atomicAdd(&sums[64 + tid], qq);
  }
}

// ---------------- BN finalize + relu, in place on d_out ----------------
__global__ __launch_bounds__(256) void bn_k(float* __restrict__ h2out,
                                            const float* __restrict__ sums,
                                            const float* __restrict__ gamma,
                                            const float* __restrict__ beta) {
  __shared__ float sc[64], sh[64];
  int tid = threadIdx.x;
  if (tid < 64) {
    const float invN = 1.0f / NN;
    float mean = sums[tid] * invN;
    float var = fmaf(-mean, mean, sums[64 + tid] * invN);
    float s = gamma[tid] * rsqrtf(var + BN_EPS_C);
    sc[tid] = s;
    sh[tid] = fmaf(-mean, s, beta[tid]);
  }
  __syncthreads();
  int gid = blockIdx.x * 256 + tid;
  const int tot = NN * 16;
  float4* p = (float4*)h2out;
  for (int i = gid; i < tot; i += gridDim.x * 256) {
    int f0 = (i & 15) * 4;
    float4 v = p[i];
    v.x = fmaxf(fmaf(v.x, sc[f0 + 0], sh[f0 + 0]), 0.f);
    v.y = fmaxf(fmaf(v.y, sc[f0 + 1], sh[f0 + 1]), 0.f);
    v.z = fmaxf(fmaf(v.z, sc[f0 + 2], sh[f0 + 2]), 0.f);
    v.w = fmaxf(fmaf(v.w, sc[f0 + 3], sh[f0 + 3]), 0.f);
    p[i] = v;
  }
}

extern "C" void kernel_launch(void* const* d_in, const int* in_sizes, int n_in,
                              void* d_out, int out_size, void* d_ws, size_t ws_size,
                              hipStream_t stream) {
  const float* x     = (const float*)d_in[0];
  const int*   src   = (const int*)d_in[1];
  const int*   dst   = (const int*)d_in[2];
  const float* ew    = (const float*)d_in[3];
  const float* W1    = (const float*)d_in[4];
  const float* b1    = (const float*)d_in[5];
  const float* W2    = (const float*)d_in[6];
  const float* b2    = (const float*)d_in[7];
  const float* eps   = (const float*)d_in[8];
  const float* gamma = (const float*)d_in[9];
  const float* beta  = (const float*)d_in[10];
  int E = in_sizes[1];

  // ws: counts[NN] | offs[NN] | cursor[NN] | sorted[E] int2 | W1t[4096] | W2t[4096] | sums[128]
  int*   counts = (int*)d_ws;
  int*   offs   = counts + NN;
  int*   cursor = offs + NN;
  int2*  sorted = (int2*)(cursor + NN);
  float* W1t    = (float*)(sorted + E);
  float* W2t    = W1t + 4096;
  float* sums   = W2t + 4096;
  float* h2     = (float*)d_out;

  int eb = (E + 255) / 256;
  prep_k<<<64, 256, 0, stream>>>(W1, W2, counts, sums, W1t, W2t);
  hist_k<<<eb, 256, 0, stream>>>(dst, counts, E);
  scan_k<<<1, 1024, 0, stream>>>(counts, offs, cursor);
  scatter_k<<<eb, 256, 0, stream>>>(src, dst, ew, cursor, sorted, E);
  fuse_k<<<NB, 256, 0, stream>>>(x, sorted, offs, counts, W1t, W2t, b1, b2, eps, h2, sums);
  bn_k<<<3125, 256, 0, stream>>>(h2, sums, gamma, beta);
}

// Round 4
// 316.442 us; speedup vs baseline: 2.9821x; 1.0516x over previous
//
#include <hip/hip_runtime.h>

#define NN 50000
#define BN_EPS_C 1e-5f
#define TILE 32
#define NB ((NN + TILE - 1) / TILE)  // 1563

// ---------------- prep: zero counts/sums, transpose W1,W2 into ws ----------------
__global__ __launch_bounds__(256) void prep_k(const float* __restrict__ W1,
                                              const float* __restrict__ W2,
                                              int* __restrict__ counts,
                                              float* __restrict__ sums,
                                              float* __restrict__ W1t,
                                              float* __restrict__ W2t) {
  int gid = blockIdx.x * 256 + threadIdx.x;
  for (int i = gid; i < NN; i += gridDim.x * 256) counts[i] = 0;
  if (gid < 128) sums[gid] = 0.f;
  for (int i = gid; i < 4096; i += gridDim.x * 256) {
    int f = i >> 6, k = i & 63;
    W1t[k * 64 + f] = W1[i];  // Wt[k][f] = W[f][k]
    W2t[k * 64 + f] = W2[i];
  }
}

// ---------------- histogram of dst (4 edges/thread) ----------------
__global__ __launch_bounds__(256) void hist_k(const int* __restrict__ dst,
                                              int* __restrict__ counts, int E) {
  int t = blockIdx.x * 256 + threadIdx.x;
  int e = t * 4;
  if (e + 3 < E) {
    int4 d = *(const int4*)(dst + e);
    atomicAdd(&counts[d.x], 1);
    atomicAdd(&counts[d.y], 1);
    atomicAdd(&counts[d.z], 1);
    atomicAdd(&counts[d.w], 1);
  } else {
    for (; e < E; ++e) atomicAdd(&counts[dst[e]], 1);
  }
}

// ---------------- exclusive scan over counts (single block) ----------------
__global__ __launch_bounds__(1024) void scan_k(const int* __restrict__ counts,
                                               int* __restrict__ offs,
                                               int* __restrict__ cursor) {
  __shared__ int sbuf[1024];
  int tid = threadIdx.x;
  const int C = (NN + 1023) / 1024;  // 49
  int lo = tid * C, hi = min(lo + C, NN);
  int lsum = 0;
  for (int i = lo; i < hi; ++i) lsum += counts[i];
  sbuf[tid] = lsum;
  __syncthreads();
  for (int off = 1; off < 1024; off <<= 1) {
    int v = (tid >= off) ? sbuf[tid - off] : 0;
    __syncthreads();
    sbuf[tid] += v;
    __syncthreads();
  }
  int run = sbuf[tid] - lsum;
  for (int i = lo; i < hi; ++i) {
    offs[i] = run;
    cursor[i] = run;
    run += counts[i];
  }
}

// ---------------- scatter edges into dst-sorted order (4 edges/thread) --------
__global__ __launch_bounds__(256) void scatter_k(const int* __restrict__ src,
                                                 const int* __restrict__ dst,
                                                 const float* __restrict__ ew,
                                                 int* __restrict__ cursor,
                                                 int2* __restrict__ sorted, int E) {
  int t = blockIdx.x * 256 + threadIdx.x;
  int e = t * 4;
  if (e + 3 < E) {
    int4 s = *(const int4*)(src + e);
    int4 d = *(const int4*)(dst + e);
    float4 w = *(const float4*)(ew + e);
    int p0 = atomicAdd(&cursor[d.x], 1);
    int p1 = atomicAdd(&cursor[d.y], 1);
    int p2 = atomicAdd(&cursor[d.z], 1);
    int p3 = atomicAdd(&cursor[d.w], 1);
    sorted[p0] = make_int2(s.x, __float_as_int(w.x));
    sorted[p1] = make_int2(s.y, __float_as_int(w.y));
    sorted[p2] = make_int2(s.z, __float_as_int(w.z));
    sorted[p3] = make_int2(s.w, __float_as_int(w.w));
  } else {
    for (; e < E; ++e) {
      int pos = atomicAdd(&cursor[dst[e]], 1);
      sorted[pos] = make_int2(src[e], __float_as_int(ew[e]));
    }
  }
}

// ---------------- fused: gather + residual + MLP1(relu) + MLP2 + BN partials ----
// Block = 32-node tile, 256 threads (4 waves, 8 nodes/wave in gather).
// GEMMs: 16fg x 16ng thread grid, 2-node x 4-feat register tile per thread.
// LDS: hT[64][34] (k-major, reused for h1 and BN reduce) + WA[64][64] = 25KB.
__global__ __launch_bounds__(256) void fuse_k(const float* __restrict__ x,
                                              const int2* __restrict__ sorted,
                                              const int* __restrict__ offs,
                                              const int* __restrict__ counts,
                                              const float* __restrict__ W1t,
                                              const float* __restrict__ W2t,
                                              const float* __restrict__ b1,
                                              const float* __restrict__ b2,
                                              const float* __restrict__ eps,
                                              float* __restrict__ out,
                                              float* __restrict__ sums) {
  __shared__ float hT[64][34];   // [k][local node]
  __shared__ float WA[64][64];   // W1t, then reused for W2t
  int tid = threadIdx.x;
  int lane = tid & 63;
  int wv = tid >> 6;
  int tile0 = blockIdx.x * TILE;

  for (int i = tid; i < 4096; i += 256) ((float*)WA)[i] = W1t[i];

  const float c1 = 1.0f + eps[0];
  // ---- gather: 8 nodes per wave, lane = input feature, 8-deep load ILP ----
  for (int i = 0; i < 8; ++i) {
    int node = tile0 + wv * 8 + i;
    float acc = 0.f;
    if (node < NN) {
      acc = c1 * x[node * 64 + lane];
      int off = offs[node], cnt = counts[node];
      float a0 = 0.f, a1 = 0.f, a2 = 0.f, a3 = 0.f;
      float a4 = 0.f, a5 = 0.f, a6 = 0.f, a7 = 0.f;
      for (int b = 0; b < cnt; b += 64) {
        int take = min(64, cnt - b);
        int2 meta = make_int2(0, 0);
        if (lane < take) meta = sorted[off + b + lane];
        int j = 0;
        for (; j + 7 < take; j += 8) {
          int s0 = __shfl(meta.x, j + 0), s1 = __shfl(meta.x, j + 1),
              s2 = __shfl(meta.x, j + 2), s3 = __shfl(meta.x, j + 3),
              s4 = __shfl(meta.x, j + 4), s5 = __shfl(meta.x, j + 5),
              s6 = __shfl(meta.x, j + 6), s7 = __shfl(meta.x, j + 7);
          float w0 = __int_as_float(__shfl(meta.y, j + 0));
          float w1 = __int_as_float(__shfl(meta.y, j + 1));
          float w2 = __int_as_float(__shfl(meta.y, j + 2));
          float w3 = __int_as_float(__shfl(meta.y, j + 3));
          float w4 = __int_as_float(__shfl(meta.y, j + 4));
          float w5 = __int_as_float(__shfl(meta.y, j + 5));
          float w6 = __int_as_float(__shfl(meta.y, j + 6));
          float w7 = __int_as_float(__shfl(meta.y, j + 7));
          a0 = fmaf(x[s0 * 64 + lane], w0, a0);
          a1 = fmaf(x[s1 * 64 + lane], w1, a1);
          a2 = fmaf(x[s2 * 64 + lane], w2, a2);
          a3 = fmaf(x[s3 * 64 + lane], w3, a3);
          a4 = fmaf(x[s4 * 64 + lane], w4, a4);
          a5 = fmaf(x[s5 * 64 + lane], w5, a5);
          a6 = fmaf(x[s6 * 64 + lane], w6, a6);
          a7 = fmaf(x[s7 * 64 + lane], w7, a7);
        }
        for (; j < take; ++j) {
          int s = __shfl(meta.x, j);
          float w = __int_as_float(__shfl(meta.y, j));
          a0 = fmaf(x[s * 64 + lane], w, a0);
        }
      }
      acc += ((a0 + a1) + (a2 + a3)) + ((a4 + a5) + (a6 + a7));
    }
    hT[lane][wv * 8 + i] = acc;
  }
  __syncthreads();

  // ---- GEMM1: o[n][f] = relu(b1[f] + sum_k hT[k][n] * WA[k][f]) ----
  int fg = tid & 15, ng = tid >> 4;
  int f0 = fg * 4, n0 = ng * 2;
  float4 bv = *(const float4*)(b1 + f0);
  float o[2][4];
#pragma unroll
  for (int n = 0; n < 2; ++n) {
    o[n][0] = bv.x; o[n][1] = bv.y; o[n][2] = bv.z; o[n][3] = bv.w;
  }
#pragma unroll 8
  for (int k = 0; k < 64; ++k) {
    float2 in2 = *(const float2*)&hT[k][n0];
    float4 w4 = *(const float4*)&WA[k][f0];
    float in[2] = {in2.x, in2.y};
    float ww[4] = {w4.x, w4.y, w4.z, w4.w};
#pragma unroll
    for (int n = 0; n < 2; ++n)
#pragma unroll
      for (int j = 0; j < 4; ++j) o[n][j] = fmaf(in[n], ww[j], o[n][j]);
  }
#pragma unroll
  for (int n = 0; n < 2; ++n)
#pragma unroll
    for (int j = 0; j < 4; ++j) o[n][j] = fmaxf(o[n][j], 0.f);

  __syncthreads();  // all GEMM1 reads of hT/WA done
  // write h1 (relu'd) back into hT; swap WA to W2t
#pragma unroll
  for (int j = 0; j < 4; ++j) {
    float2 v = {o[0][j], o[1][j]};
    *(float2*)&hT[f0 + j][n0] = v;
  }
  for (int i = tid; i < 4096; i += 256) ((float*)WA)[i] = W2t[i];
  __syncthreads();

  // ---- GEMM2: o2[n][f] = b2[f] + sum_k hT[k][n] * WA[k][f] ----
  float4 bv2 = *(const float4*)(b2 + f0);
  float o2[2][4];
#pragma unroll
  for (int n = 0; n < 2; ++n) {
    o2[n][0] = bv2.x; o2[n][1] = bv2.y; o2[n][2] = bv2.z; o2[n][3] = bv2.w;
  }
#pragma unroll 8
  for (int k = 0; k < 64; ++k) {
    float2 in2 = *(const float2*)&hT[k][n0];
    float4 w4 = *(const float4*)&WA[k][f0];
    float in[2] = {in2.x, in2.y};
    float ww[4] = {w4.x, w4.y, w4.z, w4.w};
#pragma unroll
    for (int n = 0; n < 2; ++n)
#pragma unroll
      for (int j = 0; j < 4; ++j) o2[n][j] = fmaf(in[n], ww[j], o2[n][j]);
  }
  __syncthreads();  // GEMM2 reads done; hT reusable as reduce scratch

  // ---- write h2 + BN partial sums ----
  float s[4] = {0.f, 0.f, 0.f, 0.f}, q[4] = {0.f, 0.f, 0.f, 0.f};
#pragma unroll
  for (int n = 0; n < 2; ++n) {
    int node = tile0 + n0 + n;
    if (node < NN) {
      float4 v = {o2[n][0], o2[n][1], o2[n][2], o2[n][3]};
      *(float4*)&out[node * 64 + f0] = v;
#pragma unroll
      for (int j = 0; j < 4; ++j) {
        s[j] += o2[n][j];
        q[j] = fmaf(o2[n][j], o2[n][j], q[j]);
      }
    }
  }
  float* red = &hT[0][0];  // 2048 floats needed, hT has 2176
#pragma unroll
  for (int j = 0; j < 4; ++j) {
    red[(f0 + j) * 16 + ng] = s[j];
    red[1024 + (f0 + j) * 16 + ng] = q[j];
  }
  __syncthreads();
  if (tid < 64) {
    float ss = 0.f, qq = 0.f;
    for (int g = 0; g < 16; ++g) {
      ss += red[tid * 16 + g];
      qq += red[1024 + tid * 16 + g];
    }
    atomicAdd(&sums[tid], ss);
    atomicAdd(&sums[64 + tid], qq);
  }
}

// ---------------- BN finalize + relu, in place on d_out ----------------
__global__ __launch_bounds__(256) void bn_k(float* __restrict__ h2out,
                                            const float* __restrict__ sums,
                                            const float* __restrict__ gamma,
                                            const float* __restrict__ beta) {
  __shared__ float sc[64], sh[64];
  int tid = threadIdx.x;
  if (tid < 64) {
    const float invN = 1.0f / NN;
    float mean = sums[tid] * invN;
    float var = fmaf(-mean, mean, sums[64 + tid] * invN);
    float s = gamma[tid] * rsqrtf(var + BN_EPS_C);
    sc[tid] = s;
    sh[tid] = fmaf(-mean, s, beta[tid]);
  }
  __syncthreads();
  int gid = blockIdx.x * 256 + tid;
  const int tot = NN * 16;
  float4* p = (float4*)h2out;
  for (int i = gid; i < tot; i += gridDim.x * 256) {
    int f0 = (i & 15) * 4;
    float4 v = p[i];
    v.x = fmaxf(fmaf(v.x, sc[f0 + 0], sh[f0 + 0]), 0.f);
    v.y = fmaxf(fmaf(v.y, sc[f0 + 1], sh[f0 + 1]), 0.f);
    v.z = fmaxf(fmaf(v.z, sc[f0 + 2], sh[f0 + 2]), 0.f);
    v.w = fmaxf(fmaf(v.w, sc[f0 + 3], sh[f0 + 3]), 0.f);
    p[i] = v;
  }
}

extern "C" void kernel_launch(void* const* d_in, const int* in_sizes, int n_in,
                              void* d_out, int out_size, void* d_ws, size_t ws_size,
                              hipStream_t stream) {
  const float* x     = (const float*)d_in[0];
  const int*   src   = (const int*)d_in[1];
  const int*   dst   = (const int*)d_in[2];
  const float* ew    = (const float*)d_in[3];
  const float* W1    = (const float*)d_in[4];
  const float* b1    = (const float*)d_in[5];
  const float* W2    = (const float*)d_in[6];
  const float* b2    = (const float*)d_in[7];
  const float* eps   = (const float*)d_in[8];
  const float* gamma = (const float*)d_in[9];
  const float* beta  = (const float*)d_in[10];
  int E = in_sizes[1];

  // ws: counts[NN] | offs[NN] | cursor[NN] | sorted[E] int2 | W1t[4096] | W2t[4096] | sums[128]
  int*   counts = (int*)d_ws;
  int*   offs   = counts + NN;
  int*   cursor = offs + NN;
  int2*  sorted = (int2*)(cursor + NN);
  float* W1t    = (float*)(sorted + E);
  float* W2t    = W1t + 4096;
  float* sums   = W2t + 4096;
  float* h2     = (float*)d_out;

  int eb4 = (E / 4 + 255) / 256;
  prep_k<<<64, 256, 0, stream>>>(W1, W2, counts, sums, W1t, W2t);
  hist_k<<<eb4, 256, 0, stream>>>(dst, counts, E);
  scan_k<<<1, 1024, 0, stream>>>(counts, offs, cursor);
  scatter_k<<<eb4, 256, 0, stream>>>(src, dst, ew, cursor, sorted, E);
  fuse_k<<<NB, 256, 0, stream>>>(x, sorted, offs, counts, W1t, W2t, b1, b2, eps, h2, sums);
  bn_k<<<3125, 256, 0, stream>>>(h2, sums, gamma, beta);
}

// Round 5
// 197.904 us; speedup vs baseline: 4.7683x; 1.5990x over previous
//
#include <hip/hip_runtime.h>

#define NN 50000
#define BN_EPS_C 1e-5f
#define TILE 32
#define NB ((NN + TILE - 1) / TILE)  // 1563
#define SCAN_CHUNK 512
#define NSB ((NN + SCAN_CHUNK - 1) / SCAN_CHUNK)  // 98

// ---------------- prep: zero counts/sums, transpose W1,W2 into ws ----------------
__global__ __launch_bounds__(256) void prep_k(const float* __restrict__ W1,
                                              const float* __restrict__ W2,
                                              int* __restrict__ counts,
                                              float* __restrict__ sums,
                                              float* __restrict__ W1t,
                                              float* __restrict__ W2t) {
  int gid = blockIdx.x * 256 + threadIdx.x;
  for (int i = gid; i < NN; i += gridDim.x * 256) counts[i] = 0;
  if (gid < 128) sums[gid] = 0.f;
  for (int i = gid; i < 4096; i += gridDim.x * 256) {
    int f = i >> 6, k = i & 63;
    W1t[k * 64 + f] = W1[i];  // Wt[k][f] = W[f][k]
    W2t[k * 64 + f] = W2[i];
  }
}

// ---------------- histogram of dst (4 edges/thread) ----------------
__global__ __launch_bounds__(256) void hist_k(const int* __restrict__ dst,
                                              int* __restrict__ counts, int E) {
  int t = blockIdx.x * 256 + threadIdx.x;
  int e = t * 4;
  if (e + 3 < E) {
    int4 d = *(const int4*)(dst + e);
    atomicAdd(&counts[d.x], 1);
    atomicAdd(&counts[d.y], 1);
    atomicAdd(&counts[d.z], 1);
    atomicAdd(&counts[d.w], 1);
  } else {
    for (; e < E; ++e) atomicAdd(&counts[dst[e]], 1);
  }
}

// ---------------- two-level scan: A) block sums ----------------
__global__ __launch_bounds__(256) void scana_k(const int* __restrict__ counts,
                                               int* __restrict__ bsum) {
  __shared__ int red[256];
  int b = blockIdx.x, tid = threadIdx.x;
  int i0 = b * SCAN_CHUNK + tid;
  int v = 0;
  if (i0 < NN) v += counts[i0];
  if (i0 + 256 < NN && tid + 256 < SCAN_CHUNK) v += counts[i0 + 256];
  red[tid] = v;
  __syncthreads();
  for (int s = 128; s > 0; s >>= 1) {
    if (tid < s) red[tid] += red[tid + s];
    __syncthreads();
  }
  if (tid == 0) bsum[b] = red[0];
}

// ---------------- B) exclusive scan of NSB partials (1 block) ----------------
__global__ __launch_bounds__(128) void scanb_k(int* __restrict__ bsum) {
  __shared__ int s[128];
  int tid = threadIdx.x;
  int v = (tid < NSB) ? bsum[tid] : 0;
  s[tid] = v;
  __syncthreads();
  for (int off = 1; off < 128; off <<= 1) {
    int t = (tid >= off) ? s[tid - off] : 0;
    __syncthreads();
    s[tid] += t;
    __syncthreads();
  }
  if (tid < NSB) bsum[tid] = s[tid] - v;  // exclusive
}

// ---------------- C) local exclusive scan + base -> offs/cursor ----------------
__global__ __launch_bounds__(256) void scanc_k(const int* __restrict__ counts,
                                               const int* __restrict__ bsum,
                                               int* __restrict__ offs,
                                               int* __restrict__ cursor) {
  __shared__ int s[256];
  int b = blockIdx.x, tid = threadIdx.x;
  int i0 = b * SCAN_CHUNK + 2 * tid;
  int c0 = (i0 < NN) ? counts[i0] : 0;
  int c1 = (i0 + 1 < NN) ? counts[i0 + 1] : 0;
  int tsum = c0 + c1;
  s[tid] = tsum;
  __syncthreads();
  for (int off = 1; off < 256; off <<= 1) {
    int t = (tid >= off) ? s[tid - off] : 0;
    __syncthreads();
    s[tid] += t;
    __syncthreads();
  }
  int pre = bsum[b] + s[tid] - tsum;
  if (i0 < NN) { offs[i0] = pre; cursor[i0] = pre; }
  if (i0 + 1 < NN) { offs[i0 + 1] = pre + c0; cursor[i0 + 1] = pre + c0; }
}

// ---------------- scatter edges into dst-sorted order (4 edges/thread) --------
__global__ __launch_bounds__(256) void scatter_k(const int* __restrict__ src,
                                                 const int* __restrict__ dst,
                                                 const float* __restrict__ ew,
                                                 int* __restrict__ cursor,
                                                 int2* __restrict__ sorted, int E) {
  int t = blockIdx.x * 256 + threadIdx.x;
  int e = t * 4;
  if (e + 3 < E) {
    int4 s = *(const int4*)(src + e);
    int4 d = *(const int4*)(dst + e);
    float4 w = *(const float4*)(ew + e);
    int p0 = atomicAdd(&cursor[d.x], 1);
    int p1 = atomicAdd(&cursor[d.y], 1);
    int p2 = atomicAdd(&cursor[d.z], 1);
    int p3 = atomicAdd(&cursor[d.w], 1);
    sorted[p0] = make_int2(s.x, __float_as_int(w.x));
    sorted[p1] = make_int2(s.y, __float_as_int(w.y));
    sorted[p2] = make_int2(s.z, __float_as_int(w.z));
    sorted[p3] = make_int2(s.w, __float_as_int(w.w));
  } else {
    for (; e < E; ++e) {
      int pos = atomicAdd(&cursor[dst[e]], 1);
      sorted[pos] = make_int2(src[e], __float_as_int(ew[e]));
    }
  }
}

// ---------------- fused: gather + residual + MLP1(relu) + MLP2 + BN partials ----
// Gather lanes: es = lane>>4 (edge slot), fq = lane&15 (feature quad).
// One float4 load fetches 4 edge rows per wave instr; 2 nodes interleaved
// -> 4 independent load streams. Padding edges carry w=0 (no tails).
__global__ __launch_bounds__(256) void fuse_k(const float* __restrict__ x,
                                              const int2* __restrict__ sorted,
                                              const int* __restrict__ offs,
                                              const int* __restrict__ counts,
                                              const float* __restrict__ W1t,
                                              const float* __restrict__ W2t,
                                              const float* __restrict__ b1,
                                              const float* __restrict__ b2,
                                              const float* __restrict__ eps,
                                              float* __restrict__ out,
                                              float* __restrict__ sums) {
  __shared__ float hT[64][34];   // [k][local node]
  __shared__ float WA[64][64];   // W1t, then reused for W2t
  int tid = threadIdx.x;
  int lane = tid & 63;
  int wv = tid >> 6;
  int es = lane >> 4, fq = lane & 15;
  int tile0 = blockIdx.x * TILE;

  for (int i = tid; i < 4096; i += 256) ((float*)WA)[i] = W1t[i];

  const float c1 = 1.0f + eps[0];
  const float4* x4 = (const float4*)x;

  // ---- gather: 8 nodes per wave as 4 interleaved pairs ----
  for (int p = 0; p < 4; ++p) {
    int nA = tile0 + wv * 8 + 2 * p;
    int nB = nA + 1;
    bool vA = nA < NN, vB = nB < NN;
    int offA = vA ? offs[nA] : 0, cntA = vA ? counts[nA] : 0;
    int offB = vB ? offs[nB] : 0, cntB = vB ? counts[nB] : 0;
    float rA = vA ? c1 * x[nA * 64 + 4 * fq + es] : 0.f;
    float rB = vB ? c1 * x[nB * 64 + 4 * fq + es] : 0.f;
    int tkA = min(cntA, 64), tkB = min(cntB, 64);
    int2 mA = make_int2(0, 0), mB = make_int2(0, 0);
    if (lane < tkA) mA = sorted[offA + lane];
    if (lane < tkB) mB = sorted[offB + lane];
    float4 aA0 = {0, 0, 0, 0}, aA1 = {0, 0, 0, 0};
    float4 aB0 = {0, 0, 0, 0}, aB1 = {0, 0, 0, 0};
    int nbA = (tkA + 3) >> 2, nbB = (tkB + 3) >> 2;
    int nbM = max(nbA, nbB);
    for (int t = 0; t < nbM; t += 2) {
      int i0 = t * 4 + es, i1 = i0 + 4;  // both <= 63 (nbM <= 16, t even)
      int sA0 = __shfl(mA.x, i0), sB0 = __shfl(mB.x, i0);
      int sA1 = __shfl(mA.x, i1), sB1 = __shfl(mB.x, i1);
      float wA0 = __int_as_float(__shfl(mA.y, i0));
      float wB0 = __int_as_float(__shfl(mB.y, i0));
      float wA1 = __int_as_float(__shfl(mA.y, i1));
      float wB1 = __int_as_float(__shfl(mB.y, i1));
      float4 vA0 = x4[sA0 * 16 + fq];
      float4 vB0 = x4[sB0 * 16 + fq];
      float4 vA1 = x4[sA1 * 16 + fq];
      float4 vB1 = x4[sB1 * 16 + fq];
      aA0.x = fmaf(wA0, vA0.x, aA0.x); aA0.y = fmaf(wA0, vA0.y, aA0.y);
      aA0.z = fmaf(wA0, vA0.z, aA0.z); aA0.w = fmaf(wA0, vA0.w, aA0.w);
      aB0.x = fmaf(wB0, vB0.x, aB0.x); aB0.y = fmaf(wB0, vB0.y, aB0.y);
      aB0.z = fmaf(wB0, vB0.z, aB0.z); aB0.w = fmaf(wB0, vB0.w, aB0.w);
      aA1.x = fmaf(wA1, vA1.x, aA1.x); aA1.y = fmaf(wA1, vA1.y, aA1.y);
      aA1.z = fmaf(wA1, vA1.z, aA1.z); aA1.w = fmaf(wA1, vA1.w, aA1.w);
      aB1.x = fmaf(wB1, vB1.x, aB1.x); aB1.y = fmaf(wB1, vB1.y, aB1.y);
      aB1.z = fmaf(wB1, vB1.z, aB1.z); aB1.w = fmaf(wB1, vB1.w, aB1.w);
    }
    // rare overflow (cnt > 64)
    for (int b = 64; b < cntA; b += 64) {
      int take = min(64, cntA - b);
      int2 m = make_int2(0, 0);
      if (lane < take) m = sorted[offA + b + lane];
      int nb = (take + 3) >> 2;
      for (int t = 0; t < nb; ++t) {
        int i0 = t * 4 + es;
        int s0 = __shfl(m.x, i0);
        float w0 = __int_as_float(__shfl(m.y, i0));
        float4 v0 = x4[s0 * 16 + fq];
        aA0.x = fmaf(w0, v0.x, aA0.x); aA0.y = fmaf(w0, v0.y, aA0.y);
        aA0.z = fmaf(w0, v0.z, aA0.z); aA0.w = fmaf(w0, v0.w, aA0.w);
      }
    }
    for (int b = 64; b < cntB; b += 64) {
      int take = min(64, cntB - b);
      int2 m = make_int2(0, 0);
      if (lane < take) m = sorted[offB + b + lane];
      int nb = (take + 3) >> 2;
      for (int t = 0; t < nb; ++t) {
        int i0 = t * 4 + es;
        int s0 = __shfl(m.x, i0);
        float w0 = __int_as_float(__shfl(m.y, i0));
        float4 v0 = x4[s0 * 16 + fq];
        aB0.x = fmaf(w0, v0.x, aB0.x); aB0.y = fmaf(w0, v0.y, aB0.y);
        aB0.z = fmaf(w0, v0.z, aB0.z); aB0.w = fmaf(w0, v0.w, aB0.w);
      }
    }
    float4 aA = {aA0.x + aA1.x, aA0.y + aA1.y, aA0.z + aA1.z, aA0.w + aA1.w};
    float4 aB = {aB0.x + aB1.x, aB0.y + aB1.y, aB0.z + aB1.z, aB0.w + aB1.w};
    // reduce across es groups (lane bits 4,5)
    aA.x += __shfl_xor(aA.x, 16); aA.x += __shfl_xor(aA.x, 32);
    aA.y += __shfl_xor(aA.y, 16); aA.y += __shfl_xor(aA.y, 32);
    aA.z += __shfl_xor(aA.z, 16); aA.z += __shfl_xor(aA.z, 32);
    aA.w += __shfl_xor(aA.w, 16); aA.w += __shfl_xor(aA.w, 32);
    aB.x += __shfl_xor(aB.x, 16); aB.x += __shfl_xor(aB.x, 32);
    aB.y += __shfl_xor(aB.y, 16); aB.y += __shfl_xor(aB.y, 32);
    aB.z += __shfl_xor(aB.z, 16); aB.z += __shfl_xor(aB.z, 32);
    aB.w += __shfl_xor(aB.w, 16); aB.w += __shfl_xor(aB.w, 32);
    float sA = (es == 0) ? aA.x : (es == 1) ? aA.y : (es == 2) ? aA.z : aA.w;
    float sB = (es == 0) ? aB.x : (es == 1) ? aB.y : (es == 2) ? aB.z : aB.w;
    hT[4 * fq + es][wv * 8 + 2 * p] = rA + sA;
    hT[4 * fq + es][wv * 8 + 2 * p + 1] = rB + sB;
  }
  __syncthreads();

  // ---- GEMM1: o[n][f] = relu(b1[f] + sum_k hT[k][n] * WA[k][f]) ----
  int fg = tid & 15, ng = tid >> 4;
  int f0 = fg * 4, n0 = ng * 2;
  float4 bv = *(const float4*)(b1 + f0);
  float o[2][4];
#pragma unroll
  for (int n = 0; n < 2; ++n) {
    o[n][0] = bv.x; o[n][1] = bv.y; o[n][2] = bv.z; o[n][3] = bv.w;
  }
#pragma unroll 8
  for (int k = 0; k < 64; ++k) {
    float2 in2 = *(const float2*)&hT[k][n0];
    float4 w4 = *(const float4*)&WA[k][f0];
    float in[2] = {in2.x, in2.y};
    float ww[4] = {w4.x, w4.y, w4.z, w4.w};
#pragma unroll
    for (int n = 0; n < 2; ++n)
#pragma unroll
      for (int j = 0; j < 4; ++j) o[n][j] = fmaf(in[n], ww[j], o[n][j]);
  }
#pragma unroll
  for (int n = 0; n < 2; ++n)
#pragma unroll
    for (int j = 0; j < 4; ++j) o[n][j] = fmaxf(o[n][j], 0.f);

  __syncthreads();  // all GEMM1 reads of hT/WA done
  // write h1 (relu'd) back into hT; swap WA to W2t
#pragma unroll
  for (int j = 0; j < 4; ++j) {
    float2 v = {o[0][j], o[1][j]};
    *(float2*)&hT[f0 + j][n0] = v;
  }
  for (int i = tid; i < 4096; i += 256) ((float*)WA)[i] = W2t[i];
  __syncthreads();

  // ---- GEMM2: o2[n][f] = b2[f] + sum_k hT[k][n] * WA[k][f] ----
  float4 bv2 = *(const float4*)(b2 + f0);
  float o2[2][4];
#pragma unroll
  for (int n = 0; n < 2; ++n) {
    o2[n][0] = bv2.x; o2[n][1] = bv2.y; o2[n][2] = bv2.z; o2[n][3] = bv2.w;
  }
#pragma unroll 8
  for (int k = 0; k < 64; ++k) {
    float2 in2 = *(const float2*)&hT[k][n0];
    float4 w4 = *(const float4*)&WA[k][f0];
    float in[2] = {in2.x, in2.y};
    float ww[4] = {w4.x, w4.y, w4.z, w4.w};
#pragma unroll
    for (int n = 0; n < 2; ++n)
#pragma unroll
      for (int j = 0; j < 4; ++j) o2[n][j] = fmaf(in[n], ww[j], o2[n][j]);
  }
  __syncthreads();  // GEMM2 reads done; hT reusable as reduce scratch

  // ---- write h2 + BN partial sums ----
  float s[4] = {0.f, 0.f, 0.f, 0.f}, q[4] = {0.f, 0.f, 0.f, 0.f};
#pragma unroll
  for (int n = 0; n < 2; ++n) {
    int node = tile0 + n0 + n;
    if (node < NN) {
      float4 v = {o2[n][0], o2[n][1], o2[n][2], o2[n][3]};
      *(float4*)&out[node * 64 + f0] = v;
#pragma unroll
      for (int j = 0; j < 4; ++j) {
        s[j] += o2[n][j];
        q[j] = fmaf(o2[n][j], o2[n][j], q[j]);
      }
    }
  }
  float* red = &hT[0][0];  // 2048 floats needed, hT has 2176
#pragma unroll
  for (int j = 0; j < 4; ++j) {
    red[(f0 + j) * 16 + ng] = s[j];
    red[1024 + (f0 + j) * 16 + ng] = q[j];
  }
  __syncthreads();
  if (tid < 64) {
    float ss = 0.f, qq = 0.f;
    for (int g = 0; g < 16; ++g) {
      ss += red[tid * 16 + g];
      qq += red[1024 + tid * 16 + g];
    }
    atomicAdd(&sums[tid], ss);
    atomicAdd(&sums[64 + tid], qq);
  }
}

// ---------------- BN finalize + relu, in place on d_out ----------------
__global__ __launch_bounds__(256) void bn_k(float* __restrict__ h2out,
                                            const float* __restrict__ sums,
                                            const float* __restrict__ gamma,
                                            const float* __restrict__ beta) {
  __shared__ float sc[64], sh[64];
  int tid = threadIdx.x;
  if (tid < 64) {
    const float invN = 1.0f / NN;
    float mean = sums[tid] * invN;
    float var = fmaf(-mean, mean, sums[64 + tid] * invN);
    float s = gamma[tid] * rsqrtf(var + BN_EPS_C);
    sc[tid] = s;
    sh[tid] = fmaf(-mean, s, beta[tid]);
  }
  __syncthreads();
  int gid = blockIdx.x * 256 + tid;
  const int tot = NN * 16;
  float4* p = (float4*)h2out;
  for (int i = gid; i < tot; i += gridDim.x * 256) {
    int f0 = (i & 15) * 4;
    float4 v = p[i];
    v.x = fmaxf(fmaf(v.x, sc[f0 + 0], sh[f0 + 0]), 0.f);
    v.y = fmaxf(fmaf(v.y, sc[f0 + 1], sh[f0 + 1]), 0.f);
    v.z = fmaxf(fmaf(v.z, sc[f0 + 2], sh[f0 + 2]), 0.f);
    v.w = fmaxf(fmaf(v.w, sc[f0 + 3], sh[f0 + 3]), 0.f);
    p[i] = v;
  }
}

extern "C" void kernel_launch(void* const* d_in, const int* in_sizes, int n_in,
                              void* d_out, int out_size, void* d_ws, size_t ws_size,
                              hipStream_t stream) {
  const float* x     = (const float*)d_in[0];
  const int*   src   = (const int*)d_in[1];
  const int*   dst   = (const int*)d_in[2];
  const float* ew    = (const float*)d_in[3];
  const float* W1    = (const float*)d_in[4];
  const float* b1    = (const float*)d_in[5];
  const float* W2    = (const float*)d_in[6];
  const float* b2    = (const float*)d_in[7];
  const float* eps   = (const float*)d_in[8];
  const float* gamma = (const float*)d_in[9];
  const float* beta  = (const float*)d_in[10];
  int E = in_sizes[1];

  // ws: counts[NN] | offs[NN] | cursor[NN] | sorted[E] int2 | W1t[4096] | W2t[4096] | sums[128] | bsum[NSB]
  int*   counts = (int*)d_ws;
  int*   offs   = counts + NN;
  int*   cursor = offs + NN;
  int2*  sorted = (int2*)(cursor + NN);
  float* W1t    = (float*)(sorted + E);
  float* W2t    = W1t + 4096;
  float* sums   = W2t + 4096;
  int*   bsum   = (int*)(sums + 128);
  float* h2     = (float*)d_out;

  int eb4 = (E / 4 + 255) / 256;
  prep_k<<<64, 256, 0, stream>>>(W1, W2, counts, sums, W1t, W2t);
  hist_k<<<eb4, 256, 0, stream>>>(dst, counts, E);
  scana_k<<<NSB, 256, 0, stream>>>(counts, bsum);
  scanb_k<<<1, 128, 0, stream>>>(bsum);
  scanc_k<<<NSB, 256, 0, stream>>>(counts, bsum, offs, cursor);
  scatter_k<<<eb4, 256, 0, stream>>>(src, dst, ew, cursor, sorted, E);
  fuse_k<<<NB, 256, 0, stream>>>(x, sorted, offs, counts, W1t, W2t, b1, b2, eps, h2, sums);
  bn_k<<<3125, 256, 0, stream>>>(h2, sums, gamma, beta);
}

// Round 6
// 178.805 us; speedup vs baseline: 5.2776x; 1.1068x over previous
//
#include <hip/hip_runtime.h>

#define NN 50000
#define BN_EPS_C 1e-5f
#define SCAN_CHUNK 512
#define NSB ((NN + SCAN_CHUNK - 1) / SCAN_CHUNK)  // 98

// ---------------- prep: zero counts/sums, transpose W1,W2 into ws ----------------
__global__ __launch_bounds__(256) void prep_k(const float* __restrict__ W1,
                                              const float* __restrict__ W2,
                                              int* __restrict__ counts,
                                              float* __restrict__ sums,
                                              float* __restrict__ W1t,
                                              float* __restrict__ W2t) {
  int gid = blockIdx.x * 256 + threadIdx.x;
  for (int i = gid; i < NN; i += gridDim.x * 256) counts[i] = 0;
  if (gid < 128) sums[gid] = 0.f;
  for (int i = gid; i < 4096; i += gridDim.x * 256) {
    int f = i >> 6, k = i & 63;
    W1t[k * 64 + f] = W1[i];  // Wt[k][f] = W[f][k]
    W2t[k * 64 + f] = W2[i];
  }
}

// ---------------- histogram of dst (4 edges/thread) ----------------
__global__ __launch_bounds__(256) void hist_k(const int* __restrict__ dst,
                                              int* __restrict__ counts, int E) {
  int t = blockIdx.x * 256 + threadIdx.x;
  int e = t * 4;
  if (e + 3 < E) {
    int4 d = *(const int4*)(dst + e);
    atomicAdd(&counts[d.x], 1);
    atomicAdd(&counts[d.y], 1);
    atomicAdd(&counts[d.z], 1);
    atomicAdd(&counts[d.w], 1);
  } else {
    for (; e < E; ++e) atomicAdd(&counts[dst[e]], 1);
  }
}

// ---------------- two-level scan: A) block sums ----------------
__global__ __launch_bounds__(256) void scana_k(const int* __restrict__ counts,
                                               int* __restrict__ bsum) {
  __shared__ int red[256];
  int b = blockIdx.x, tid = threadIdx.x;
  int i0 = b * SCAN_CHUNK + tid;
  int v = 0;
  if (i0 < NN) v += counts[i0];
  if (i0 + 256 < NN && tid + 256 < SCAN_CHUNK) v += counts[i0 + 256];
  red[tid] = v;
  __syncthreads();
  for (int s = 128; s > 0; s >>= 1) {
    if (tid < s) red[tid] += red[tid + s];
    __syncthreads();
  }
  if (tid == 0) bsum[b] = red[0];
}

// ---------------- B+C fused: per-block base reduce + local scan -> offs/cursor --
__global__ __launch_bounds__(256) void scanc_k(const int* __restrict__ counts,
                                               const int* __restrict__ bsum,
                                               int* __restrict__ offs,
                                               int* __restrict__ cursor) {
  __shared__ int s[256];
  __shared__ int basev;
  int b = blockIdx.x, tid = threadIdx.x;
  // base = sum_{j<b} bsum[j]  (NSB=98 <= 256)
  s[tid] = (tid < b) ? bsum[tid] : 0;
  __syncthreads();
  for (int st = 128; st > 0; st >>= 1) {
    if (tid < st) s[tid] += s[tid + st];
    __syncthreads();
  }
  if (tid == 0) basev = s[0];
  __syncthreads();
  int base = basev;
  __syncthreads();  // everyone read basev; s reusable
  int i0 = b * SCAN_CHUNK + 2 * tid;
  int c0 = (i0 < NN) ? counts[i0] : 0;
  int c1 = (i0 + 1 < NN) ? counts[i0 + 1] : 0;
  int tsum = c0 + c1;
  s[tid] = tsum;
  __syncthreads();
  for (int off = 1; off < 256; off <<= 1) {
    int t = (tid >= off) ? s[tid - off] : 0;
    __syncthreads();
    s[tid] += t;
    __syncthreads();
  }
  int pre = base + s[tid] - tsum;
  if (i0 < NN) { offs[i0] = pre; cursor[i0] = pre; }
  if (i0 + 1 < NN) { offs[i0 + 1] = pre + c0; cursor[i0 + 1] = pre + c0; }
}

// ---------------- scatter edges into dst-sorted order (4 edges/thread) --------
__global__ __launch_bounds__(256) void scatter_k(const int* __restrict__ src,
                                                 const int* __restrict__ dst,
                                                 const float* __restrict__ ew,
                                                 int* __restrict__ cursor,
                                                 int2* __restrict__ sorted, int E) {
  int t = blockIdx.x * 256 + threadIdx.x;
  int e = t * 4;
  if (e + 3 < E) {
    int4 s = *(const int4*)(src + e);
    int4 d = *(const int4*)(dst + e);
    float4 w = *(const float4*)(ew + e);
    int p0 = atomicAdd(&cursor[d.x], 1);
    int p1 = atomicAdd(&cursor[d.y], 1);
    int p2 = atomicAdd(&cursor[d.z], 1);
    int p3 = atomicAdd(&cursor[d.w], 1);
    sorted[p0] = make_int2(s.x, __float_as_int(w.x));
    sorted[p1] = make_int2(s.y, __float_as_int(w.y));
    sorted[p2] = make_int2(s.z, __float_as_int(w.z));
    sorted[p3] = make_int2(s.w, __float_as_int(w.w));
  } else {
    for (; e < E; ++e) {
      int pos = atomicAdd(&cursor[dst[e]], 1);
      sorted[pos] = make_int2(src[e], __float_as_int(ew[e]));
    }
  }
}

// ---------------- overflow helper (deg > 64, rare) ----------------
__device__ inline void ovf_add(const float4* __restrict__ x4,
                               const int2* __restrict__ sorted, int off, int cnt,
                               int lane, int es, int fq, float4& acc) {
  for (int b = 64; b < cnt; b += 64) {
    int take = min(64, cnt - b);
    int2 m = make_int2(0, 0);
    if (lane < take) m = sorted[off + b + lane];
    int nb = (take + 3) >> 2;
    for (int t = 0; t < nb; ++t) {
      int i0 = t * 4 + es;
      int s = __shfl(m.x, i0);
      float w = __int_as_float(__shfl(m.y, i0));
      float4 v = x4[s * 16 + fq];
      acc.x = fmaf(w, v.x, acc.x); acc.y = fmaf(w, v.y, acc.y);
      acc.z = fmaf(w, v.z, acc.z); acc.w = fmaf(w, v.w, acc.w);
    }
  }
}

// ---------------- gather: y[n] = (1+eps)*x[n] + sum_e w_e * x[src_e] ----------
// No LDS -> high occupancy. Wave handles 4 nodes; es=lane>>4 picks edge slot,
// fq=lane&15 picks feature quad. 8 independent float4 streams per iteration.
__global__ __launch_bounds__(256, 6) void gather_k(const float* __restrict__ x,
                                                   const int2* __restrict__ sorted,
                                                   const int* __restrict__ offs,
                                                   const int* __restrict__ counts,
                                                   const float* __restrict__ eps,
                                                   float* __restrict__ y) {
  int tid = threadIdx.x;
  int lane = tid & 63;
  int wv = tid >> 6;
  int es = lane >> 4, fq = lane & 15;
  int nbase = (blockIdx.x * 4 + wv) * 4;
  if (nbase >= NN) return;
  const float c1 = 1.0f + eps[0];
  const float4* x4 = (const float4*)x;
  float4* y4 = (float4*)y;

  bool v1 = nbase + 1 < NN, v2 = nbase + 2 < NN, v3 = nbase + 3 < NN;
  int off0 = offs[nbase],            cnt0 = counts[nbase];
  int off1 = v1 ? offs[nbase + 1] : 0, cnt1 = v1 ? counts[nbase + 1] : 0;
  int off2 = v2 ? offs[nbase + 2] : 0, cnt2 = v2 ? counts[nbase + 2] : 0;
  int off3 = v3 ? offs[nbase + 3] : 0, cnt3 = v3 ? counts[nbase + 3] : 0;
  int tk0 = min(cnt0, 64), tk1 = min(cnt1, 64);
  int tk2 = min(cnt2, 64), tk3 = min(cnt3, 64);
  int2 m0 = make_int2(0, 0), m1 = make_int2(0, 0);
  int2 m2 = make_int2(0, 0), m3 = make_int2(0, 0);
  if (lane < tk0) m0 = sorted[off0 + lane];
  if (lane < tk1) m1 = sorted[off1 + lane];
  if (lane < tk2) m2 = sorted[off2 + lane];
  if (lane < tk3) m3 = sorted[off3 + lane];
  float4 a0 = {0, 0, 0, 0}, a1 = {0, 0, 0, 0};
  float4 a2 = {0, 0, 0, 0}, a3 = {0, 0, 0, 0};
  int nb0 = (tk0 + 3) >> 2, nb1 = (tk1 + 3) >> 2;
  int nb2 = (tk2 + 3) >> 2, nb3 = (tk3 + 3) >> 2;
  int nbM = max(max(nb0, nb1), max(nb2, nb3));
  for (int t = 0; t < nbM; t += 2) {
    int i0 = t * 4 + es, i1 = i0 + 4;  // i1 <= 63 since t <= 14
    int s00 = __shfl(m0.x, i0), s01 = __shfl(m0.x, i1);
    int s10 = __shfl(m1.x, i0), s11 = __shfl(m1.x, i1);
    int s20 = __shfl(m2.x, i0), s21 = __shfl(m2.x, i1);
    int s30 = __shfl(m3.x, i0), s31 = __shfl(m3.x, i1);
    float w00 = __int_as_float(__shfl(m0.y, i0)), w01 = __int_as_float(__shfl(m0.y, i1));
    float w10 = __int_as_float(__shfl(m1.y, i0)), w11 = __int_as_float(__shfl(m1.y, i1));
    float w20 = __int_as_float(__shfl(m2.y, i0)), w21 = __int_as_float(__shfl(m2.y, i1));
    float w30 = __int_as_float(__shfl(m3.y, i0)), w31 = __int_as_float(__shfl(m3.y, i1));
    float4 q00 = x4[s00 * 16 + fq], q01 = x4[s01 * 16 + fq];
    float4 q10 = x4[s10 * 16 + fq], q11 = x4[s11 * 16 + fq];
    float4 q20 = x4[s20 * 16 + fq], q21 = x4[s21 * 16 + fq];
    float4 q30 = x4[s30 * 16 + fq], q31 = x4[s31 * 16 + fq];
    a0.x = fmaf(w00, q00.x, a0.x); a0.y = fmaf(w00, q00.y, a0.y);
    a0.z = fmaf(w00, q00.z, a0.z); a0.w = fmaf(w00, q00.w, a0.w);
    a1.x = fmaf(w10, q10.x, a1.x); a1.y = fmaf(w10, q10.y, a1.y);
    a1.z = fmaf(w10, q10.z, a1.z); a1.w = fmaf(w10, q10.w, a1.w);
    a2.x = fmaf(w20, q20.x, a2.x); a2.y = fmaf(w20, q20.y, a2.y);
    a2.z = fmaf(w20, q20.z, a2.z); a2.w = fmaf(w20, q20.w, a2.w);
    a3.x = fmaf(w30, q30.x, a3.x); a3.y = fmaf(w30, q30.y, a3.y);
    a3.z = fmaf(w30, q30.z, a3.z); a3.w = fmaf(w30, q30.w, a3.w);
    a0.x = fmaf(w01, q01.x, a0.x); a0.y = fmaf(w01, q01.y, a0.y);
    a0.z = fmaf(w01, q01.z, a0.z); a0.w = fmaf(w01, q01.w, a0.w);
    a1.x = fmaf(w11, q11.x, a1.x); a1.y = fmaf(w11, q11.y, a1.y);
    a1.z = fmaf(w11, q11.z, a1.z); a1.w = fmaf(w11, q11.w, a1.w);
    a2.x = fmaf(w21, q21.x, a2.x); a2.y = fmaf(w21, q21.y, a2.y);
    a2.z = fmaf(w21, q21.z, a2.z); a2.w = fmaf(w21, q21.w, a2.w);
    a3.x = fmaf(w31, q31.x, a3.x); a3.y = fmaf(w31, q31.y, a3.y);
    a3.z = fmaf(w31, q31.z, a3.z); a3.w = fmaf(w31, q31.w, a3.w);
  }
  if (cnt0 > 64) ovf_add(x4, sorted, off0, cnt0, lane, es, fq, a0);
  if (cnt1 > 64) ovf_add(x4, sorted, off1, cnt1, lane, es, fq, a1);
  if (cnt2 > 64) ovf_add(x4, sorted, off2, cnt2, lane, es, fq, a2);
  if (cnt3 > 64) ovf_add(x4, sorted, off3, cnt3, lane, es, fq, a3);
  // reduce across es groups (lane bits 4,5)
#define RED4(a)                                     \
  a.x += __shfl_xor(a.x, 16); a.x += __shfl_xor(a.x, 32); \
  a.y += __shfl_xor(a.y, 16); a.y += __shfl_xor(a.y, 32); \
  a.z += __shfl_xor(a.z, 16); a.z += __shfl_xor(a.z, 32); \
  a.w += __shfl_xor(a.w, 16); a.w += __shfl_xor(a.w, 32);
  RED4(a0) RED4(a1) RED4(a2) RED4(a3)
#undef RED4
  // es group c stores node nbase+c -> fully coalesced 1KB store per wave
  int nst = nbase + es;
  if (nst < NN) {
    float4 r = (es == 0) ? a0 : (es == 1) ? a1 : (es == 2) ? a2 : a3;
    float4 xv = x4[nst * 16 + fq];
    r.x = fmaf(c1, xv.x, r.x); r.y = fmaf(c1, xv.y, r.y);
    r.z = fmaf(c1, xv.z, r.z); r.w = fmaf(c1, xv.w, r.w);
    y4[nst * 16 + fq] = r;
  }
}

// ---------------- MLP1(relu) + MLP2 + BN partials from y ----------------
// 64-node tile, 256 threads; 16fg x 16ng grid, 4-node x 4-feat register tile.
__global__ __launch_bounds__(256) void mlp_k(const float* __restrict__ y,
                                             const float* __restrict__ W1t,
                                             const float* __restrict__ W2t,
                                             const float* __restrict__ b1,
                                             const float* __restrict__ b2,
                                             float* __restrict__ out,
                                             float* __restrict__ sums) {
  __shared__ float hT[64][66];   // [k][local node]
  __shared__ float WA[64][64];
  int tid = threadIdx.x;
  int tile0 = blockIdx.x * 64;
  for (int i = tid; i < 4096; i += 256) ((float*)WA)[i] = W1t[i];
  const float4* y4 = (const float4*)y;
  for (int i = tid; i < 1024; i += 256) {
    int nl = i >> 4, fq = i & 15;
    int node = tile0 + nl;
    float4 v = {0, 0, 0, 0};
    if (node < NN) v = y4[node * 16 + fq];
    hT[4 * fq + 0][nl] = v.x; hT[4 * fq + 1][nl] = v.y;
    hT[4 * fq + 2][nl] = v.z; hT[4 * fq + 3][nl] = v.w;
  }
  __syncthreads();

  int fg = tid & 15, ng = tid >> 4;
  int f0 = fg * 4, n0 = ng * 4;
  float4 bv = *(const float4*)(b1 + f0);
  float o[4][4];
#pragma unroll
  for (int n = 0; n < 4; ++n) {
    o[n][0] = bv.x; o[n][1] = bv.y; o[n][2] = bv.z; o[n][3] = bv.w;
  }
#pragma unroll 8
  for (int k = 0; k < 64; ++k) {
    float2 iA = *(const float2*)&hT[k][n0];
    float2 iB = *(const float2*)&hT[k][n0 + 2];
    float4 w4 = *(const float4*)&WA[k][f0];
    float in[4] = {iA.x, iA.y, iB.x, iB.y};
    float ww[4] = {w4.x, w4.y, w4.z, w4.w};
#pragma unroll
    for (int n = 0; n < 4; ++n)
#pragma unroll
      for (int j = 0; j < 4; ++j) o[n][j] = fmaf(in[n], ww[j], o[n][j]);
  }
#pragma unroll
  for (int n = 0; n < 4; ++n)
#pragma unroll
    for (int j = 0; j < 4; ++j) o[n][j] = fmaxf(o[n][j], 0.f);

  __syncthreads();  // all GEMM1 reads done
#pragma unroll
  for (int j = 0; j < 4; ++j) {
    float2 vA = {o[0][j], o[1][j]}, vB = {o[2][j], o[3][j]};
    *(float2*)&hT[f0 + j][n0] = vA;
    *(float2*)&hT[f0 + j][n0 + 2] = vB;
  }
  for (int i = tid; i < 4096; i += 256) ((float*)WA)[i] = W2t[i];
  __syncthreads();

  float4 bv2 = *(const float4*)(b2 + f0);
  float o2[4][4];
#pragma unroll
  for (int n = 0; n < 4; ++n) {
    o2[n][0] = bv2.x; o2[n][1] = bv2.y; o2[n][2] = bv2.z; o2[n][3] = bv2.w;
  }
#pragma unroll 8
  for (int k = 0; k < 64; ++k) {
    float2 iA = *(const float2*)&hT[k][n0];
    float2 iB = *(const float2*)&hT[k][n0 + 2];
    float4 w4 = *(const float4*)&WA[k][f0];
    float in[4] = {iA.x, iA.y, iB.x, iB.y};
    float ww[4] = {w4.x, w4.y, w4.z, w4.w};
#pragma unroll
    for (int n = 0; n < 4; ++n)
#pragma unroll
      for (int j = 0; j < 4; ++j) o2[n][j] = fmaf(in[n], ww[j], o2[n][j]);
  }
  __syncthreads();  // GEMM2 reads done; hT reusable as reduce scratch

  float s[4] = {0.f, 0.f, 0.f, 0.f}, q[4] = {0.f, 0.f, 0.f, 0.f};
#pragma unroll
  for (int n = 0; n < 4; ++n) {
    int node = tile0 + n0 + n;
    if (node < NN) {
      float4 v = {o2[n][0], o2[n][1], o2[n][2], o2[n][3]};
      *(float4*)&out[node * 64 + f0] = v;
#pragma unroll
      for (int j = 0; j < 4; ++j) {
        s[j] += o2[n][j];
        q[j] = fmaf(o2[n][j], o2[n][j], q[j]);
      }
    }
  }
  float* red = &hT[0][0];  // 2048 floats needed, hT has 4224
#pragma unroll
  for (int j = 0; j < 4; ++j) {
    red[(f0 + j) * 16 + ng] = s[j];
    red[1024 + (f0 + j) * 16 + ng] = q[j];
  }
  __syncthreads();
  if (tid < 64) {
    float ss = 0.f, qq = 0.f;
    for (int g = 0; g < 16; ++g) {
      ss += red[tid * 16 + g];
      qq += red[1024 + tid * 16 + g];
    }
    atomicAdd(&sums[tid], ss);
    atomicAdd(&sums[64 + tid], qq);
  }
}

// ---------------- BN finalize + relu, in place on d_out ----------------
__global__ __launch_bounds__(256) void bn_k(float* __restrict__ h2out,
                                            const float* __restrict__ sums,
                                            const float* __restrict__ gamma,
                                            const float* __restrict__ beta) {
  __shared__ float sc[64], sh[64];
  int tid = threadIdx.x;
  if (tid < 64) {
    const float invN = 1.0f / NN;
    float mean = sums[tid] * invN;
    float var = fmaf(-mean, mean, sums[64 + tid] * invN);
    float s = gamma[tid] * rsqrtf(var + BN_EPS_C);
    sc[tid] = s;
    sh[tid] = fmaf(-mean, s, beta[tid]);
  }
  __syncthreads();
  int gid = blockIdx.x * 256 + tid;
  const int tot = NN * 16;
  float4* p = (float4*)h2out;
  for (int i = gid; i < tot; i += gridDim.x * 256) {
    int f0 = (i & 15) * 4;
    float4 v = p[i];
    v.x = fmaxf(fmaf(v.x, sc[f0 + 0], sh[f0 + 0]), 0.f);
    v.y = fmaxf(fmaf(v.y, sc[f0 + 1], sh[f0 + 1]), 0.f);
    v.z = fmaxf(fmaf(v.z, sc[f0 + 2], sh[f0 + 2]), 0.f);
    v.w = fmaxf(fmaf(v.w, sc[f0 + 3], sh[f0 + 3]), 0.f);
    p[i] = v;
  }
}

extern "C" void kernel_launch(void* const* d_in, const int* in_sizes, int n_in,
                              void* d_out, int out_size, void* d_ws, size_t ws_size,
                              hipStream_t stream) {
  const float* x     = (const float*)d_in[0];
  const int*   src   = (const int*)d_in[1];
  const int*   dst   = (const int*)d_in[2];
  const float* ew    = (const float*)d_in[3];
  const float* W1    = (const float*)d_in[4];
  const float* b1    = (const float*)d_in[5];
  const float* W2    = (const float*)d_in[6];
  const float* b2    = (const float*)d_in[7];
  const float* eps   = (const float*)d_in[8];
  const float* gamma = (const float*)d_in[9];
  const float* beta  = (const float*)d_in[10];
  int E = in_sizes[1];

  // ws: counts[NN] | offs[NN] | cursor[NN] | sorted[E] int2 | W1t | W2t | sums[128] | bsum[NSB] | y[NN*64]
  int*   counts = (int*)d_ws;
  int*   offs   = counts + NN;
  int*   cursor = offs + NN;
  int2*  sorted = (int2*)(cursor + NN);
  float* W1t    = (float*)(sorted + E);
  float* W2t    = W1t + 4096;
  float* sums   = W2t + 4096;
  int*   bsum   = (int*)(sums + 128);
  float* y      = (float*)(bsum + ((NSB + 3) & ~3));
  float* h2     = (float*)d_out;

  int eb4 = (E / 4 + 255) / 256;
  prep_k<<<64, 256, 0, stream>>>(W1, W2, counts, sums, W1t, W2t);
  hist_k<<<eb4, 256, 0, stream>>>(dst, counts, E);
  scana_k<<<NSB, 256, 0, stream>>>(counts, bsum);
  scanc_k<<<NSB, 256, 0, stream>>>(counts, bsum, offs, cursor);
  scatter_k<<<eb4, 256, 0, stream>>>(src, dst, ew, cursor, sorted, E);
  gather_k<<<(NN + 15) / 16, 256, 0, stream>>>(x, sorted, offs, counts, eps, y);
  mlp_k<<<(NN + 63) / 64, 256, 0, stream>>>(y, W1t, W2t, b1, b2, h2, sums);
  bn_k<<<3125, 256, 0, stream>>>(h2, sums, gamma, beta);
}

// Round 7
// 171.007 us; speedup vs baseline: 5.5183x; 1.0456x over previous
//
#include <hip/hip_runtime.h>

#define NN 50000
#define BN_EPS_C 1e-5f
#define SCAN_CHUNK 512
#define NSB ((NN + SCAN_CHUNK - 1) / SCAN_CHUNK)  // 98

// ---------------- prep: zero counts/sums, transpose W1,W2 into ws ----------------
__global__ __launch_bounds__(256) void prep_k(const float* __restrict__ W1,
                                              const float* __restrict__ W2,
                                              int* __restrict__ counts,
                                              float* __restrict__ sums,
                                              float* __restrict__ W1t,
                                              float* __restrict__ W2t) {
  int gid = blockIdx.x * 256 + threadIdx.x;
  for (int i = gid; i < NN; i += gridDim.x * 256) counts[i] = 0;
  if (gid < 128) sums[gid] = 0.f;
  for (int i = gid; i < 4096; i += gridDim.x * 256) {
    int f = i >> 6, k = i & 63;
    W1t[k * 64 + f] = W1[i];  // Wt[k][f] = W[f][k]
    W2t[k * 64 + f] = W2[i];
  }
}

// ---------------- histogram of dst + per-edge rank capture ----------------
__global__ __launch_bounds__(256) void histrank_k(const int* __restrict__ dst,
                                                  int* __restrict__ counts,
                                                  int* __restrict__ rank, int E) {
  int t = blockIdx.x * 256 + threadIdx.x;
  int e = t * 4;
  if (e + 3 < E) {
    int4 d = *(const int4*)(dst + e);
    int4 r;
    r.x = atomicAdd(&counts[d.x], 1);
    r.y = atomicAdd(&counts[d.y], 1);
    r.z = atomicAdd(&counts[d.z], 1);
    r.w = atomicAdd(&counts[d.w], 1);
    *(int4*)(rank + e) = r;  // coalesced
  } else {
    for (; e < E; ++e) rank[e] = atomicAdd(&counts[dst[e]], 1);
  }
}

// ---------------- two-level scan: A) block sums ----------------
__global__ __launch_bounds__(256) void scana_k(const int* __restrict__ counts,
                                               int* __restrict__ bsum) {
  __shared__ int red[256];
  int b = blockIdx.x, tid = threadIdx.x;
  int i0 = b * SCAN_CHUNK + tid;
  int v = 0;
  if (i0 < NN) v += counts[i0];
  if (i0 + 256 < NN && tid + 256 < SCAN_CHUNK) v += counts[i0 + 256];
  red[tid] = v;
  __syncthreads();
  for (int s = 128; s > 0; s >>= 1) {
    if (tid < s) red[tid] += red[tid + s];
    __syncthreads();
  }
  if (tid == 0) bsum[b] = red[0];
}

// ---------------- B+C fused: per-block base reduce + local scan -> offs --------
__global__ __launch_bounds__(256) void scanc_k(const int* __restrict__ counts,
                                               const int* __restrict__ bsum,
                                               int* __restrict__ offs) {
  __shared__ int s[256];
  __shared__ int basev;
  int b = blockIdx.x, tid = threadIdx.x;
  s[tid] = (tid < b) ? bsum[tid] : 0;  // NSB=98 <= 256
  __syncthreads();
  for (int st = 128; st > 0; st >>= 1) {
    if (tid < st) s[tid] += s[tid + st];
    __syncthreads();
  }
  if (tid == 0) basev = s[0];
  __syncthreads();
  int base = basev;
  __syncthreads();  // everyone read basev; s reusable
  int i0 = b * SCAN_CHUNK + 2 * tid;
  int c0 = (i0 < NN) ? counts[i0] : 0;
  int c1 = (i0 + 1 < NN) ? counts[i0 + 1] : 0;
  int tsum = c0 + c1;
  s[tid] = tsum;
  __syncthreads();
  for (int off = 1; off < 256; off <<= 1) {
    int t = (tid >= off) ? s[tid - off] : 0;
    __syncthreads();
    s[tid] += t;
    __syncthreads();
  }
  int pre = base + s[tid] - tsum;
  if (i0 < NN) offs[i0] = pre;
  if (i0 + 1 < NN) offs[i0 + 1] = pre + c0;
}

// ---------------- atomic-free permutation: perm[offs[d]+rank[e]] = e ----------
__global__ __launch_bounds__(256) void perm_k(const int* __restrict__ dst,
                                              const int* __restrict__ rank,
                                              const int* __restrict__ offs,
                                              int* __restrict__ perm, int E) {
  int t = blockIdx.x * 256 + threadIdx.x;
  int e = t * 4;
  if (e + 3 < E) {
    int4 d = *(const int4*)(dst + e);
    int4 r = *(const int4*)(rank + e);
    int o0 = offs[d.x], o1 = offs[d.y], o2 = offs[d.z], o3 = offs[d.w];
    __builtin_nontemporal_store(e + 0, &perm[o0 + r.x]);
    __builtin_nontemporal_store(e + 1, &perm[o1 + r.y]);
    __builtin_nontemporal_store(e + 2, &perm[o2 + r.z]);
    __builtin_nontemporal_store(e + 3, &perm[o3 + r.w]);
  } else {
    for (; e < E; ++e) perm[offs[dst[e]] + rank[e]] = e;
  }
}

// ---------------- overflow helper (deg > 64, rare) ----------------
__device__ inline void ovf_add(const float4* __restrict__ x4,
                               const int* __restrict__ perm,
                               const int* __restrict__ srcv,
                               const float* __restrict__ ew,
                               int off, int cnt,
                               int lane, int es, int fq, float4& acc) {
  for (int b = 64; b < cnt; b += 64) {
    int take = min(64, cnt - b);
    int2 m = make_int2(0, 0);
    if (lane < take) {
      int p = perm[off + b + lane];
      m.x = srcv[p];
      m.y = __float_as_int(ew[p]);
    }
    int nb = (take + 3) >> 2;
    for (int t = 0; t < nb; ++t) {
      int i0 = t * 4 + es;
      int s = __shfl(m.x, i0);
      float w = __int_as_float(__shfl(m.y, i0));
      float4 v = x4[s * 16 + fq];
      acc.x = fmaf(w, v.x, acc.x); acc.y = fmaf(w, v.y, acc.y);
      acc.z = fmaf(w, v.z, acc.z); acc.w = fmaf(w, v.w, acc.w);
    }
  }
}

// ---------------- gather: y[n] = (1+eps)*x[n] + sum_e w_e * x[src_e] ----------
// No LDS -> high occupancy. Wave handles 4 nodes; es=lane>>4 picks edge slot,
// fq=lane&15 picks feature quad. 8 independent float4 streams per iteration.
__global__ __launch_bounds__(256, 6) void gather_k(const float* __restrict__ x,
                                                   const int* __restrict__ perm,
                                                   const int* __restrict__ srcv,
                                                   const float* __restrict__ ew,
                                                   const int* __restrict__ offs,
                                                   const int* __restrict__ counts,
                                                   const float* __restrict__ eps,
                                                   float* __restrict__ y) {
  int tid = threadIdx.x;
  int lane = tid & 63;
  int wv = tid >> 6;
  int es = lane >> 4, fq = lane & 15;
  int nbase = (blockIdx.x * 4 + wv) * 4;
  if (nbase >= NN) return;
  const float c1 = 1.0f + eps[0];
  const float4* x4 = (const float4*)x;
  float4* y4 = (float4*)y;

  bool v1 = nbase + 1 < NN, v2 = nbase + 2 < NN, v3 = nbase + 3 < NN;
  int off0 = offs[nbase],              cnt0 = counts[nbase];
  int off1 = v1 ? offs[nbase + 1] : 0, cnt1 = v1 ? counts[nbase + 1] : 0;
  int off2 = v2 ? offs[nbase + 2] : 0, cnt2 = v2 ? counts[nbase + 2] : 0;
  int off3 = v3 ? offs[nbase + 3] : 0, cnt3 = v3 ? counts[nbase + 3] : 0;
  int tk0 = min(cnt0, 64), tk1 = min(cnt1, 64);
  int tk2 = min(cnt2, 64), tk3 = min(cnt3, 64);
  // coalesced perm loads (4 independent streams)
  int p0 = (lane < tk0) ? perm[off0 + lane] : -1;
  int p1 = (lane < tk1) ? perm[off1 + lane] : -1;
  int p2 = (lane < tk2) ? perm[off2 + lane] : -1;
  int p3 = (lane < tk3) ? perm[off3 + lane] : -1;
  // random 4B src/ew loads (L2-resident, 8 independent streams)
  int2 m0 = make_int2(0, 0), m1 = make_int2(0, 0);
  int2 m2 = make_int2(0, 0), m3 = make_int2(0, 0);
  if (p0 >= 0) { m0.x = srcv[p0]; m0.y = __float_as_int(ew[p0]); }
  if (p1 >= 0) { m1.x = srcv[p1]; m1.y = __float_as_int(ew[p1]); }
  if (p2 >= 0) { m2.x = srcv[p2]; m2.y = __float_as_int(ew[p2]); }
  if (p3 >= 0) { m3.x = srcv[p3]; m3.y = __float_as_int(ew[p3]); }
  float4 a0 = {0, 0, 0, 0}, a1 = {0, 0, 0, 0};
  float4 a2 = {0, 0, 0, 0}, a3 = {0, 0, 0, 0};
  int nb0 = (tk0 + 3) >> 2, nb1 = (tk1 + 3) >> 2;
  int nb2 = (tk2 + 3) >> 2, nb3 = (tk3 + 3) >> 2;
  int nbM = max(max(nb0, nb1), max(nb2, nb3));
  for (int t = 0; t < nbM; t += 2) {
    int i0 = t * 4 + es, i1 = i0 + 4;  // i1 <= 63 since t <= 14
    int s00 = __shfl(m0.x, i0), s01 = __shfl(m0.x, i1);
    int s10 = __shfl(m1.x, i0), s11 = __shfl(m1.x, i1);
    int s20 = __shfl(m2.x, i0), s21 = __shfl(m2.x, i1);
    int s30 = __shfl(m3.x, i0), s31 = __shfl(m3.x, i1);
    float w00 = __int_as_float(__shfl(m0.y, i0)), w01 = __int_as_float(__shfl(m0.y, i1));
    float w10 = __int_as_float(__shfl(m1.y, i0)), w11 = __int_as_float(__shfl(m1.y, i1));
    float w20 = __int_as_float(__shfl(m2.y, i0)), w21 = __int_as_float(__shfl(m2.y, i1));
    float w30 = __int_as_float(__shfl(m3.y, i0)), w31 = __int_as_float(__shfl(m3.y, i1));
    float4 q00 = x4[s00 * 16 + fq], q01 = x4[s01 * 16 + fq];
    float4 q10 = x4[s10 * 16 + fq], q11 = x4[s11 * 16 + fq];
    float4 q20 = x4[s20 * 16 + fq], q21 = x4[s21 * 16 + fq];
    float4 q30 = x4[s30 * 16 + fq], q31 = x4[s31 * 16 + fq];
    a0.x = fmaf(w00, q00.x, a0.x); a0.y = fmaf(w00, q00.y, a0.y);
    a0.z = fmaf(w00, q00.z, a0.z); a0.w = fmaf(w00, q00.w, a0.w);
    a1.x = fmaf(w10, q10.x, a1.x); a1.y = fmaf(w10, q10.y, a1.y);
    a1.z = fmaf(w10, q10.z, a1.z); a1.w = fmaf(w10, q10.w, a1.w);
    a2.x = fmaf(w20, q20.x, a2.x); a2.y = fmaf(w20, q20.y, a2.y);
    a2.z = fmaf(w20, q20.z, a2.z); a2.w = fmaf(w20, q20.w, a2.w);
    a3.x = fmaf(w30, q30.x, a3.x); a3.y = fmaf(w30, q30.y, a3.y);
    a3.z = fmaf(w30, q30.z, a3.z); a3.w = fmaf(w30, q30.w, a3.w);
    a0.x = fmaf(w01, q01.x, a0.x); a0.y = fmaf(w01, q01.y, a0.y);
    a0.z = fmaf(w01, q01.z, a0.z); a0.w = fmaf(w01, q01.w, a0.w);
    a1.x = fmaf(w11, q11.x, a1.x); a1.y = fmaf(w11, q11.y, a1.y);
    a1.z = fmaf(w11, q11.z, a1.z); a1.w = fmaf(w11, q11.w, a1.w);
    a2.x = fmaf(w21, q21.x, a2.x); a2.y = fmaf(w21, q21.y, a2.y);
    a2.z = fmaf(w21, q21.z, a2.z); a2.w = fmaf(w21, q21.w, a2.w);
    a3.x = fmaf(w31, q31.x, a3.x); a3.y = fmaf(w31, q31.y, a3.y);
    a3.z = fmaf(w31, q31.z, a3.z); a3.w = fmaf(w31, q31.w, a3.w);
  }
  if (cnt0 > 64) ovf_add(x4, perm, srcv, ew, off0, cnt0, lane, es, fq, a0);
  if (cnt1 > 64) ovf_add(x4, perm, srcv, ew, off1, cnt1, lane, es, fq, a1);
  if (cnt2 > 64) ovf_add(x4, perm, srcv, ew, off2, cnt2, lane, es, fq, a2);
  if (cnt3 > 64) ovf_add(x4, perm, srcv, ew, off3, cnt3, lane, es, fq, a3);
  // reduce across es groups (lane bits 4,5)
#define RED4(a)                                     \
  a.x += __shfl_xor(a.x, 16); a.x += __shfl_xor(a.x, 32); \
  a.y += __shfl_xor(a.y, 16); a.y += __shfl_xor(a.y, 32); \
  a.z += __shfl_xor(a.z, 16); a.z += __shfl_xor(a.z, 32); \
  a.w += __shfl_xor(a.w, 16); a.w += __shfl_xor(a.w, 32);
  RED4(a0) RED4(a1) RED4(a2) RED4(a3)
#undef RED4
  // es group c stores node nbase+c -> fully coalesced 1KB store per wave
  int nst = nbase + es;
  if (nst < NN) {
    float4 r = (es == 0) ? a0 : (es == 1) ? a1 : (es == 2) ? a2 : a3;
    float4 xv = x4[nst * 16 + fq];
    r.x = fmaf(c1, xv.x, r.x); r.y = fmaf(c1, xv.y, r.y);
    r.z = fmaf(c1, xv.z, r.z); r.w = fmaf(c1, xv.w, r.w);
    y4[nst * 16 + fq] = r;
  }
}

// ---------------- MLP1(relu) + MLP2 + BN partials from y ----------------
// 64-node tile, 256 threads; 16fg x 16ng grid, 4-node x 4-feat register tile.
__global__ __launch_bounds__(256) void mlp_k(const float* __restrict__ y,
                                             const float* __restrict__ W1t,
                                             const float* __restrict__ W2t,
                                             const float* __restrict__ b1,
                                             const float* __restrict__ b2,
                                             float* __restrict__ out,
                                             float* __restrict__ sums) {
  __shared__ float hT[64][66];   // [k][local node]
  __shared__ float WA[64][64];
  int tid = threadIdx.x;
  int tile0 = blockIdx.x * 64;
  for (int i = tid; i < 4096; i += 256) ((float*)WA)[i] = W1t[i];
  const float4* y4 = (const float4*)y;
  for (int i = tid; i < 1024; i += 256) {
    int nl = i >> 4, fq = i & 15;
    int node = tile0 + nl;
    float4 v = {0, 0, 0, 0};
    if (node < NN) v = y4[node * 16 + fq];
    hT[4 * fq + 0][nl] = v.x; hT[4 * fq + 1][nl] = v.y;
    hT[4 * fq + 2][nl] = v.z; hT[4 * fq + 3][nl] = v.w;
  }
  __syncthreads();

  int fg = tid & 15, ng = tid >> 4;
  int f0 = fg * 4, n0 = ng * 4;
  float4 bv = *(const float4*)(b1 + f0);
  float o[4][4];
#pragma unroll
  for (int n = 0; n < 4; ++n) {
    o[n][0] = bv.x; o[n][1] = bv.y; o[n][2] = bv.z; o[n][3] = bv.w;
  }
#pragma unroll 8
  for (int k = 0; k < 64; ++k) {
    float2 iA = *(const float2*)&hT[k][n0];
    float2 iB = *(const float2*)&hT[k][n0 + 2];
    float4 w4 = *(const float4*)&WA[k][f0];
    float in[4] = {iA.x, iA.y, iB.x, iB.y};
    float ww[4] = {w4.x, w4.y, w4.z, w4.w};
#pragma unroll
    for (int n = 0; n < 4; ++n)
#pragma unroll
      for (int j = 0; j < 4; ++j) o[n][j] = fmaf(in[n], ww[j], o[n][j]);
  }
#pragma unroll
  for (int n = 0; n < 4; ++n)
#pragma unroll
    for (int j = 0; j < 4; ++j) o[n][j] = fmaxf(o[n][j], 0.f);

  __syncthreads();  // all GEMM1 reads done
#pragma unroll
  for (int j = 0; j < 4; ++j) {
    float2 vA = {o[0][j], o[1][j]}, vB = {o[2][j], o[3][j]};
    *(float2*)&hT[f0 + j][n0] = vA;
    *(float2*)&hT[f0 + j][n0 + 2] = vB;
  }
  for (int i = tid; i < 4096; i += 256) ((float*)WA)[i] = W2t[i];
  __syncthreads();

  float4 bv2 = *(const float4*)(b2 + f0);
  float o2[4][4];
#pragma unroll
  for (int n = 0; n < 4; ++n) {
    o2[n][0] = bv2.x; o2[n][1] = bv2.y; o2[n][2] = bv2.z; o2[n][3] = bv2.w;
  }
#pragma unroll 8
  for (int k = 0; k < 64; ++k) {
    float2 iA = *(const float2*)&hT[k][n0];
    float2 iB = *(const float2*)&hT[k][n0 + 2];
    float4 w4 = *(const float4*)&WA[k][f0];
    float in[4] = {iA.x, iA.y, iB.x, iB.y};
    float ww[4] = {w4.x, w4.y, w4.z, w4.w};
#pragma unroll
    for (int n = 0; n < 4; ++n)
#pragma unroll
      for (int j = 0; j < 4; ++j) o2[n][j] = fmaf(in[n], ww[j], o2[n][j]);
  }
  __syncthreads();  // GEMM2 reads done; hT reusable as reduce scratch

  float s[4] = {0.f, 0.f, 0.f, 0.f}, q[4] = {0.f, 0.f, 0.f, 0.f};
#pragma unroll
  for (int n = 0; n < 4; ++n) {
    int node = tile0 + n0 + n;
    if (node < NN) {
      float4 v = {o2[n][0], o2[n][1], o2[n][2], o2[n][3]};
      *(float4*)&out[node * 64 + f0] = v;
#pragma unroll
      for (int j = 0; j < 4; ++j) {
        s[j] += o2[n][j];
        q[j] = fmaf(o2[n][j], o2[n][j], q[j]);
      }
    }
  }
  float* red = &hT[0][0];  // 2048 floats needed, hT has 4224
#pragma unroll
  for (int j = 0; j < 4; ++j) {
    red[(f0 + j) * 16 + ng] = s[j];
    red[1024 + (f0 + j) * 16 + ng] = q[j];
  }
  __syncthreads();
  if (tid < 64) {
    float ss = 0.f, qq = 0.f;
    for (int g = 0; g < 16; ++g) {
      ss += red[tid * 16 + g];
      qq += red[1024 + tid * 16 + g];
    }
    atomicAdd(&sums[tid], ss);
    atomicAdd(&sums[64 + tid], qq);
  }
}

// ---------------- BN finalize + relu, in place on d_out ----------------
__global__ __launch_bounds__(256) void bn_k(float* __restrict__ h2out,
                                            const float* __restrict__ sums,
                                            const float* __restrict__ gamma,
                                            const float* __restrict__ beta) {
  __shared__ float sc[64], sh[64];
  int tid = threadIdx.x;
  if (tid < 64) {
    const float invN = 1.0f / NN;
    float mean = sums[tid] * invN;
    float var = fmaf(-mean, mean, sums[64 + tid] * invN);
    float s = gamma[tid] * rsqrtf(var + BN_EPS_C);
    sc[tid] = s;
    sh[tid] = fmaf(-mean, s, beta[tid]);
  }
  __syncthreads();
  int gid = blockIdx.x * 256 + tid;
  const int tot = NN * 16;
  float4* p = (float4*)h2out;
  for (int i = gid; i < tot; i += gridDim.x * 256) {
    int f0 = (i & 15) * 4;
    float4 v = p[i];
    v.x = fmaxf(fmaf(v.x, sc[f0 + 0], sh[f0 + 0]), 0.f);
    v.y = fmaxf(fmaf(v.y, sc[f0 + 1], sh[f0 + 1]), 0.f);
    v.z = fmaxf(fmaf(v.z, sc[f0 + 2], sh[f0 + 2]), 0.f);
    v.w = fmaxf(fmaf(v.w, sc[f0 + 3], sh[f0 + 3]), 0.f);
    p[i] = v;
  }
}

extern "C" void kernel_launch(void* const* d_in, const int* in_sizes, int n_in,
                              void* d_out, int out_size, void* d_ws, size_t ws_size,
                              hipStream_t stream) {
  const float* x     = (const float*)d_in[0];
  const int*   src   = (const int*)d_in[1];
  const int*   dst   = (const int*)d_in[2];
  const float* ew    = (const float*)d_in[3];
  const float* W1    = (const float*)d_in[4];
  const float* b1    = (const float*)d_in[5];
  const float* W2    = (const float*)d_in[6];
  const float* b2    = (const float*)d_in[7];
  const float* eps   = (const float*)d_in[8];
  const float* gamma = (const float*)d_in[9];
  const float* beta  = (const float*)d_in[10];
  int E = in_sizes[1];

  // ws: counts[NN] | offs[NN] | rank[E] | perm[E] | W1t | W2t | sums[128] | bsum | y[NN*64]
  int*   counts = (int*)d_ws;
  int*   offs   = counts + NN;
  int*   rank   = offs + NN;
  int*   perm   = rank + E;
  float* W1t    = (float*)(perm + E);
  float* W2t    = W1t + 4096;
  float* sums   = W2t + 4096;
  int*   bsum   = (int*)(sums + 128);
  float* y      = (float*)(bsum + ((NSB + 3) & ~3));
  float* h2     = (float*)d_out;

  int eb4 = (E / 4 + 255) / 256;
  prep_k<<<64, 256, 0, stream>>>(W1, W2, counts, sums, W1t, W2t);
  histrank_k<<<eb4, 256, 0, stream>>>(dst, counts, rank, E);
  scana_k<<<NSB, 256, 0, stream>>>(counts, bsum);
  scanc_k<<<NSB, 256, 0, stream>>>(counts, bsum, offs);
  perm_k<<<eb4, 256, 0, stream>>>(dst, rank, offs, perm, E);
  gather_k<<<(NN + 15) / 16, 256, 0, stream>>>(x, perm, src, ew, offs, counts, eps, y);
  mlp_k<<<(NN + 63) / 64, 256, 0, stream>>>(y, W1t, W2t, b1, b2, h2, sums);
  bn_k<<<3125, 256, 0, stream>>>(h2, sums, gamma, beta);
}

// Round 9
// 164.521 us; speedup vs baseline: 5.7358x; 1.0394x over previous
//
#include <hip/hip_runtime.h>
#include <hip/hip_fp16.h>

#define NN 50000
#define BN_EPS_C 1e-5f
#define SCAN_CHUNK 512
#define NSB ((NN + SCAN_CHUNK - 1) / SCAN_CHUNK)  // 98

// ---------------- prep: zero counts/sums, transpose W1,W2, x -> fp16 ----------
__global__ __launch_bounds__(256) void prep_k(const float* __restrict__ x,
                                              const float* __restrict__ W1,
                                              const float* __restrict__ W2,
                                              int* __restrict__ counts,
                                              float* __restrict__ sums,
                                              float* __restrict__ W1t,
                                              float* __restrict__ W2t,
                                              unsigned short* __restrict__ xh) {
  int gid = blockIdx.x * 256 + threadIdx.x;
  int stride = gridDim.x * 256;
  for (int i = gid; i < NN; i += stride) counts[i] = 0;
  if (gid < 128) sums[gid] = 0.f;
  for (int i = gid; i < 4096; i += stride) {
    int f = i >> 6, k = i & 63;
    W1t[k * 64 + f] = W1[i];  // Wt[k][f] = W[f][k]
    W2t[k * 64 + f] = W2[i];
  }
  const float4* x4 = (const float4*)x;
  uint2* xh2 = (uint2*)xh;
  for (int i = gid; i < NN * 16; i += stride) {
    float4 v = x4[i];
    __half2 h0 = __floats2half2_rn(v.x, v.y);
    __half2 h1 = __floats2half2_rn(v.z, v.w);
    uint2 u;
    u.x = *reinterpret_cast<unsigned*>(&h0);
    u.y = *reinterpret_cast<unsigned*>(&h1);
    xh2[i] = u;
  }
}

// ---------------- histogram of dst + per-edge rank capture ----------------
__global__ __launch_bounds__(256) void histrank_k(const int* __restrict__ dst,
                                                  int* __restrict__ counts,
                                                  int* __restrict__ rank, int E) {
  int t = blockIdx.x * 256 + threadIdx.x;
  int e = t * 4;
  if (e + 3 < E) {
    int4 d = *(const int4*)(dst + e);
    int4 r;
    r.x = atomicAdd(&counts[d.x], 1);
    r.y = atomicAdd(&counts[d.y], 1);
    r.z = atomicAdd(&counts[d.z], 1);
    r.w = atomicAdd(&counts[d.w], 1);
    *(int4*)(rank + e) = r;  // coalesced
  } else {
    for (; e < E; ++e) rank[e] = atomicAdd(&counts[dst[e]], 1);
  }
}

// ---------------- two-level scan: A) block sums ----------------
__global__ __launch_bounds__(256) void scana_k(const int* __restrict__ counts,
                                               int* __restrict__ bsum) {
  __shared__ int red[256];
  int b = blockIdx.x, tid = threadIdx.x;
  int i0 = b * SCAN_CHUNK + tid;
  int v = 0;
  if (i0 < NN) v += counts[i0];
  if (i0 + 256 < NN && tid + 256 < SCAN_CHUNK) v += counts[i0 + 256];
  red[tid] = v;
  __syncthreads();
  for (int s = 128; s > 0; s >>= 1) {
    if (tid < s) red[tid] += red[tid + s];
    __syncthreads();
  }
  if (tid == 0) bsum[b] = red[0];
}

// ---------------- B+C fused: per-block base reduce + local scan -> offs --------
__global__ __launch_bounds__(256) void scanc_k(const int* __restrict__ counts,
                                               const int* __restrict__ bsum,
                                               int* __restrict__ offs) {
  __shared__ int s[256];
  __shared__ int basev;
  int b = blockIdx.x, tid = threadIdx.x;
  s[tid] = (tid < b) ? bsum[tid] : 0;  // NSB=98 <= 256
  __syncthreads();
  for (int st = 128; st > 0; st >>= 1) {
    if (tid < st) s[tid] += s[tid + st];
    __syncthreads();
  }
  if (tid == 0) basev = s[0];
  __syncthreads();
  int base = basev;
  __syncthreads();  // everyone read basev; s reusable
  int i0 = b * SCAN_CHUNK + 2 * tid;
  int c0 = (i0 < NN) ? counts[i0] : 0;
  int c1 = (i0 + 1 < NN) ? counts[i0 + 1] : 0;
  int tsum = c0 + c1;
  s[tid] = tsum;
  __syncthreads();
  for (int off = 1; off < 256; off <<= 1) {
    int t = (tid >= off) ? s[tid - off] : 0;
    __syncthreads();
    s[tid] += t;
    __syncthreads();
  }
  int pre = base + s[tid] - tsum;
  if (i0 < NN) offs[i0] = pre;
  if (i0 + 1 < NN) offs[i0 + 1] = pre + c0;
}

// ---- atomic-free sorted (src,w) build: sorted[offs[d]+rank[e]] = {src,w} ----
__global__ __launch_bounds__(256) void sort_k(const int* __restrict__ dst,
                                              const int* __restrict__ rank,
                                              const int* __restrict__ srcv,
                                              const float* __restrict__ ew,
                                              const int* __restrict__ offs,
                                              long long* __restrict__ sorted, int E) {
  int t = blockIdx.x * 256 + threadIdx.x;
  int e = t * 4;
  if (e + 3 < E) {
    int4 d = *(const int4*)(dst + e);
    int4 r = *(const int4*)(rank + e);
    int4 s = *(const int4*)(srcv + e);
    float4 w = *(const float4*)(ew + e);
    long long v0 = ((long long)__float_as_int(w.x) << 32) | (unsigned)s.x;
    long long v1 = ((long long)__float_as_int(w.y) << 32) | (unsigned)s.y;
    long long v2 = ((long long)__float_as_int(w.z) << 32) | (unsigned)s.z;
    long long v3 = ((long long)__float_as_int(w.w) << 32) | (unsigned)s.w;
    __builtin_nontemporal_store(v0, &sorted[offs[d.x] + r.x]);
    __builtin_nontemporal_store(v1, &sorted[offs[d.y] + r.y]);
    __builtin_nontemporal_store(v2, &sorted[offs[d.z] + r.z]);
    __builtin_nontemporal_store(v3, &sorted[offs[d.w] + r.w]);
  } else {
    for (; e < E; ++e) {
      long long v = ((long long)__float_as_int(ew[e]) << 32) | (unsigned)srcv[e];
      sorted[offs[dst[e]] + rank[e]] = v;
    }
  }
}

// ------- fp16 accumulate: 8 halves (uint4) -> 8 f32 accumulators -------
__device__ inline void acc8(float* a, uint4 q, float wgt) {
  float2 f;
  f = __half22float2(*(const __half2*)&q.x);
  a[0] = fmaf(wgt, f.x, a[0]); a[1] = fmaf(wgt, f.y, a[1]);
  f = __half22float2(*(const __half2*)&q.y);
  a[2] = fmaf(wgt, f.x, a[2]); a[3] = fmaf(wgt, f.y, a[3]);
  f = __half22float2(*(const __half2*)&q.z);
  a[4] = fmaf(wgt, f.x, a[4]); a[5] = fmaf(wgt, f.y, a[5]);
  f = __half22float2(*(const __half2*)&q.w);
  a[6] = fmaf(wgt, f.x, a[6]); a[7] = fmaf(wgt, f.y, a[7]);
}

// ------- overflow tail for deg > 64 (rare) -------
__device__ inline void ovf8(float* a, const uint4* __restrict__ xh4,
                            const long long* __restrict__ sorted,
                            int off, int cnt, int lane, int es, int fo) {
  for (int b = 64; b < cnt; b += 64) {
    int take = min(64, cnt - b);
    int2 m = make_int2(0, 0);
    if (lane < take) {
      long long vv = sorted[off + b + lane];
      m.x = (int)(vv & 0xffffffffLL);
      m.y = (int)(vv >> 32);
    }
    int nb = (take + 7) >> 3;
    for (int t = 0; t < nb; ++t) {
      int i0 = t * 8 + es;
      int s = __shfl(m.x, i0);
      float wgt = __int_as_float(__shfl(m.y, i0));
      uint4 q = xh4[s * 8 + fo];
      acc8(a, q, wgt);
    }
  }
}

// ---------------- gather: y[n] = (1+eps)*x[n] + sum_e w_e * xh[src_e] ----------
// es = lane>>3 (8 edge slots), fo = lane&7 (16B half-octet). One wave load
// fetches 8 fp16 rows; 4 nodes interleaved -> 4 independent load streams.
__global__ __launch_bounds__(256, 4) void gather_k(const float* __restrict__ x,
                                                   const unsigned short* __restrict__ xh,
                                                   const long long* __restrict__ sorted,
                                                   const int* __restrict__ offs,
                                                   const int* __restrict__ counts,
                                                   const float* __restrict__ eps,
                                                   float* __restrict__ y) {
  int tid = threadIdx.x;
  int lane = tid & 63;
  int wv = tid >> 6;
  int es = lane >> 3, fo = lane & 7;
  int nbase = (blockIdx.x * 4 + wv) * 4;
  if (nbase >= NN) return;
  const float c1 = 1.0f + eps[0];
  const uint4* xh4 = (const uint4*)xh;
  const float4* x4 = (const float4*)x;
  float4* y4 = (float4*)y;

  bool v1 = nbase + 1 < NN, v2 = nbase + 2 < NN, v3 = nbase + 3 < NN;
  int off0 = offs[nbase],              cnt0 = counts[nbase];
  int off1 = v1 ? offs[nbase + 1] : 0, cnt1 = v1 ? counts[nbase + 1] : 0;
  int off2 = v2 ? offs[nbase + 2] : 0, cnt2 = v2 ? counts[nbase + 2] : 0;
  int off3 = v3 ? offs[nbase + 3] : 0, cnt3 = v3 ? counts[nbase + 3] : 0;
  int tk0 = min(cnt0, 64), tk1 = min(cnt1, 64);
  int tk2 = min(cnt2, 64), tk3 = min(cnt3, 64);
  int2 m0 = make_int2(0, 0), m1 = make_int2(0, 0);
  int2 m2 = make_int2(0, 0), m3 = make_int2(0, 0);
  if (lane < tk0) { long long v = sorted[off0 + lane]; m0.x = (int)(v & 0xffffffffLL); m0.y = (int)(v >> 32); }
  if (lane < tk1) { long long v = sorted[off1 + lane]; m1.x = (int)(v & 0xffffffffLL); m1.y = (int)(v >> 32); }
  if (lane < tk2) { long long v = sorted[off2 + lane]; m2.x = (int)(v & 0xffffffffLL); m2.y = (int)(v >> 32); }
  if (lane < tk3) { long long v = sorted[off3 + lane]; m3.x = (int)(v & 0xffffffffLL); m3.y = (int)(v >> 32); }
  float a0[8] = {0, 0, 0, 0, 0, 0, 0, 0};
  float a1[8] = {0, 0, 0, 0, 0, 0, 0, 0};
  float a2[8] = {0, 0, 0, 0, 0, 0, 0, 0};
  float a3[8] = {0, 0, 0, 0, 0, 0, 0, 0};
  int nb0 = (tk0 + 7) >> 3, nb1 = (tk1 + 7) >> 3;
  int nb2 = (tk2 + 7) >> 3, nb3 = (tk3 + 7) >> 3;
  int nbM = max(max(nb0, nb1), max(nb2, nb3));
  for (int t = 0; t < nbM; ++t) {
    int i0 = t * 8 + es;  // <= 63 (t <= 7)
    int s0 = __shfl(m0.x, i0), s1 = __shfl(m1.x, i0);
    int s2 = __shfl(m2.x, i0), s3 = __shfl(m3.x, i0);
    float w0 = __int_as_float(__shfl(m0.y, i0));
    float w1 = __int_as_float(__shfl(m1.y, i0));
    float w2 = __int_as_float(__shfl(m2.y, i0));
    float w3 = __int_as_float(__shfl(m3.y, i0));
    uint4 q0 = xh4[s0 * 8 + fo];
    uint4 q1 = xh4[s1 * 8 + fo];
    uint4 q2 = xh4[s2 * 8 + fo];
    uint4 q3 = xh4[s3 * 8 + fo];
    acc8(a0, q0, w0);
    acc8(a1, q1, w1);
    acc8(a2, q2, w2);
    acc8(a3, q3, w3);
  }
  if (cnt0 > 64) ovf8(a0, xh4, sorted, off0, cnt0, lane, es, fo);
  if (cnt1 > 64) ovf8(a1, xh4, sorted, off1, cnt1, lane, es, fo);
  if (cnt2 > 64) ovf8(a2, xh4, sorted, off2, cnt2, lane, es, fo);
  if (cnt3 > 64) ovf8(a3, xh4, sorted, off3, cnt3, lane, es, fo);
  // reduce across es (lane bits 3,4,5)
#pragma unroll
  for (int j = 0; j < 8; ++j) {
    a0[j] += __shfl_xor(a0[j], 8); a0[j] += __shfl_xor(a0[j], 16); a0[j] += __shfl_xor(a0[j], 32);
    a1[j] += __shfl_xor(a1[j], 8); a1[j] += __shfl_xor(a1[j], 16); a1[j] += __shfl_xor(a1[j], 32);
    a2[j] += __shfl_xor(a2[j], 8); a2[j] += __shfl_xor(a2[j], 16); a2[j] += __shfl_xor(a2[j], 32);
    a3[j] += __shfl_xor(a3[j], 8); a3[j] += __shfl_xor(a3[j], 16); a3[j] += __shfl_xor(a3[j], 32);
  }
  // es group g (g<4) stores node nbase+g: 8 lanes x 32B contiguous
  {
    int g = es & 3;
    bool sel = es < 4;  // only groups 0..3 store
    const float* arr = (g == 0) ? a0 : (g == 1) ? a1 : (g == 2) ? a2 : a3;
    int nst = nbase + g;
    if (sel && nst < NN) {
      float4 xlo = x4[nst * 16 + fo * 2];
      float4 xhi = x4[nst * 16 + fo * 2 + 1];
      float4 lo = {fmaf(c1, xlo.x, arr[0]), fmaf(c1, xlo.y, arr[1]),
                   fmaf(c1, xlo.z, arr[2]), fmaf(c1, xlo.w, arr[3])};
      float4 hi = {fmaf(c1, xhi.x, arr[4]), fmaf(c1, xhi.y, arr[5]),
                   fmaf(c1, xhi.z, arr[6]), fmaf(c1, xhi.w, arr[7])};
      y4[nst * 16 + fo * 2] = lo;
      y4[nst * 16 + fo * 2 + 1] = hi;
    }
  }
}

// ---------------- MLP1(relu) + MLP2 + BN partials from y ----------------
__global__ __launch_bounds__(256) void mlp_k(const float* __restrict__ y,
                                             const float* __restrict__ W1t,
                                             const float* __restrict__ W2t,
                                             const float* __restrict__ b1,
                                             const float* __restrict__ b2,
                                             float* __restrict__ out,
                                             float* __restrict__ sums) {
  __shared__ float hT[64][66];   // [k][local node]
  __shared__ float WA[64][64];
  int tid = threadIdx.x;
  int tile0 = blockIdx.x * 64;
  for (int i = tid; i < 4096; i += 256) ((float*)WA)[i] = W1t[i];
  const float4* y4 = (const float4*)y;
  for (int i = tid; i < 1024; i += 256) {
    int nl = i >> 4, fq = i & 15;
    int node = tile0 + nl;
    float4 v = {0, 0, 0, 0};
    if (node < NN) v = y4[node * 16 + fq];
    hT[4 * fq + 0][nl] = v.x; hT[4 * fq + 1][nl] = v.y;
    hT[4 * fq + 2][nl] = v.z; hT[4 * fq + 3][nl] = v.w;
  }
  __syncthreads();

  int fg = tid & 15, ng = tid >> 4;
  int f0 = fg * 4, n0 = ng * 4;
  float4 bv = *(const float4*)(b1 + f0);
  float o[4][4];
#pragma unroll
  for (int n = 0; n < 4; ++n) {
    o[n][0] = bv.x; o[n][1] = bv.y; o[n][2] = bv.z; o[n][3] = bv.w;
  }
#pragma unroll 8
  for (int k = 0; k < 64; ++k) {
    float2 iA = *(const float2*)&hT[k][n0];
    float2 iB = *(const float2*)&hT[k][n0 + 2];
    float4 w4 = *(const float4*)&WA[k][f0];
    float in[4] = {iA.x, iA.y, iB.x, iB.y};
    float ww[4] = {w4.x, w4.y, w4.z, w4.w};
#pragma unroll
    for (int n = 0; n < 4; ++n)
#pragma unroll
      for (int j = 0; j < 4; ++j) o[n][j] = fmaf(in[n], ww[j], o[n][j]);
  }
#pragma unroll
  for (int n = 0; n < 4; ++n)
#pragma unroll
    for (int j = 0; j < 4; ++j) o[n][j] = fmaxf(o[n][j], 0.f);

  __syncthreads();  // all GEMM1 reads done
#pragma unroll
  for (int j = 0; j < 4; ++j) {
    float2 vA = {o[0][j], o[1][j]}, vB = {o[2][j], o[3][j]};
    *(float2*)&hT[f0 + j][n0] = vA;
    *(float2*)&hT[f0 + j][n0 + 2] = vB;
  }
  for (int i = tid; i < 4096; i += 256) ((float*)WA)[i] = W2t[i];
  __syncthreads();

  float4 bv2 = *(const float4*)(b2 + f0);
  float o2[4][4];
#pragma unroll
  for (int n = 0; n < 4; ++n) {
    o2[n][0] = bv2.x; o2[n][1] = bv2.y; o2[n][2] = bv2.z; o2[n][3] = bv2.w;
  }
#pragma unroll 8
  for (int k = 0; k < 64; ++k) {
    float2 iA = *(const float2*)&hT[k][n0];
    float2 iB = *(const float2*)&hT[k][n0 + 2];
    float4 w4 = *(const float4*)&WA[k][f0];
    float in[4] = {iA.x, iA.y, iB.x, iB.y};
    float ww[4] = {w4.x, w4.y, w4.z, w4.w};
#pragma unroll
    for (int n = 0; n < 4; ++n)
#pragma unroll
      for (int j = 0; j < 4; ++j) o2[n][j] = fmaf(in[n], ww[j], o2[n][j]);
  }
  __syncthreads();  // GEMM2 reads done; hT reusable as reduce scratch

  float s[4] = {0.f, 0.f, 0.f, 0.f}, q[4] = {0.f, 0.f, 0.f, 0.f};
#pragma unroll
  for (int n = 0; n < 4; ++n) {
    int node = tile0 + n0 + n;
    if (node < NN) {
      float4 v = {o2[n][0], o2[n][1], o2[n][2], o2[n][3]};
      *(float4*)&out[node * 64 + f0] = v;
#pragma unroll
      for (int j = 0; j < 4; ++j) {
        s[j] += o2[n][j];
        q[j] = fmaf(o2[n][j], o2[n][j], q[j]);
      }
    }
  }
  float* red = &hT[0][0];
#pragma unroll
  for (int j = 0; j < 4; ++j) {
    red[(f0 + j) * 16 + ng] = s[j];
    red[1024 + (f0 + j) * 16 + ng] = q[j];
  }
  __syncthreads();
  if (tid < 64) {
    float ss = 0.f, qq = 0.f;
    for (int g = 0; g < 16; ++g) {
      ss += red[tid * 16 + g];
      qq += red[1024 + tid * 16 + g];
    }
    atomicAdd(&sums[tid], ss);
    atomicAdd(&sums[64 + tid], qq);
  }
}

// ---------------- BN finalize + relu, in place on d_out ----------------
__global__ __launch_bounds__(256) void bn_k(float* __restrict__ h2out,
                                            const float* __restrict__ sums,
                                            const float* __restrict__ gamma,
                                            const float* __restrict__ beta) {
  __shared__ float sc[64], sh[64];
  int tid = threadIdx.x;
  if (tid < 64) {
    const float invN = 1.0f / NN;
    float mean = sums[tid] * invN;
    float var = fmaf(-mean, mean, sums[64 + tid] * invN);
    float s = gamma[tid] * rsqrtf(var + BN_EPS_C);
    sc[tid] = s;
    sh[tid] = fmaf(-mean, s, beta[tid]);
  }
  __syncthreads();
  int gid = blockIdx.x * 256 + tid;
  const int tot = NN * 16;
  float4* p = (float4*)h2out;
  for (int i = gid; i < tot; i += gridDim.x * 256) {
    int f0 = (i & 15) * 4;
    float4 v = p[i];
    v.x = fmaxf(fmaf(v.x, sc[f0 + 0], sh[f0 + 0]), 0.f);
    v.y = fmaxf(fmaf(v.y, sc[f0 + 1], sh[f0 + 1]), 0.f);
    v.z = fmaxf(fmaf(v.z, sc[f0 + 2], sh[f0 + 2]), 0.f);
    v.w = fmaxf(fmaf(v.w, sc[f0 + 3], sh[f0 + 3]), 0.f);
    p[i] = v;
  }
}

extern "C" void kernel_launch(void* const* d_in, const int* in_sizes, int n_in,
                              void* d_out, int out_size, void* d_ws, size_t ws_size,
                              hipStream_t stream) {
  const float* x     = (const float*)d_in[0];
  const int*   src   = (const int*)d_in[1];
  const int*   dst   = (const int*)d_in[2];
  const float* ew    = (const float*)d_in[3];
  const float* W1    = (const float*)d_in[4];
  const float* b1    = (const float*)d_in[5];
  const float* W2    = (const float*)d_in[6];
  const float* b2    = (const float*)d_in[7];
  const float* eps   = (const float*)d_in[8];
  const float* gamma = (const float*)d_in[9];
  const float* beta  = (const float*)d_in[10];
  int E = in_sizes[1];

  // ws: counts[NN] | offs[NN] | sorted[E] i64 | xh[NN*64 halves] |
  //     {rank[E] overlaid by y[NN*64]} | sums[128] | W1t | W2t | bsum
  int*            counts = (int*)d_ws;
  int*            offs   = counts + NN;
  long long*      sorted = (long long*)(offs + NN);
  unsigned short* xh     = (unsigned short*)(sorted + E);
  float*          y      = (float*)(xh + NN * 64);
  int*            rank   = (int*)y;             // dead before gather writes y
  float*          sums   = y + NN * 64;
  float*          W1t    = sums + 128;
  float*          W2t    = W1t + 4096;
  int*            bsum   = (int*)(W2t + 4096);
  float*          h2     = (float*)d_out;

  int eb4 = (E / 4 + 255) / 256;
  prep_k<<<256, 256, 0, stream>>>(x, W1, W2, counts, sums, W1t, W2t, xh);
  histrank_k<<<eb4, 256, 0, stream>>>(dst, counts, rank, E);
  scana_k<<<NSB, 256, 0, stream>>>(counts, bsum);
  scanc_k<<<NSB, 256, 0, stream>>>(counts, bsum, offs);
  sort_k<<<eb4, 256, 0, stream>>>(dst, rank, src, ew, offs, sorted, E);
  gather_k<<<(NN + 15) / 16, 256, 0, stream>>>(x, xh, sorted, offs, counts, eps, y);
  mlp_k<<<(NN + 63) / 64, 256, 0, stream>>>(y, W1t, W2t, b1, b2, h2, sums);
  bn_k<<<3125, 256, 0, stream>>>(h2, sums, gamma, beta);
}

// Round 10
// 163.122 us; speedup vs baseline: 5.7850x; 1.0086x over previous
//
#include <hip/hip_runtime.h>
#include <hip/hip_fp16.h>

#define NN 50000
#define BN_EPS_C 1e-5f
#define SCAN_CHUNK 512
#define NSB ((NN + SCAN_CHUNK - 1) / SCAN_CHUNK)  // 98

__device__ inline unsigned short f2h_bits(float f) {
  __half h = __float2half_rn(f);
  return *reinterpret_cast<unsigned short*>(&h);
}
__device__ inline float h_bits2f(unsigned short b) {
  __half h;
  *reinterpret_cast<unsigned short*>(&h) = b;
  return __half2float(h);
}

// ---------------- prep: zero counts/sums, transpose W1,W2, x -> fp16 ----------
__global__ __launch_bounds__(256) void prep_k(const float* __restrict__ x,
                                              const float* __restrict__ W1,
                                              const float* __restrict__ W2,
                                              int* __restrict__ counts,
                                              float* __restrict__ sums,
                                              float* __restrict__ W1t,
                                              float* __restrict__ W2t,
                                              unsigned short* __restrict__ xh) {
  int gid = blockIdx.x * 256 + threadIdx.x;
  int stride = gridDim.x * 256;
  for (int i = gid; i < NN; i += stride) counts[i] = 0;
  if (gid < 128) sums[gid] = 0.f;
  for (int i = gid; i < 4096; i += stride) {
    int f = i >> 6, k = i & 63;
    W1t[k * 64 + f] = W1[i];  // Wt[k][f] = W[f][k]
    W2t[k * 64 + f] = W2[i];
  }
  const float4* x4 = (const float4*)x;
  uint2* xh2 = (uint2*)xh;
  for (int i = gid; i < NN * 16; i += stride) {
    float4 v = x4[i];
    __half2 h0 = __floats2half2_rn(v.x, v.y);
    __half2 h1 = __floats2half2_rn(v.z, v.w);
    uint2 u;
    u.x = *reinterpret_cast<unsigned*>(&h0);
    u.y = *reinterpret_cast<unsigned*>(&h1);
    xh2[i] = u;
  }
}

// ---------------- histogram of dst + per-edge rank capture ----------------
__global__ __launch_bounds__(256) void histrank_k(const int* __restrict__ dst,
                                                  int* __restrict__ counts,
                                                  int* __restrict__ rank, int E) {
  int t = blockIdx.x * 256 + threadIdx.x;
  int e = t * 4;
  if (e + 3 < E) {
    int4 d = *(const int4*)(dst + e);
    int4 r;
    r.x = atomicAdd(&counts[d.x], 1);
    r.y = atomicAdd(&counts[d.y], 1);
    r.z = atomicAdd(&counts[d.z], 1);
    r.w = atomicAdd(&counts[d.w], 1);
    *(int4*)(rank + e) = r;  // coalesced
  } else {
    for (; e < E; ++e) rank[e] = atomicAdd(&counts[dst[e]], 1);
  }
}

// ---------------- two-level scan: A) block sums ----------------
__global__ __launch_bounds__(256) void scana_k(const int* __restrict__ counts,
                                               int* __restrict__ bsum) {
  __shared__ int red[256];
  int b = blockIdx.x, tid = threadIdx.x;
  int i0 = b * SCAN_CHUNK + tid;
  int v = 0;
  if (i0 < NN) v += counts[i0];
  if (i0 + 256 < NN && tid + 256 < SCAN_CHUNK) v += counts[i0 + 256];
  red[tid] = v;
  __syncthreads();
  for (int s = 128; s > 0; s >>= 1) {
    if (tid < s) red[tid] += red[tid + s];
    __syncthreads();
  }
  if (tid == 0) bsum[b] = red[0];
}

// ---------------- B+C fused: per-block base reduce + local scan -> offs --------
__global__ __launch_bounds__(256) void scanc_k(const int* __restrict__ counts,
                                               const int* __restrict__ bsum,
                                               int* __restrict__ offs) {
  __shared__ int s[256];
  __shared__ int basev;
  int b = blockIdx.x, tid = threadIdx.x;
  s[tid] = (tid < b) ? bsum[tid] : 0;  // NSB=98 <= 256
  __syncthreads();
  for (int st = 128; st > 0; st >>= 1) {
    if (tid < st) s[tid] += s[tid + st];
    __syncthreads();
  }
  if (tid == 0) basev = s[0];
  __syncthreads();
  int base = basev;
  __syncthreads();  // everyone read basev; s reusable
  int i0 = b * SCAN_CHUNK + 2 * tid;
  int c0 = (i0 < NN) ? counts[i0] : 0;
  int c1 = (i0 + 1 < NN) ? counts[i0 + 1] : 0;
  int tsum = c0 + c1;
  s[tid] = tsum;
  __syncthreads();
  for (int off = 1; off < 256; off <<= 1) {
    int t = (tid >= off) ? s[tid - off] : 0;
    __syncthreads();
    s[tid] += t;
    __syncthreads();
  }
  int pre = base + s[tid] - tsum;
  if (i0 < NN) offs[i0] = pre;
  if (i0 + 1 < NN) offs[i0 + 1] = pre + c0;
}

// ---- atomic-free sorted edge build: sorted[offs[d]+rank[e]] = {w:fp16|src:u16} ----
__global__ __launch_bounds__(256) void sort_k(const int* __restrict__ dst,
                                              const int* __restrict__ rank,
                                              const int* __restrict__ srcv,
                                              const float* __restrict__ ew,
                                              const int* __restrict__ offs,
                                              unsigned* __restrict__ sorted, int E) {
  int t = blockIdx.x * 256 + threadIdx.x;
  int e = t * 4;
  if (e + 3 < E) {
    int4 d = *(const int4*)(dst + e);
    int4 r = *(const int4*)(rank + e);
    int4 s = *(const int4*)(srcv + e);
    float4 w = *(const float4*)(ew + e);
    unsigned v0 = (unsigned)s.x | ((unsigned)f2h_bits(w.x) << 16);
    unsigned v1 = (unsigned)s.y | ((unsigned)f2h_bits(w.y) << 16);
    unsigned v2 = (unsigned)s.z | ((unsigned)f2h_bits(w.z) << 16);
    unsigned v3 = (unsigned)s.w | ((unsigned)f2h_bits(w.w) << 16);
    __builtin_nontemporal_store(v0, &sorted[offs[d.x] + r.x]);
    __builtin_nontemporal_store(v1, &sorted[offs[d.y] + r.y]);
    __builtin_nontemporal_store(v2, &sorted[offs[d.z] + r.z]);
    __builtin_nontemporal_store(v3, &sorted[offs[d.w] + r.w]);
  } else {
    for (; e < E; ++e) {
      unsigned v = (unsigned)srcv[e] | ((unsigned)f2h_bits(ew[e]) << 16);
      sorted[offs[dst[e]] + rank[e]] = v;
    }
  }
}

// ------- fp16 accumulate: 8 halves (uint4) -> 8 f32 accumulators -------
__device__ inline void acc8(float* a, uint4 q, float wgt) {
  float2 f;
  f = __half22float2(*(const __half2*)&q.x);
  a[0] = fmaf(wgt, f.x, a[0]); a[1] = fmaf(wgt, f.y, a[1]);
  f = __half22float2(*(const __half2*)&q.y);
  a[2] = fmaf(wgt, f.x, a[2]); a[3] = fmaf(wgt, f.y, a[3]);
  f = __half22float2(*(const __half2*)&q.z);
  a[4] = fmaf(wgt, f.x, a[4]); a[5] = fmaf(wgt, f.y, a[5]);
  f = __half22float2(*(const __half2*)&q.w);
  a[6] = fmaf(wgt, f.x, a[6]); a[7] = fmaf(wgt, f.y, a[7]);
}

// ------- overflow tail for deg > 64 (rare) -------
__device__ inline void ovf8(float* a, const uint4* __restrict__ xh4,
                            const unsigned* __restrict__ sorted,
                            int off, int cnt, int lane, int es, int fo) {
  for (int b = 64; b < cnt; b += 64) {
    int take = min(64, cnt - b);
    unsigned m = 0;
    if (lane < take) m = sorted[off + b + lane];
    int nb = (take + 7) >> 3;
    for (int t = 0; t < nb; ++t) {
      int i0 = t * 8 + es;
      unsigned v = __shfl((int)m, i0);
      int s = (int)(v & 0xFFFFu);
      float wgt = h_bits2f((unsigned short)(v >> 16));
      uint4 q = xh4[s * 8 + fo];
      acc8(a, q, wgt);
    }
  }
}

// ---------------- gather: y[n] = (1+eps)*xh[n] + sum_e w_e * xh[src_e] --------
// es = lane>>3 (8 edge slots), fo = lane&7 (16B half-octet). One wave load
// fetches 8 fp16 rows; 4 nodes interleaved. Dense 1KB y-store via LDS bounce.
__global__ __launch_bounds__(256, 4) void gather_k(const unsigned short* __restrict__ xh,
                                                   const unsigned* __restrict__ sorted,
                                                   const int* __restrict__ offs,
                                                   const int* __restrict__ counts,
                                                   const float* __restrict__ eps,
                                                   float* __restrict__ y) {
  __shared__ float stage[4][4][64];  // [wave][node][feat], 4KB
  int tid = threadIdx.x;
  int lane = tid & 63;
  int wv = tid >> 6;
  int es = lane >> 3, fo = lane & 7;
  int nbase = (blockIdx.x * 4 + wv) * 4;
  if (nbase >= NN) return;
  const float c1 = 1.0f + eps[0];
  const uint4* xh4 = (const uint4*)xh;
  const uint2* xh2 = (const uint2*)xh;
  float4* y4 = (float4*)y;

  bool v1 = nbase + 1 < NN, v2 = nbase + 2 < NN, v3 = nbase + 3 < NN;
  int off0 = offs[nbase],              cnt0 = counts[nbase];
  int off1 = v1 ? offs[nbase + 1] : 0, cnt1 = v1 ? counts[nbase + 1] : 0;
  int off2 = v2 ? offs[nbase + 2] : 0, cnt2 = v2 ? counts[nbase + 2] : 0;
  int off3 = v3 ? offs[nbase + 3] : 0, cnt3 = v3 ? counts[nbase + 3] : 0;
  int tk0 = min(cnt0, 64), tk1 = min(cnt1, 64);
  int tk2 = min(cnt2, 64), tk3 = min(cnt3, 64);
  unsigned m0 = 0, m1 = 0, m2 = 0, m3 = 0;
  if (lane < tk0) m0 = sorted[off0 + lane];
  if (lane < tk1) m1 = sorted[off1 + lane];
  if (lane < tk2) m2 = sorted[off2 + lane];
  if (lane < tk3) m3 = sorted[off3 + lane];
  float a0[8] = {0, 0, 0, 0, 0, 0, 0, 0};
  float a1[8] = {0, 0, 0, 0, 0, 0, 0, 0};
  float a2[8] = {0, 0, 0, 0, 0, 0, 0, 0};
  float a3[8] = {0, 0, 0, 0, 0, 0, 0, 0};
  int nb0 = (tk0 + 7) >> 3, nb1 = (tk1 + 7) >> 3;
  int nb2 = (tk2 + 7) >> 3, nb3 = (tk3 + 7) >> 3;
  int nbM = max(max(nb0, nb1), max(nb2, nb3));
  for (int t = 0; t < nbM; ++t) {
    int i0 = t * 8 + es;  // <= 63 (t <= 7)
    unsigned e0 = (unsigned)__shfl((int)m0, i0);
    unsigned e1 = (unsigned)__shfl((int)m1, i0);
    unsigned e2 = (unsigned)__shfl((int)m2, i0);
    unsigned e3 = (unsigned)__shfl((int)m3, i0);
    int s0 = (int)(e0 & 0xFFFFu), s1 = (int)(e1 & 0xFFFFu);
    int s2 = (int)(e2 & 0xFFFFu), s3 = (int)(e3 & 0xFFFFu);
    float w0 = h_bits2f((unsigned short)(e0 >> 16));
    float w1 = h_bits2f((unsigned short)(e1 >> 16));
    float w2 = h_bits2f((unsigned short)(e2 >> 16));
    float w3 = h_bits2f((unsigned short)(e3 >> 16));
    uint4 q0 = xh4[s0 * 8 + fo];
    uint4 q1 = xh4[s1 * 8 + fo];
    uint4 q2 = xh4[s2 * 8 + fo];
    uint4 q3 = xh4[s3 * 8 + fo];
    acc8(a0, q0, w0);
    acc8(a1, q1, w1);
    acc8(a2, q2, w2);
    acc8(a3, q3, w3);
  }
  if (cnt0 > 64) ovf8(a0, xh4, sorted, off0, cnt0, lane, es, fo);
  if (cnt1 > 64) ovf8(a1, xh4, sorted, off1, cnt1, lane, es, fo);
  if (cnt2 > 64) ovf8(a2, xh4, sorted, off2, cnt2, lane, es, fo);
  if (cnt3 > 64) ovf8(a3, xh4, sorted, off3, cnt3, lane, es, fo);
  // reduce across es (lane bits 3,4,5)
#pragma unroll
  for (int j = 0; j < 8; ++j) {
    a0[j] += __shfl_xor(a0[j], 8); a0[j] += __shfl_xor(a0[j], 16); a0[j] += __shfl_xor(a0[j], 32);
    a1[j] += __shfl_xor(a1[j], 8); a1[j] += __shfl_xor(a1[j], 16); a1[j] += __shfl_xor(a1[j], 32);
    a2[j] += __shfl_xor(a2[j], 8); a2[j] += __shfl_xor(a2[j], 16); a2[j] += __shfl_xor(a2[j], 32);
    a3[j] += __shfl_xor(a3[j], 8); a3[j] += __shfl_xor(a3[j], 16); a3[j] += __shfl_xor(a3[j], 32);
  }
  // stage this wave's 4 nodes in LDS (es groups 0..3 write their node)
  if (es < 4) {
    const float* ag = (es == 0) ? a0 : (es == 1) ? a1 : (es == 2) ? a2 : a3;
    float4 lo = {ag[0], ag[1], ag[2], ag[3]};
    float4 hi = {ag[4], ag[5], ag[6], ag[7]};
    float* dp = &stage[wv][es][fo * 8];
    *(float4*)dp = lo;
    *(float4*)(dp + 4) = hi;
  }
  __builtin_amdgcn_wave_barrier();  // intra-wave: DS ops complete in order
  // dense store: lane l -> y4[nbase*16 + l] (1KB contiguous per wave)
  {
    int node = nbase + (lane >> 4);
    int q = lane & 15;
    if (node < NN) {
      float4 r = *(float4*)&stage[wv][lane >> 4][q * 4];
      uint2 xb = xh2[node * 16 + q];
      float2 xlo = __half22float2(*(const __half2*)&xb.x);
      float2 xhi = __half22float2(*(const __half2*)&xb.y);
      r.x = fmaf(c1, xlo.x, r.x); r.y = fmaf(c1, xlo.y, r.y);
      r.z = fmaf(c1, xhi.x, r.z); r.w = fmaf(c1, xhi.y, r.w);
      y4[node * 16 + q] = r;
    }
  }
}

// ---------------- MLP1(relu) + MLP2 + BN partials from y ----------------
__global__ __launch_bounds__(256) void mlp_k(const float* __restrict__ y,
                                             const float* __restrict__ W1t,
                                             const float* __restrict__ W2t,
                                             const float* __restrict__ b1,
                                             const float* __restrict__ b2,
                                             float* __restrict__ out,
                                             float* __restrict__ sums) {
  __shared__ float hT[64][66];   // [k][local node]
  __shared__ float WA[64][64];
  int tid = threadIdx.x;
  int tile0 = blockIdx.x * 64;
  for (int i = tid; i < 4096; i += 256) ((float*)WA)[i] = W1t[i];
  const float4* y4 = (const float4*)y;
  for (int i = tid; i < 1024; i += 256) {
    int nl = i >> 4, fq = i & 15;
    int node = tile0 + nl;
    float4 v = {0, 0, 0, 0};
    if (node < NN) v = y4[node * 16 + fq];
    hT[4 * fq + 0][nl] = v.x; hT[4 * fq + 1][nl] = v.y;
    hT[4 * fq + 2][nl] = v.z; hT[4 * fq + 3][nl] = v.w;
  }
  __syncthreads();

  int fg = tid & 15, ng = tid >> 4;
  int f0 = fg * 4, n0 = ng * 4;
  float4 bv = *(const float4*)(b1 + f0);
  float o[4][4];
#pragma unroll
  for (int n = 0; n < 4; ++n) {
    o[n][0] = bv.x; o[n][1] = bv.y; o[n][2] = bv.z; o[n][3] = bv.w;
  }
#pragma unroll 8
  for (int k = 0; k < 64; ++k) {
    float2 iA = *(const float2*)&hT[k][n0];
    float2 iB = *(const float2*)&hT[k][n0 + 2];
    float4 w4 = *(const float4*)&WA[k][f0];
    float in[4] = {iA.x, iA.y, iB.x, iB.y};
    float ww[4] = {w4.x, w4.y, w4.z, w4.w};
#pragma unroll
    for (int n = 0; n < 4; ++n)
#pragma unroll
      for (int j = 0; j < 4; ++j) o[n][j] = fmaf(in[n], ww[j], o[n][j]);
  }
#pragma unroll
  for (int n = 0; n < 4; ++n)
#pragma unroll
    for (int j = 0; j < 4; ++j) o[n][j] = fmaxf(o[n][j], 0.f);

  __syncthreads();  // all GEMM1 reads done
#pragma unroll
  for (int j = 0; j < 4; ++j) {
    float2 vA = {o[0][j], o[1][j]}, vB = {o[2][j], o[3][j]};
    *(float2*)&hT[f0 + j][n0] = vA;
    *(float2*)&hT[f0 + j][n0 + 2] = vB;
  }
  for (int i = tid; i < 4096; i += 256) ((float*)WA)[i] = W2t[i];
  __syncthreads();

  float4 bv2 = *(const float4*)(b2 + f0);
  float o2[4][4];
#pragma unroll
  for (int n = 0; n < 4; ++n) {
    o2[n][0] = bv2.x; o2[n][1] = bv2.y; o2[n][2] = bv2.z; o2[n][3] = bv2.w;
  }
#pragma unroll 8
  for (int k = 0; k < 64; ++k) {
    float2 iA = *(const float2*)&hT[k][n0];
    float2 iB = *(const float2*)&hT[k][n0 + 2];
    float4 w4 = *(const float4*)&WA[k][f0];
    float in[4] = {iA.x, iA.y, iB.x, iB.y};
    float ww[4] = {w4.x, w4.y, w4.z, w4.w};
#pragma unroll
    for (int n = 0; n < 4; ++n)
#pragma unroll
      for (int j = 0; j < 4; ++j) o2[n][j] = fmaf(in[n], ww[j], o2[n][j]);
  }
  __syncthreads();  // GEMM2 reads done; hT reusable as reduce scratch

  float s[4] = {0.f, 0.f, 0.f, 0.f}, q[4] = {0.f, 0.f, 0.f, 0.f};
#pragma unroll
  for (int n = 0; n < 4; ++n) {
    int node = tile0 + n0 + n;
    if (node < NN) {
      float4 v = {o2[n][0], o2[n][1], o2[n][2], o2[n][3]};
      *(float4*)&out[node * 64 + f0] = v;
#pragma unroll
      for (int j = 0; j < 4; ++j) {
        s[j] += o2[n][j];
        q[j] = fmaf(o2[n][j], o2[n][j], q[j]);
      }
    }
  }
  float* red = &hT[0][0];
#pragma unroll
  for (int j = 0; j < 4; ++j) {
    red[(f0 + j) * 16 + ng] = s[j];
    red[1024 + (f0 + j) * 16 + ng] = q[j];
  }
  __syncthreads();
  if (tid < 64) {
    float ss = 0.f, qq = 0.f;
    for (int g = 0; g < 16; ++g) {
      ss += red[tid * 16 + g];
      qq += red[1024 + tid * 16 + g];
    }
    atomicAdd(&sums[tid], ss);
    atomicAdd(&sums[64 + tid], qq);
  }
}

// ---------------- BN finalize + relu, in place on d_out ----------------
__global__ __launch_bounds__(256) void bn_k(float* __restrict__ h2out,
                                            const float* __restrict__ sums,
                                            const float* __restrict__ gamma,
                                            const float* __restrict__ beta) {
  __shared__ float sc[64], sh[64];
  int tid = threadIdx.x;
  if (tid < 64) {
    const float invN = 1.0f / NN;
    float mean = sums[tid] * invN;
    float var = fmaf(-mean, mean, sums[64 + tid] * invN);
    float s = gamma[tid] * rsqrtf(var + BN_EPS_C);
    sc[tid] = s;
    sh[tid] = fmaf(-mean, s, beta[tid]);
  }
  __syncthreads();
  int gid = blockIdx.x * 256 + tid;
  const int tot = NN * 16;
  float4* p = (float4*)h2out;
  for (int i = gid; i < tot; i += gridDim.x * 256) {
    int f0 = (i & 15) * 4;
    float4 v = p[i];
    v.x = fmaxf(fmaf(v.x, sc[f0 + 0], sh[f0 + 0]), 0.f);
    v.y = fmaxf(fmaf(v.y, sc[f0 + 1], sh[f0 + 1]), 0.f);
    v.z = fmaxf(fmaf(v.z, sc[f0 + 2], sh[f0 + 2]), 0.f);
    v.w = fmaxf(fmaf(v.w, sc[f0 + 3], sh[f0 + 3]), 0.f);
    p[i] = v;
  }
}

extern "C" void kernel_launch(void* const* d_in, const int* in_sizes, int n_in,
                              void* d_out, int out_size, void* d_ws, size_t ws_size,
                              hipStream_t stream) {
  const float* x     = (const float*)d_in[0];
  const int*   src   = (const int*)d_in[1];
  const int*   dst   = (const int*)d_in[2];
  const float* ew    = (const float*)d_in[3];
  const float* W1    = (const float*)d_in[4];
  const float* b1    = (const float*)d_in[5];
  const float* W2    = (const float*)d_in[6];
  const float* b2    = (const float*)d_in[7];
  const float* eps   = (const float*)d_in[8];
  const float* gamma = (const float*)d_in[9];
  const float* beta  = (const float*)d_in[10];
  int E = in_sizes[1];

  // ws: counts[NN] | offs[NN] | sorted[E] u32 | xh[NN*64 halves] |
  //     {rank[E] overlaid by y[NN*64]} | sums[128] | W1t | W2t | bsum
  int*            counts = (int*)d_ws;
  int*            offs   = counts + NN;
  unsigned*       sorted = (unsigned*)(offs + NN);
  unsigned short* xh     = (unsigned short*)(sorted + E);
  float*          y      = (float*)(xh + NN * 64);
  int*            rank   = (int*)y;             // dead before gather writes y
  float*          sums   = y + NN * 64;
  float*          W1t    = sums + 128;
  float*          W2t    = W1t + 4096;
  int*            bsum   = (int*)(W2t + 4096);
  float*          h2     = (float*)d_out;

  int eb4 = (E / 4 + 255) / 256;
  prep_k<<<256, 256, 0, stream>>>(x, W1, W2, counts, sums, W1t, W2t, xh);
  histrank_k<<<eb4, 256, 0, stream>>>(dst, counts, rank, E);
  scana_k<<<NSB, 256, 0, stream>>>(counts, bsum);
  scanc_k<<<NSB, 256, 0, stream>>>(counts, bsum, offs);
  sort_k<<<eb4, 256, 0, stream>>>(dst, rank, src, ew, offs, sorted, E);
  gather_k<<<(NN + 15) / 16, 256, 0, stream>>>(xh, sorted, offs, counts, eps, y);
  mlp_k<<<(NN + 63) / 64, 256, 0, stream>>>(y, W1t, W2t, b1, b2, h2, sums);
  bn_k<<<3125, 256, 0, stream>>>(h2, sums, gamma, beta);
}

// Round 11
// 147.090 us; speedup vs baseline: 6.4156x; 1.1090x over previous
//
#include <hip/hip_runtime.h>
#include <hip/hip_fp16.h>

#define NN 50000
#define BN_EPS_C 1e-5f
#define SCAN_CHUNK 512
#define NSB ((NN + SCAN_CHUNK - 1) / SCAN_CHUNK)  // 98

__device__ inline unsigned short f2h_bits(float f) {
  __half h = __float2half_rn(f);
  return *reinterpret_cast<unsigned short*>(&h);
}
__device__ inline float h_bits2f(unsigned short b) {
  __half h;
  *reinterpret_cast<unsigned short*>(&h) = b;
  return __half2float(h);
}

// ---------------- prep: zero counts/sums, transpose W1,W2, x -> fp16 ----------
__global__ __launch_bounds__(256) void prep_k(const float* __restrict__ x,
                                              const float* __restrict__ W1,
                                              const float* __restrict__ W2,
                                              int* __restrict__ counts,
                                              float* __restrict__ sums,
                                              float* __restrict__ W1t,
                                              float* __restrict__ W2t,
                                              unsigned short* __restrict__ xh) {
  int gid = blockIdx.x * 256 + threadIdx.x;
  int stride = gridDim.x * 256;
  for (int i = gid; i < NN; i += stride) counts[i] = 0;
  if (gid < 128) sums[gid] = 0.f;
  for (int i = gid; i < 4096; i += stride) {
    int f = i >> 6, k = i & 63;
    W1t[k * 64 + f] = W1[i];  // Wt[k][f] = W[f][k]
    W2t[k * 64 + f] = W2[i];
  }
  const float4* x4 = (const float4*)x;
  uint2* xh2 = (uint2*)xh;
  for (int i = gid; i < NN * 16; i += stride) {
    float4 v = x4[i];
    __half2 h0 = __floats2half2_rn(v.x, v.y);
    __half2 h1 = __floats2half2_rn(v.z, v.w);
    uint2 u;
    u.x = *reinterpret_cast<unsigned*>(&h0);
    u.y = *reinterpret_cast<unsigned*>(&h1);
    xh2[i] = u;
  }
}

// ---------------- histogram of dst + per-edge rank capture ----------------
__global__ __launch_bounds__(256) void histrank_k(const int* __restrict__ dst,
                                                  int* __restrict__ counts,
                                                  int* __restrict__ rank, int E) {
  int t = blockIdx.x * 256 + threadIdx.x;
  int e = t * 4;
  if (e + 3 < E) {
    int4 d = *(const int4*)(dst + e);
    int4 r;
    r.x = atomicAdd(&counts[d.x], 1);
    r.y = atomicAdd(&counts[d.y], 1);
    r.z = atomicAdd(&counts[d.z], 1);
    r.w = atomicAdd(&counts[d.w], 1);
    *(int4*)(rank + e) = r;  // coalesced
  } else {
    for (; e < E; ++e) rank[e] = atomicAdd(&counts[dst[e]], 1);
  }
}

// ---------------- two-level scan: A) block sums ----------------
__global__ __launch_bounds__(256) void scana_k(const int* __restrict__ counts,
                                               int* __restrict__ bsum) {
  __shared__ int red[256];
  int b = blockIdx.x, tid = threadIdx.x;
  int i0 = b * SCAN_CHUNK + tid;
  int v = 0;
  if (i0 < NN) v += counts[i0];
  if (i0 + 256 < NN && tid + 256 < SCAN_CHUNK) v += counts[i0 + 256];
  red[tid] = v;
  __syncthreads();
  for (int s = 128; s > 0; s >>= 1) {
    if (tid < s) red[tid] += red[tid + s];
    __syncthreads();
  }
  if (tid == 0) bsum[b] = red[0];
}

// ---------------- B+C fused: per-block base reduce + local scan -> offs --------
__global__ __launch_bounds__(256) void scanc_k(const int* __restrict__ counts,
                                               const int* __restrict__ bsum,
                                               int* __restrict__ offs) {
  __shared__ int s[256];
  __shared__ int basev;
  int b = blockIdx.x, tid = threadIdx.x;
  s[tid] = (tid < b) ? bsum[tid] : 0;  // NSB=98 <= 256
  __syncthreads();
  for (int st = 128; st > 0; st >>= 1) {
    if (tid < st) s[tid] += s[tid + st];
    __syncthreads();
  }
  if (tid == 0) basev = s[0];
  __syncthreads();
  int base = basev;
  __syncthreads();  // everyone read basev; s reusable
  int i0 = b * SCAN_CHUNK + 2 * tid;
  int c0 = (i0 < NN) ? counts[i0] : 0;
  int c1 = (i0 + 1 < NN) ? counts[i0 + 1] : 0;
  int tsum = c0 + c1;
  s[tid] = tsum;
  __syncthreads();
  for (int off = 1; off < 256; off <<= 1) {
    int t = (tid >= off) ? s[tid - off] : 0;
    __syncthreads();
    s[tid] += t;
    __syncthreads();
  }
  int pre = base + s[tid] - tsum;
  if (i0 < NN) offs[i0] = pre;
  if (i0 + 1 < NN) offs[i0 + 1] = pre + c0;
}

// ---- atomic-free sorted edge build: sorted[offs[d]+rank[e]] = {w:fp16|src:u16} ----
// Plain stores (NOT nontemporal): sorted is 3.2MB -> L2 absorbs the random
// 4B scatter and writes back full lines (~3.2MB HBM instead of ~51MB NT).
__global__ __launch_bounds__(256) void sort_k(const int* __restrict__ dst,
                                              const int* __restrict__ rank,
                                              const int* __restrict__ srcv,
                                              const float* __restrict__ ew,
                                              const int* __restrict__ offs,
                                              unsigned* __restrict__ sorted, int E) {
  int t = blockIdx.x * 256 + threadIdx.x;
  int e = t * 4;
  if (e + 3 < E) {
    int4 d = *(const int4*)(dst + e);
    int4 r = *(const int4*)(rank + e);
    int4 s = *(const int4*)(srcv + e);
    float4 w = *(const float4*)(ew + e);
    sorted[offs[d.x] + r.x] = (unsigned)s.x | ((unsigned)f2h_bits(w.x) << 16);
    sorted[offs[d.y] + r.y] = (unsigned)s.y | ((unsigned)f2h_bits(w.y) << 16);
    sorted[offs[d.z] + r.z] = (unsigned)s.z | ((unsigned)f2h_bits(w.z) << 16);
    sorted[offs[d.w] + r.w] = (unsigned)s.w | ((unsigned)f2h_bits(w.w) << 16);
  } else {
    for (; e < E; ++e) {
      unsigned v = (unsigned)srcv[e] | ((unsigned)f2h_bits(ew[e]) << 16);
      sorted[offs[dst[e]] + rank[e]] = v;
    }
  }
}

// ------- fp16 accumulate: 8 halves (uint4) -> 8 f32 accumulators -------
__device__ inline void acc8(float* a, uint4 q, float wgt) {
  float2 f;
  f = __half22float2(*(const __half2*)&q.x);
  a[0] = fmaf(wgt, f.x, a[0]); a[1] = fmaf(wgt, f.y, a[1]);
  f = __half22float2(*(const __half2*)&q.y);
  a[2] = fmaf(wgt, f.x, a[2]); a[3] = fmaf(wgt, f.y, a[3]);
  f = __half22float2(*(const __half2*)&q.z);
  a[4] = fmaf(wgt, f.x, a[4]); a[5] = fmaf(wgt, f.y, a[5]);
  f = __half22float2(*(const __half2*)&q.w);
  a[6] = fmaf(wgt, f.x, a[6]); a[7] = fmaf(wgt, f.y, a[7]);
}

// ------- overflow tail for deg > 64 (rare) -------
__device__ inline void ovf8(float* a, const uint4* __restrict__ xh4,
                            const unsigned* __restrict__ sorted,
                            int off, int cnt, int lane, int es, int fo) {
  for (int b = 64; b < cnt; b += 64) {
    int take = min(64, cnt - b);
    unsigned m = 0;
    if (lane < take) m = sorted[off + b + lane];
    int nb = (take + 7) >> 3;
    for (int t = 0; t < nb; ++t) {
      int i0 = t * 8 + es;
      unsigned v = __shfl((int)m, i0);
      int s = (int)(v & 0xFFFFu);
      float wgt = h_bits2f((unsigned short)(v >> 16));
      uint4 q = xh4[s * 8 + fo];
      acc8(a, q, wgt);
    }
  }
}

// ---------------- gather: y[n] = (1+eps)*xh[n] + sum_e w_e * xh[src_e] --------
// es = lane>>3 (8 edge slots), fo = lane&7 (16B half-octet). Unroll 2 ->
// 8 independent 16B loads in flight per iteration. Zero-padded meta (w=0)
// makes the over-read iteration harmless. Dense 1KB y-store via LDS bounce.
__global__ __launch_bounds__(256) void gather_k(const unsigned short* __restrict__ xh,
                                                const unsigned* __restrict__ sorted,
                                                const int* __restrict__ offs,
                                                const int* __restrict__ counts,
                                                const float* __restrict__ eps,
                                                float* __restrict__ y) {
  __shared__ float stage[4][4][64];  // [wave][node][feat], 4KB
  int tid = threadIdx.x;
  int lane = tid & 63;
  int wv = tid >> 6;
  int es = lane >> 3, fo = lane & 7;
  int nbase = (blockIdx.x * 4 + wv) * 4;
  if (nbase >= NN) return;
  const float c1 = 1.0f + eps[0];
  const uint4* xh4 = (const uint4*)xh;
  const uint2* xh2 = (const uint2*)xh;
  float4* y4 = (float4*)y;

  bool v1 = nbase + 1 < NN, v2 = nbase + 2 < NN, v3 = nbase + 3 < NN;
  int off0 = offs[nbase],              cnt0 = counts[nbase];
  int off1 = v1 ? offs[nbase + 1] : 0, cnt1 = v1 ? counts[nbase + 1] : 0;
  int off2 = v2 ? offs[nbase + 2] : 0, cnt2 = v2 ? counts[nbase + 2] : 0;
  int off3 = v3 ? offs[nbase + 3] : 0, cnt3 = v3 ? counts[nbase + 3] : 0;
  int tk0 = min(cnt0, 64), tk1 = min(cnt1, 64);
  int tk2 = min(cnt2, 64), tk3 = min(cnt3, 64);
  unsigned m0 = 0, m1 = 0, m2 = 0, m3 = 0;
  if (lane < tk0) m0 = sorted[off0 + lane];
  if (lane < tk1) m1 = sorted[off1 + lane];
  if (lane < tk2) m2 = sorted[off2 + lane];
  if (lane < tk3) m3 = sorted[off3 + lane];
  float a0[8] = {0, 0, 0, 0, 0, 0, 0, 0};
  float a1[8] = {0, 0, 0, 0, 0, 0, 0, 0};
  float a2[8] = {0, 0, 0, 0, 0, 0, 0, 0};
  float a3[8] = {0, 0, 0, 0, 0, 0, 0, 0};
  int nb0 = (tk0 + 7) >> 3, nb1 = (tk1 + 7) >> 3;
  int nb2 = (tk2 + 7) >> 3, nb3 = (tk3 + 7) >> 3;
  int nbM = max(max(nb0, nb1), max(nb2, nb3));
  // unroll 2: 8 broadcasts + 8 loads in flight, then 8 acc8
  for (int t = 0; t < nbM; t += 2) {
    int i0 = t * 8 + es;        // <= 55 when t <= 6
    int i1 = i0 + 8;            // <= 63; lanes beyond tk hold m=0 -> w=0
    unsigned e00 = (unsigned)__shfl((int)m0, i0), e01 = (unsigned)__shfl((int)m0, i1);
    unsigned e10 = (unsigned)__shfl((int)m1, i0), e11 = (unsigned)__shfl((int)m1, i1);
    unsigned e20 = (unsigned)__shfl((int)m2, i0), e21 = (unsigned)__shfl((int)m2, i1);
    unsigned e30 = (unsigned)__shfl((int)m3, i0), e31 = (unsigned)__shfl((int)m3, i1);
    uint4 q00 = xh4[(int)(e00 & 0xFFFFu) * 8 + fo];
    uint4 q01 = xh4[(int)(e01 & 0xFFFFu) * 8 + fo];
    uint4 q10 = xh4[(int)(e10 & 0xFFFFu) * 8 + fo];
    uint4 q11 = xh4[(int)(e11 & 0xFFFFu) * 8 + fo];
    uint4 q20 = xh4[(int)(e20 & 0xFFFFu) * 8 + fo];
    uint4 q21 = xh4[(int)(e21 & 0xFFFFu) * 8 + fo];
    uint4 q30 = xh4[(int)(e30 & 0xFFFFu) * 8 + fo];
    uint4 q31 = xh4[(int)(e31 & 0xFFFFu) * 8 + fo];
    acc8(a0, q00, h_bits2f((unsigned short)(e00 >> 16)));
    acc8(a1, q10, h_bits2f((unsigned short)(e10 >> 16)));
    acc8(a2, q20, h_bits2f((unsigned short)(e20 >> 16)));
    acc8(a3, q30, h_bits2f((unsigned short)(e30 >> 16)));
    acc8(a0, q01, h_bits2f((unsigned short)(e01 >> 16)));
    acc8(a1, q11, h_bits2f((unsigned short)(e11 >> 16)));
    acc8(a2, q21, h_bits2f((unsigned short)(e21 >> 16)));
    acc8(a3, q31, h_bits2f((unsigned short)(e31 >> 16)));
  }
  if (cnt0 > 64) ovf8(a0, xh4, sorted, off0, cnt0, lane, es, fo);
  if (cnt1 > 64) ovf8(a1, xh4, sorted, off1, cnt1, lane, es, fo);
  if (cnt2 > 64) ovf8(a2, xh4, sorted, off2, cnt2, lane, es, fo);
  if (cnt3 > 64) ovf8(a3, xh4, sorted, off3, cnt3, lane, es, fo);
  // reduce across es (lane bits 3,4,5)
#pragma unroll
  for (int j = 0; j < 8; ++j) {
    a0[j] += __shfl_xor(a0[j], 8); a0[j] += __shfl_xor(a0[j], 16); a0[j] += __shfl_xor(a0[j], 32);
    a1[j] += __shfl_xor(a1[j], 8); a1[j] += __shfl_xor(a1[j], 16); a1[j] += __shfl_xor(a1[j], 32);
    a2[j] += __shfl_xor(a2[j], 8); a2[j] += __shfl_xor(a2[j], 16); a2[j] += __shfl_xor(a2[j], 32);
    a3[j] += __shfl_xor(a3[j], 8); a3[j] += __shfl_xor(a3[j], 16); a3[j] += __shfl_xor(a3[j], 32);
  }
  // stage this wave's 4 nodes in LDS (es groups 0..3 write their node)
  if (es < 4) {
    const float* ag = (es == 0) ? a0 : (es == 1) ? a1 : (es == 2) ? a2 : a3;
    float4 lo = {ag[0], ag[1], ag[2], ag[3]};
    float4 hi = {ag[4], ag[5], ag[6], ag[7]};
    float* dp = &stage[wv][es][fo * 8];
    *(float4*)dp = lo;
    *(float4*)(dp + 4) = hi;
  }
  __builtin_amdgcn_wave_barrier();  // intra-wave: DS ops complete in order
  // dense store: lane l -> y4[nbase*16 + l] (1KB contiguous per wave)
  {
    int node = nbase + (lane >> 4);
    int q = lane & 15;
    if (node < NN) {
      float4 r = *(float4*)&stage[wv][lane >> 4][q * 4];
      uint2 xb = xh2[node * 16 + q];
      float2 xlo = __half22float2(*(const __half2*)&xb.x);
      float2 xhi = __half22float2(*(const __half2*)&xb.y);
      r.x = fmaf(c1, xlo.x, r.x); r.y = fmaf(c1, xlo.y, r.y);
      r.z = fmaf(c1, xhi.x, r.z); r.w = fmaf(c1, xhi.y, r.w);
      y4[node * 16 + q] = r;
    }
  }
}

// ---------------- MLP1(relu) + MLP2 + BN partials from y ----------------
__global__ __launch_bounds__(256) void mlp_k(const float* __restrict__ y,
                                             const float* __restrict__ W1t,
                                             const float* __restrict__ W2t,
                                             const float* __restrict__ b1,
                                             const float* __restrict__ b2,
                                             float* __restrict__ out,
                                             float* __restrict__ sums) {
  __shared__ float hT[64][66];   // [k][local node]
  __shared__ float WA[64][64];
  int tid = threadIdx.x;
  int tile0 = blockIdx.x * 64;
  for (int i = tid; i < 4096; i += 256) ((float*)WA)[i] = W1t[i];
  const float4* y4 = (const float4*)y;
  for (int i = tid; i < 1024; i += 256) {
    int nl = i >> 4, fq = i & 15;
    int node = tile0 + nl;
    float4 v = {0, 0, 0, 0};
    if (node < NN) v = y4[node * 16 + fq];
    hT[4 * fq + 0][nl] = v.x; hT[4 * fq + 1][nl] = v.y;
    hT[4 * fq + 2][nl] = v.z; hT[4 * fq + 3][nl] = v.w;
  }
  __syncthreads();

  int fg = tid & 15, ng = tid >> 4;
  int f0 = fg * 4, n0 = ng * 4;
  float4 bv = *(const float4*)(b1 + f0);
  float o[4][4];
#pragma unroll
  for (int n = 0; n < 4; ++n) {
    o[n][0] = bv.x; o[n][1] = bv.y; o[n][2] = bv.z; o[n][3] = bv.w;
  }
#pragma unroll 8
  for (int k = 0; k < 64; ++k) {
    float2 iA = *(const float2*)&hT[k][n0];
    float2 iB = *(const float2*)&hT[k][n0 + 2];
    float4 w4 = *(const float4*)&WA[k][f0];
    float in[4] = {iA.x, iA.y, iB.x, iB.y};
    float ww[4] = {w4.x, w4.y, w4.z, w4.w};
#pragma unroll
    for (int n = 0; n < 4; ++n)
#pragma unroll
      for (int j = 0; j < 4; ++j) o[n][j] = fmaf(in[n], ww[j], o[n][j]);
  }
#pragma unroll
  for (int n = 0; n < 4; ++n)
#pragma unroll
    for (int j = 0; j < 4; ++j) o[n][j] = fmaxf(o[n][j], 0.f);

  __syncthreads();  // all GEMM1 reads done
#pragma unroll
  for (int j = 0; j < 4; ++j) {
    float2 vA = {o[0][j], o[1][j]}, vB = {o[2][j], o[3][j]};
    *(float2*)&hT[f0 + j][n0] = vA;
    *(float2*)&hT[f0 + j][n0 + 2] = vB;
  }
  for (int i = tid; i < 4096; i += 256) ((float*)WA)[i] = W2t[i];
  __syncthreads();

  float4 bv2 = *(const float4*)(b2 + f0);
  float o2[4][4];
#pragma unroll
  for (int n = 0; n < 4; ++n) {
    o2[n][0] = bv2.x; o2[n][1] = bv2.y; o2[n][2] = bv2.z; o2[n][3] = bv2.w;
  }
#pragma unroll 8
  for (int k = 0; k < 64; ++k) {
    float2 iA = *(const float2*)&hT[k][n0];
    float2 iB = *(const float2*)&hT[k][n0 + 2];
    float4 w4 = *(const float4*)&WA[k][f0];
    float in[4] = {iA.x, iA.y, iB.x, iB.y};
    float ww[4] = {w4.x, w4.y, w4.z, w4.w};
#pragma unroll
    for (int n = 0; n < 4; ++n)
#pragma unroll
      for (int j = 0; j < 4; ++j) o2[n][j] = fmaf(in[n], ww[j], o2[n][j]);
  }
  __syncthreads();  // GEMM2 reads done; hT reusable as reduce scratch

  float s[4] = {0.f, 0.f, 0.f, 0.f}, q[4] = {0.f, 0.f, 0.f, 0.f};
#pragma unroll
  for (int n = 0; n < 4; ++n) {
    int node = tile0 + n0 + n;
    if (node < NN) {
      float4 v = {o2[n][0], o2[n][1], o2[n][2], o2[n][3]};
      *(float4*)&out[node * 64 + f0] = v;
#pragma unroll
      for (int j = 0; j < 4; ++j) {
        s[j] += o2[n][j];
        q[j] = fmaf(o2[n][j], o2[n][j], q[j]);
      }
    }
  }
  float* red = &hT[0][0];
#pragma unroll
  for (int j = 0; j < 4; ++j) {
    red[(f0 + j) * 16 + ng] = s[j];
    red[1024 + (f0 + j) * 16 + ng] = q[j];
  }
  __syncthreads();
  if (tid < 64) {
    float ss = 0.f, qq = 0.f;
    for (int g = 0; g < 16; ++g) {
      ss += red[tid * 16 + g];
      qq += red[1024 + tid * 16 + g];
    }
    atomicAdd(&sums[tid], ss);
    atomicAdd(&sums[64 + tid], qq);
  }
}

// ---------------- BN finalize + relu, in place on d_out ----------------
__global__ __launch_bounds__(256) void bn_k(float* __restrict__ h2out,
                                            const float* __restrict__ sums,
                                            const float* __restrict__ gamma,
                                            const float* __restrict__ beta) {
  __shared__ float sc[64], sh[64];
  int tid = threadIdx.x;
  if (tid < 64) {
    const float invN = 1.0f / NN;
    float mean = sums[tid] * invN;
    float var = fmaf(-mean, mean, sums[64 + tid] * invN);
    float s = gamma[tid] * rsqrtf(var + BN_EPS_C);
    sc[tid] = s;
    sh[tid] = fmaf(-mean, s, beta[tid]);
  }
  __syncthreads();
  int gid = blockIdx.x * 256 + tid;
  const int tot = NN * 16;
  float4* p = (float4*)h2out;
  for (int i = gid; i < tot; i += gridDim.x * 256) {
    int f0 = (i & 15) * 4;
    float4 v = p[i];
    v.x = fmaxf(fmaf(v.x, sc[f0 + 0], sh[f0 + 0]), 0.f);
    v.y = fmaxf(fmaf(v.y, sc[f0 + 1], sh[f0 + 1]), 0.f);
    v.z = fmaxf(fmaf(v.z, sc[f0 + 2], sh[f0 + 2]), 0.f);
    v.w = fmaxf(fmaf(v.w, sc[f0 + 3], sh[f0 + 3]), 0.f);
    p[i] = v;
  }
}

extern "C" void kernel_launch(void* const* d_in, const int* in_sizes, int n_in,
                              void* d_out, int out_size, void* d_ws, size_t ws_size,
                              hipStream_t stream) {
  const float* x     = (const float*)d_in[0];
  const int*   src   = (const int*)d_in[1];
  const int*   dst   = (const int*)d_in[2];
  const float* ew    = (const float*)d_in[3];
  const float* W1    = (const float*)d_in[4];
  const float* b1    = (const float*)d_in[5];
  const float* W2    = (const float*)d_in[6];
  const float* b2    = (const float*)d_in[7];
  const float* eps   = (const float*)d_in[8];
  const float* gamma = (const float*)d_in[9];
  const float* beta  = (const float*)d_in[10];
  int E = in_sizes[1];

  // ws: counts[NN] | offs[NN] | sorted[E] u32 | xh[NN*64 halves] |
  //     {rank[E] overlaid by y[NN*64]} | sums[128] | W1t | W2t | bsum
  int*            counts = (int*)d_ws;
  int*            offs   = counts + NN;
  unsigned*       sorted = (unsigned*)(offs + NN);
  unsigned short* xh     = (unsigned short*)(sorted + E);
  float*          y      = (float*)(xh + NN * 64);
  int*            rank   = (int*)y;             // dead before gather writes y
  float*          sums   = y + NN * 64;
  float*          W1t    = sums + 128;
  float*          W2t    = W1t + 4096;
  int*            bsum   = (int*)(W2t + 4096);
  float*          h2     = (float*)d_out;

  int eb4 = (E / 4 + 255) / 256;
  prep_k<<<256, 256, 0, stream>>>(x, W1, W2, counts, sums, W1t, W2t, xh);
  histrank_k<<<eb4, 256, 0, stream>>>(dst, counts, rank, E);
  scana_k<<<NSB, 256, 0, stream>>>(counts, bsum);
  scanc_k<<<NSB, 256, 0, stream>>>(counts, bsum, offs);
  sort_k<<<eb4, 256, 0, stream>>>(dst, rank, src, ew, offs, sorted, E);
  gather_k<<<(NN + 15) / 16, 256, 0, stream>>>(xh, sorted, offs, counts, eps, y);
  mlp_k<<<(NN + 63) / 64, 256, 0, stream>>>(y, W1t, W2t, b1, b2, h2, sums);
  bn_k<<<3125, 256, 0, stream>>>(h2, sums, gamma, beta);
}

// Round 12
// 141.319 us; speedup vs baseline: 6.6775x; 1.0408x over previous
//
#include <hip/hip_runtime.h>
#include <hip/hip_fp16.h>

#define NN 50000
#define BN_EPS_C 1e-5f
#define SCAN_CHUNK 512
#define NSB ((NN + SCAN_CHUNK - 1) / SCAN_CHUNK)  // 98

__device__ inline unsigned short f2h_bits(float f) {
  __half h = __float2half_rn(f);
  return *reinterpret_cast<unsigned short*>(&h);
}
__device__ inline float h_bits2f(unsigned short b) {
  __half h;
  *reinterpret_cast<unsigned short*>(&h) = b;
  return __half2float(h);
}

// ---------------- prep: zero counts/sums, transpose W1,W2, x -> fp16 ----------
__global__ __launch_bounds__(256) void prep_k(const float* __restrict__ x,
                                              const float* __restrict__ W1,
                                              const float* __restrict__ W2,
                                              int* __restrict__ counts,
                                              float* __restrict__ sums,
                                              float* __restrict__ W1t,
                                              float* __restrict__ W2t,
                                              unsigned short* __restrict__ xh) {
  int gid = blockIdx.x * 256 + threadIdx.x;
  int stride = gridDim.x * 256;
  for (int i = gid; i < NN; i += stride) counts[i] = 0;
  if (gid < 128) sums[gid] = 0.f;
  for (int i = gid; i < 4096; i += stride) {
    int f = i >> 6, k = i & 63;
    W1t[k * 64 + f] = W1[i];  // Wt[k][f] = W[f][k]
    W2t[k * 64 + f] = W2[i];
  }
  const float4* x4 = (const float4*)x;
  uint2* xh2 = (uint2*)xh;
  for (int i = gid; i < NN * 16; i += stride) {
    float4 v = x4[i];
    __half2 h0 = __floats2half2_rn(v.x, v.y);
    __half2 h1 = __floats2half2_rn(v.z, v.w);
    uint2 u;
    u.x = *reinterpret_cast<unsigned*>(&h0);
    u.y = *reinterpret_cast<unsigned*>(&h1);
    xh2[i] = u;
  }
}

// ---------------- histogram of dst + per-edge rank capture ----------------
__global__ __launch_bounds__(256) void histrank_k(const int* __restrict__ dst,
                                                  int* __restrict__ counts,
                                                  int* __restrict__ rank, int E) {
  int t = blockIdx.x * 256 + threadIdx.x;
  int e = t * 4;
  if (e + 3 < E) {
    int4 d = *(const int4*)(dst + e);
    int4 r;
    r.x = atomicAdd(&counts[d.x], 1);
    r.y = atomicAdd(&counts[d.y], 1);
    r.z = atomicAdd(&counts[d.z], 1);
    r.w = atomicAdd(&counts[d.w], 1);
    *(int4*)(rank + e) = r;  // coalesced
  } else {
    for (; e < E; ++e) rank[e] = atomicAdd(&counts[dst[e]], 1);
  }
}

// ---------------- two-level scan: A) block sums ----------------
__global__ __launch_bounds__(256) void scana_k(const int* __restrict__ counts,
                                               int* __restrict__ bsum) {
  __shared__ int red[256];
  int b = blockIdx.x, tid = threadIdx.x;
  int i0 = b * SCAN_CHUNK + tid;
  int v = 0;
  if (i0 < NN) v += counts[i0];
  if (i0 + 256 < NN && tid + 256 < SCAN_CHUNK) v += counts[i0 + 256];
  red[tid] = v;
  __syncthreads();
  for (int s = 128; s > 0; s >>= 1) {
    if (tid < s) red[tid] += red[tid + s];
    __syncthreads();
  }
  if (tid == 0) bsum[b] = red[0];
}

// ---------------- B+C fused: per-block base reduce + local scan -> offs --------
__global__ __launch_bounds__(256) void scanc_k(const int* __restrict__ counts,
                                               const int* __restrict__ bsum,
                                               int* __restrict__ offs) {
  __shared__ int s[256];
  __shared__ int basev;
  int b = blockIdx.x, tid = threadIdx.x;
  s[tid] = (tid < b) ? bsum[tid] : 0;  // NSB=98 <= 256
  __syncthreads();
  for (int st = 128; st > 0; st >>= 1) {
    if (tid < st) s[tid] += s[tid + st];
    __syncthreads();
  }
  if (tid == 0) basev = s[0];
  __syncthreads();
  int base = basev;
  __syncthreads();  // everyone read basev; s reusable
  int i0 = b * SCAN_CHUNK + 2 * tid;
  int c0 = (i0 < NN) ? counts[i0] : 0;
  int c1 = (i0 + 1 < NN) ? counts[i0 + 1] : 0;
  int tsum = c0 + c1;
  s[tid] = tsum;
  __syncthreads();
  for (int off = 1; off < 256; off <<= 1) {
    int t = (tid >= off) ? s[tid - off] : 0;
    __syncthreads();
    s[tid] += t;
    __syncthreads();
  }
  int pre = base + s[tid] - tsum;
  if (i0 < NN) offs[i0] = pre;
  if (i0 + 1 < NN) offs[i0 + 1] = pre + c0;
}

// ---- atomic-free sorted edge build: sorted[offs[d]+rank[e]] = {w:fp16|src:u16} ----
// Plain stores: sorted is 3.2MB -> L2 absorbs the random 4B scatter.
__global__ __launch_bounds__(256) void sort_k(const int* __restrict__ dst,
                                              const int* __restrict__ rank,
                                              const int* __restrict__ srcv,
                                              const float* __restrict__ ew,
                                              const int* __restrict__ offs,
                                              unsigned* __restrict__ sorted, int E) {
  int t = blockIdx.x * 256 + threadIdx.x;
  int e = t * 4;
  if (e + 3 < E) {
    int4 d = *(const int4*)(dst + e);
    int4 r = *(const int4*)(rank + e);
    int4 s = *(const int4*)(srcv + e);
    float4 w = *(const float4*)(ew + e);
    sorted[offs[d.x] + r.x] = (unsigned)s.x | ((unsigned)f2h_bits(w.x) << 16);
    sorted[offs[d.y] + r.y] = (unsigned)s.y | ((unsigned)f2h_bits(w.y) << 16);
    sorted[offs[d.z] + r.z] = (unsigned)s.z | ((unsigned)f2h_bits(w.z) << 16);
    sorted[offs[d.w] + r.w] = (unsigned)s.w | ((unsigned)f2h_bits(w.w) << 16);
  } else {
    for (; e < E; ++e) {
      unsigned v = (unsigned)srcv[e] | ((unsigned)f2h_bits(ew[e]) << 16);
      sorted[offs[dst[e]] + rank[e]] = v;
    }
  }
}

// ------- fp16 accumulate: 8 halves (uint4) -> 8 f32 accumulators -------
__device__ inline void acc8(float* a, uint4 q, float wgt) {
  float2 f;
  f = __half22float2(*(const __half2*)&q.x);
  a[0] = fmaf(wgt, f.x, a[0]); a[1] = fmaf(wgt, f.y, a[1]);
  f = __half22float2(*(const __half2*)&q.y);
  a[2] = fmaf(wgt, f.x, a[2]); a[3] = fmaf(wgt, f.y, a[3]);
  f = __half22float2(*(const __half2*)&q.z);
  a[4] = fmaf(wgt, f.x, a[4]); a[5] = fmaf(wgt, f.y, a[5]);
  f = __half22float2(*(const __half2*)&q.w);
  a[6] = fmaf(wgt, f.x, a[6]); a[7] = fmaf(wgt, f.y, a[7]);
}

// ------- overflow tail for deg > 64 (rare) -------
__device__ inline void ovf8(float* a, const uint4* __restrict__ xh4,
                            const unsigned* __restrict__ sorted,
                            int off, int cnt, int lane, int es, int fo) {
  for (int b = 64; b < cnt; b += 64) {
    int take = min(64, cnt - b);
    unsigned m = 0;
    if (lane < take) m = sorted[off + b + lane];
    int nb = (take + 7) >> 3;
    for (int t = 0; t < nb; ++t) {
      int i0 = t * 8 + es;
      unsigned v = __shfl((int)m, i0);
      int s = (int)(v & 0xFFFFu);
      float wgt = h_bits2f((unsigned short)(v >> 16));
      uint4 q = xh4[s * 8 + fo];
      acc8(a, q, wgt);
    }
  }
}

// ---------------- gather: y[n] = (1+eps)*xh[n] + sum_e w_e * xh[src_e] --------
// 8 nodes per wave: 8 meta streams, 16 independent 16B gather loads in flight
// per unrolled iteration. es = lane>>3 (8 edge slots), fo = lane&7 (16B octet).
// All register arrays indexed only in fully-unrolled loops (no scratch).
__global__ __launch_bounds__(256) void gather_k(const unsigned short* __restrict__ xh,
                                                const unsigned* __restrict__ sorted,
                                                const int* __restrict__ offs,
                                                const int* __restrict__ counts,
                                                const float* __restrict__ eps,
                                                float* __restrict__ y) {
  __shared__ float stage[4][8][64];  // [wave][node][feat], 8KB
  int tid = threadIdx.x;
  int lane = tid & 63;
  int wv = tid >> 6;
  int es = lane >> 3, fo = lane & 7;
  int nbase = (blockIdx.x * 4 + wv) * 8;
  if (nbase >= NN) return;
  const float c1 = 1.0f + eps[0];
  const uint4* xh4 = (const uint4*)xh;
  const uint2* xh2 = (const uint2*)xh;
  float4* y4 = (float4*)y;

  int offv[8], cntv[8];
  unsigned mv[8];
#pragma unroll
  for (int i = 0; i < 8; ++i) {
    int node = nbase + i;
    bool vld = node < NN;
    offv[i] = vld ? offs[node] : 0;
    cntv[i] = vld ? counts[node] : 0;
  }
#pragma unroll
  for (int i = 0; i < 8; ++i) {
    int tk = min(cntv[i], 64);
    mv[i] = (lane < tk) ? sorted[offv[i] + lane] : 0u;
  }
  float acc[8][8] = {};
  int nbM = 0;
#pragma unroll
  for (int i = 0; i < 8; ++i) nbM = max(nbM, (min(cntv[i], 64) + 7) >> 3);

  for (int t = 0; t < nbM; t += 2) {
    int i0 = t * 8 + es;  // <= 55 (t <= 6)
    int i1 = i0 + 8;      // <= 63; lanes past tk hold m=0 -> w=0
    unsigned e0[8], e1[8];
    uint4 q0[8], q1[8];
#pragma unroll
    for (int i = 0; i < 8; ++i) {
      e0[i] = (unsigned)__shfl((int)mv[i], i0);
      e1[i] = (unsigned)__shfl((int)mv[i], i1);
    }
#pragma unroll
    for (int i = 0; i < 8; ++i) q0[i] = xh4[(int)(e0[i] & 0xFFFFu) * 8 + fo];
#pragma unroll
    for (int i = 0; i < 8; ++i) q1[i] = xh4[(int)(e1[i] & 0xFFFFu) * 8 + fo];
#pragma unroll
    for (int i = 0; i < 8; ++i)
      acc8(acc[i], q0[i], h_bits2f((unsigned short)(e0[i] >> 16)));
#pragma unroll
    for (int i = 0; i < 8; ++i)
      acc8(acc[i], q1[i], h_bits2f((unsigned short)(e1[i] >> 16)));
  }
#pragma unroll
  for (int i = 0; i < 8; ++i)
    if (cntv[i] > 64) ovf8(acc[i], xh4, sorted, offv[i], cntv[i], lane, es, fo);

  // reduce across es (lane bits 3,4,5)
#pragma unroll
  for (int i = 0; i < 8; ++i)
#pragma unroll
    for (int j = 0; j < 8; ++j) {
      acc[i][j] += __shfl_xor(acc[i][j], 8);
      acc[i][j] += __shfl_xor(acc[i][j], 16);
      acc[i][j] += __shfl_xor(acc[i][j], 32);
    }
  // stage: es group i holds node nbase+i's reduced row in its 8 lanes
#pragma unroll
  for (int i = 0; i < 8; ++i) {
    if (es == i) {
      float4 lo = {acc[i][0], acc[i][1], acc[i][2], acc[i][3]};
      float4 hi = {acc[i][4], acc[i][5], acc[i][6], acc[i][7]};
      float* dp = &stage[wv][i][fo * 8];
      *(float4*)dp = lo;
      *(float4*)(dp + 4) = hi;
    }
  }
  __builtin_amdgcn_wave_barrier();  // intra-wave ordering of DS ops
  // dense store: 2KB contiguous per wave (2 float4 per lane), residual fused
#pragma unroll
  for (int h = 0; h < 2; ++h) {
    int node = nbase + h * 4 + (lane >> 4);
    int q = lane & 15;
    if (node < NN) {
      float4 r = *(float4*)&stage[wv][h * 4 + (lane >> 4)][q * 4];
      uint2 xb = xh2[node * 16 + q];
      float2 xlo = __half22float2(*(const __half2*)&xb.x);
      float2 xhi = __half22float2(*(const __half2*)&xb.y);
      r.x = fmaf(c1, xlo.x, r.x); r.y = fmaf(c1, xlo.y, r.y);
      r.z = fmaf(c1, xhi.x, r.z); r.w = fmaf(c1, xhi.y, r.w);
      y4[node * 16 + q] = r;
    }
  }
}

// ---------------- MLP1(relu) + MLP2 + BN partials from y ----------------
__global__ __launch_bounds__(256) void mlp_k(const float* __restrict__ y,
                                             const float* __restrict__ W1t,
                                             const float* __restrict__ W2t,
                                             const float* __restrict__ b1,
                                             const float* __restrict__ b2,
                                             float* __restrict__ out,
                                             float* __restrict__ sums) {
  __shared__ float hT[64][66];   // [k][local node]
  __shared__ float WA[64][64];
  int tid = threadIdx.x;
  int tile0 = blockIdx.x * 64;
  for (int i = tid; i < 4096; i += 256) ((float*)WA)[i] = W1t[i];
  const float4* y4 = (const float4*)y;
  for (int i = tid; i < 1024; i += 256) {
    int nl = i >> 4, fq = i & 15;
    int node = tile0 + nl;
    float4 v = {0, 0, 0, 0};
    if (node < NN) v = y4[node * 16 + fq];
    hT[4 * fq + 0][nl] = v.x; hT[4 * fq + 1][nl] = v.y;
    hT[4 * fq + 2][nl] = v.z; hT[4 * fq + 3][nl] = v.w;
  }
  __syncthreads();

  int fg = tid & 15, ng = tid >> 4;
  int f0 = fg * 4, n0 = ng * 4;
  float4 bv = *(const float4*)(b1 + f0);
  float o[4][4];
#pragma unroll
  for (int n = 0; n < 4; ++n) {
    o[n][0] = bv.x; o[n][1] = bv.y; o[n][2] = bv.z; o[n][3] = bv.w;
  }
#pragma unroll 8
  for (int k = 0; k < 64; ++k) {
    float2 iA = *(const float2*)&hT[k][n0];
    float2 iB = *(const float2*)&hT[k][n0 + 2];
    float4 w4 = *(const float4*)&WA[k][f0];
    float in[4] = {iA.x, iA.y, iB.x, iB.y};
    float ww[4] = {w4.x, w4.y, w4.z, w4.w};
#pragma unroll
    for (int n = 0; n < 4; ++n)
#pragma unroll
      for (int j = 0; j < 4; ++j) o[n][j] = fmaf(in[n], ww[j], o[n][j]);
  }
#pragma unroll
  for (int n = 0; n < 4; ++n)
#pragma unroll
    for (int j = 0; j < 4; ++j) o[n][j] = fmaxf(o[n][j], 0.f);

  __syncthreads();  // all GEMM1 reads done
#pragma unroll
  for (int j = 0; j < 4; ++j) {
    float2 vA = {o[0][j], o[1][j]}, vB = {o[2][j], o[3][j]};
    *(float2*)&hT[f0 + j][n0] = vA;
    *(float2*)&hT[f0 + j][n0 + 2] = vB;
  }
  for (int i = tid; i < 4096; i += 256) ((float*)WA)[i] = W2t[i];
  __syncthreads();

  float4 bv2 = *(const float4*)(b2 + f0);
  float o2[4][4];
#pragma unroll
  for (int n = 0; n < 4; ++n) {
    o2[n][0] = bv2.x; o2[n][1] = bv2.y; o2[n][2] = bv2.z; o2[n][3] = bv2.w;
  }
#pragma unroll 8
  for (int k = 0; k < 64; ++k) {
    float2 iA = *(const float2*)&hT[k][n0];
    float2 iB = *(const float2*)&hT[k][n0 + 2];
    float4 w4 = *(const float4*)&WA[k][f0];
    float in[4] = {iA.x, iA.y, iB.x, iB.y};
    float ww[4] = {w4.x, w4.y, w4.z, w4.w};
#pragma unroll
    for (int n = 0; n < 4; ++n)
#pragma unroll
      for (int j = 0; j < 4; ++j) o2[n][j] = fmaf(in[n], ww[j], o2[n][j]);
  }
  __syncthreads();  // GEMM2 reads done; hT reusable as reduce scratch

  float s[4] = {0.f, 0.f, 0.f, 0.f}, q[4] = {0.f, 0.f, 0.f, 0.f};
#pragma unroll
  for (int n = 0; n < 4; ++n) {
    int node = tile0 + n0 + n;
    if (node < NN) {
      float4 v = {o2[n][0], o2[n][1], o2[n][2], o2[n][3]};
      *(float4*)&out[node * 64 + f0] = v;
#pragma unroll
      for (int j = 0; j < 4; ++j) {
        s[j] += o2[n][j];
        q[j] = fmaf(o2[n][j], o2[n][j], q[j]);
      }
    }
  }
  float* red = &hT[0][0];
#pragma unroll
  for (int j = 0; j < 4; ++j) {
    red[(f0 + j) * 16 + ng] = s[j];
    red[1024 + (f0 + j) * 16 + ng] = q[j];
  }
  __syncthreads();
  if (tid < 64) {
    float ss = 0.f, qq = 0.f;
    for (int g = 0; g < 16; ++g) {
      ss += red[tid * 16 + g];
      qq += red[1024 + tid * 16 + g];
    }
    atomicAdd(&sums[tid], ss);
    atomicAdd(&sums[64 + tid], qq);
  }
}

// ---------------- BN finalize + relu, in place on d_out ----------------
__global__ __launch_bounds__(256) void bn_k(float* __restrict__ h2out,
                                            const float* __restrict__ sums,
                                            const float* __restrict__ gamma,
                                            const float* __restrict__ beta) {
  __shared__ float sc[64], sh[64];
  int tid = threadIdx.x;
  if (tid < 64) {
    const float invN = 1.0f / NN;
    float mean = sums[tid] * invN;
    float var = fmaf(-mean, mean, sums[64 + tid] * invN);
    float s = gamma[tid] * rsqrtf(var + BN_EPS_C);
    sc[tid] = s;
    sh[tid] = fmaf(-mean, s, beta[tid]);
  }
  __syncthreads();
  int gid = blockIdx.x * 256 + tid;
  const int tot = NN * 16;
  float4* p = (float4*)h2out;
  for (int i = gid; i < tot; i += gridDim.x * 256) {
    int f0 = (i & 15) * 4;
    float4 v = p[i];
    v.x = fmaxf(fmaf(v.x, sc[f0 + 0], sh[f0 + 0]), 0.f);
    v.y = fmaxf(fmaf(v.y, sc[f0 + 1], sh[f0 + 1]), 0.f);
    v.z = fmaxf(fmaf(v.z, sc[f0 + 2], sh[f0 + 2]), 0.f);
    v.w = fmaxf(fmaf(v.w, sc[f0 + 3], sh[f0 + 3]), 0.f);
    p[i] = v;
  }
}

extern "C" void kernel_launch(void* const* d_in, const int* in_sizes, int n_in,
                              void* d_out, int out_size, void* d_ws, size_t ws_size,
                              hipStream_t stream) {
  const float* x     = (const float*)d_in[0];
  const int*   src   = (const int*)d_in[1];
  const int*   dst   = (const int*)d_in[2];
  const float* ew    = (const float*)d_in[3];
  const float* W1    = (const float*)d_in[4];
  const float* b1    = (const float*)d_in[5];
  const float* W2    = (const float*)d_in[6];
  const float* b2    = (const float*)d_in[7];
  const float* eps   = (const float*)d_in[8];
  const float* gamma = (const float*)d_in[9];
  const float* beta  = (const float*)d_in[10];
  int E = in_sizes[1];

  // ws: counts[NN] | offs[NN] | sorted[E] u32 | xh[NN*64 halves] |
  //     {rank[E] overlaid by y[NN*64]} | sums[128] | W1t | W2t | bsum
  int*            counts = (int*)d_ws;
  int*            offs   = counts + NN;
  unsigned*       sorted = (unsigned*)(offs + NN);
  unsigned short* xh     = (unsigned short*)(sorted + E);
  float*          y      = (float*)(xh + NN * 64);
  int*            rank   = (int*)y;             // dead before gather writes y
  float*          sums   = y + NN * 64;
  float*          W1t    = sums + 128;
  float*          W2t    = W1t + 4096;
  int*            bsum   = (int*)(W2t + 4096);
  float*          h2     = (float*)d_out;

  int eb4 = (E / 4 + 255) / 256;
  prep_k<<<512, 256, 0, stream>>>(x, W1, W2, counts, sums, W1t, W2t, xh);
  histrank_k<<<eb4, 256, 0, stream>>>(dst, counts, rank, E);
  scana_k<<<NSB, 256, 0, stream>>>(counts, bsum);
  scanc_k<<<NSB, 256, 0, stream>>>(counts, bsum, offs);
  sort_k<<<eb4, 256, 0, stream>>>(dst, rank, src, ew, offs, sorted, E);
  gather_k<<<(NN + 31) / 32, 256, 0, stream>>>(xh, sorted, offs, counts, eps, y);
  mlp_k<<<(NN + 63) / 64, 256, 0, stream>>>(y, W1t, W2t, b1, b2, h2, sums);
  bn_k<<<3125, 256, 0, stream>>>(h2, sums, gamma, beta);
}